// Round 8
// baseline (765.644 us; speedup 1.0000x reference)
//
#include <hip/hip_runtime.h>
#include <stdint.h>

typedef unsigned short u16;
typedef _Float16 f16;
typedef f16    f16v8  __attribute__((ext_vector_type(8)));
typedef u16    u16v8  __attribute__((ext_vector_type(8)));
typedef float  f32x4  __attribute__((ext_vector_type(4)));
typedef int    i32x4  __attribute__((ext_vector_type(4)));
typedef int    i32x16 __attribute__((ext_vector_type(16)));

#define MFMA_F16(a,b,c)   __builtin_amdgcn_mfma_f32_16x16x32_f16((a),(b),(c),0,0,0)
#define MFMA_I8_32(a,b,c) __builtin_amdgcn_mfma_i32_32x32x32_i8((a),(b),(c),0,0,0)

__device__ __forceinline__ float b2f(u16 u){ union{unsigned u;float f;}v; v.u=((unsigned)u)<<16; return v.f; }
__device__ __forceinline__ u16 f2b(float f){ union{float f;unsigned u;}v; v.f=f;
  return (u16)((v.u + 0x7fffu + ((v.u>>16)&1u))>>16); }
__device__ __forceinline__ u16 f2h(float f){ f16 h = (f16)f; return __builtin_bit_cast(u16, h); }
__device__ __forceinline__ float h2f(u16 u){ return (float)__builtin_bit_cast(f16, u); }
__device__ __forceinline__ f16v8 ldh8(const u16* p){ return __builtin_bit_cast(f16v8, *(const u16v8*)p); }
__device__ __forceinline__ void gl2lds16(const void* g, void* l){
  __builtin_amdgcn_global_load_lds(
    (const __attribute__((address_space(1))) unsigned int*)g,
    (__attribute__((address_space(3))) unsigned int*)l,
    16, 0, 0);
}
// gelu(tanh-approx) via sigmoid identity: 0.5x(1+tanh(u)) = x*sigmoid(2u)
__device__ __forceinline__ float gelu_t(float x){
  float u2 = -1.5957691216057308f*(x + 0.044715f*x*x*x);
  return x * __builtin_amdgcn_rcpf(1.f + __expf(u2));
}

// ---------------- elementwise / prep ----------------
__global__ void mod_add_k(const float* __restrict__ sst, const float* __restrict__ t, float* __restrict__ mod){
  int i = blockIdx.x*256 + threadIdx.x;
  if (i < 2*6*1152) mod[i] = sst[i % 6912] + t[i];
}
// f32 -> f16 hi/lo planes (weights)
__global__ void split2h_k(const float* __restrict__ src, u16* __restrict__ hi, u16* __restrict__ lo, int n){
  int i = blockIdx.x*256 + threadIdx.x;
  if (i >= n) return;
  float v = src[i];
  f16 h = (f16)v;
  hi[i] = __builtin_bit_cast(u16, h);
  lo[i] = f2h(v - (float)h);
}
// fused cross-phase prep: conv qw_q, conv qw_cp, split Wkv (f16 hi/lo), y (f16 single)
__global__ void cross_prep_k(const int* __restrict__ qw_q, int8_t* __restrict__ w8q,
                             const int* __restrict__ qw_cp, int8_t* __restrict__ w8cp,
                             const float* __restrict__ Wkv, u16* __restrict__ wkvh, u16* __restrict__ wkvl,
                             const float* __restrict__ y, u16* __restrict__ yf){
  const int S1 = 1327104, S2 = 2654208, S3 = 5308416, S4 = 5824512;
  int i = blockIdx.x*256 + threadIdx.x;
  if (i < S1){ w8q[i] = (int8_t)qw_q[i]; }
  else if (i < S2){ int j = i - S1; w8cp[j] = (int8_t)qw_cp[j]; }
  else if (i < S3){ int j = i - S2; float v = Wkv[j]; f16 h = (f16)v;
    wkvh[j] = __builtin_bit_cast(u16, h); wkvl[j] = f2h(v - (float)h); }
  else if (i < S4){ int j = i - S3; yf[j] = f2h(y[j]); }
}
// fused MLP-phase prep: conv qw_f1, conv qw_f2
__global__ void mlp_prep_k(const int* __restrict__ qw_f1, int8_t* __restrict__ w8f1,
                           const int* __restrict__ qw_f2, int8_t* __restrict__ w8f2){
  const int S1 = 5308416, S2 = 10616832;
  int i = blockIdx.x*256 + threadIdx.x;
  if (i < S1){ w8f1[i] = (int8_t)qw_f1[i]; }
  else if (i < S2){ int j = i - S1; w8f2[j] = (int8_t)qw_f2[j]; }
}
// LN over C=1152 with modulation -> single f16 plane
__global__ void ln_mod_f16_k(const float* __restrict__ src, u16* __restrict__ xf,
                             const float* __restrict__ mod, int shift_row, int scale_row){
  const int row = blockIdx.x, tid = threadIdx.x;
  const int b = row >> 11;
  const float* ms = mod + ((size_t)b*6 + shift_row)*1152;
  const float* mc = mod + ((size_t)b*6 + scale_row)*1152;
  __shared__ float r1[256], r2[256];
  float s = 0.f, sq = 0.f, vals[5]; int cnt = 0;
  for (int c = tid; c < 1152; c += 256){
    float v = src[(size_t)row*1152+c];
    vals[cnt++] = v; s += v; sq += v*v;
  }
  r1[tid]=s; r2[tid]=sq; __syncthreads();
  for (int st=128; st>0; st>>=1){ if (tid<st){ r1[tid]+=r1[tid+st]; r2[tid]+=r2[tid+st]; } __syncthreads(); }
  float mean = r1[0]*(1.f/1152.f);
  float var  = r2[0]*(1.f/1152.f) - mean*mean;
  float rstd = rsqrtf(var + 1e-6f);
  cnt = 0;
  for (int c = tid; c < 1152; c += 256){
    float v = (vals[cnt++]-mean)*rstd*(1.f+mc[c]) + ms[c];
    xf[(size_t)row*1152+c] = f2h(v);
  }
}
// fused: xw = x + gate*ao, then per-row int8 quant of xw
__global__ void rgq_k(const float* __restrict__ x, const float* __restrict__ ao,
                      const float* __restrict__ mod, int gate_row, float* __restrict__ xw,
                      int8_t* __restrict__ q8, float* __restrict__ s_out, int* __restrict__ q_out){
  const int row = blockIdx.x, tid = threadIdx.x;
  const int b = row >> 11;
  const float* mg = mod + ((size_t)b*6 + gate_row)*1152;
  __shared__ float r1[256];
  __shared__ int ri[256];
  float mx = 0.f, vals[5]; int cnt = 0;
  for (int c = tid; c < 1152; c += 256){
    float v = x[(size_t)row*1152+c] + mg[c]*ao[(size_t)row*1152+c];
    xw[(size_t)row*1152+c] = v;
    vals[cnt++] = v; mx = fmaxf(mx, fabsf(v));
  }
  r1[tid]=mx; __syncthreads();
  for (int st=128; st>0; st>>=1){ if (tid<st) r1[tid]=fmaxf(r1[tid],r1[tid+st]); __syncthreads(); }
  const float s_ = fmaxf(r1[0]*(1.f/127.f), 1e-8f);
  const float inv = 1.f/s_;
  int acc = 0; cnt = 0;
  for (int c = tid; c < 1152; c += 256){
    float q = rintf(vals[cnt++]*inv);
    q = fminf(fmaxf(q, -127.f), 127.f);
    q8[(size_t)row*1152+c] = (int8_t)q;
    acc += (int)q;
  }
  ri[tid]=acc; __syncthreads();
  for (int st=128; st>0; st>>=1){ if (tid<st) ri[tid]+=ri[tid+st]; __syncthreads(); }
  if (tid==0){ s_out[row]=s_; q_out[row]=ri[0]; }
}
// fused: xw += add; LN+mod; per-row int8 quant
__global__ void rlq_k(float* __restrict__ xw, const float* __restrict__ add,
                      const float* __restrict__ mod, int shift_row, int scale_row,
                      int8_t* __restrict__ q8, float* __restrict__ s_out, int* __restrict__ q_out){
  const int row = blockIdx.x, tid = threadIdx.x;
  const int b = row >> 11;
  const float* ms = mod + ((size_t)b*6 + shift_row)*1152;
  const float* mc = mod + ((size_t)b*6 + scale_row)*1152;
  __shared__ float r1[256], r2[256];
  __shared__ int ri[256];
  float s = 0.f, sq = 0.f, vals[5]; int cnt = 0;
  for (int c = tid; c < 1152; c += 256){
    float v = xw[(size_t)row*1152+c] + add[(size_t)row*1152+c];
    xw[(size_t)row*1152+c] = v;
    vals[cnt++] = v; s += v; sq += v*v;
  }
  r1[tid]=s; r2[tid]=sq; __syncthreads();
  for (int st=128; st>0; st>>=1){ if (tid<st){ r1[tid]+=r1[tid+st]; r2[tid]+=r2[tid+st]; } __syncthreads(); }
  float mean = r1[0]*(1.f/1152.f);
  float var  = r2[0]*(1.f/1152.f) - mean*mean;
  float rstd = rsqrtf(var + 1e-6f);
  __syncthreads();
  float mx = 0.f; cnt = 0;
  for (int c = tid; c < 1152; c += 256){
    float v = (vals[cnt]-mean)*rstd*(1.f+mc[c]) + ms[c];
    vals[cnt++] = v; mx = fmaxf(mx, fabsf(v));
  }
  r1[tid]=mx; __syncthreads();
  for (int st=128; st>0; st>>=1){ if (tid<st) r1[tid]=fmaxf(r1[tid],r1[tid+st]); __syncthreads(); }
  const float s_ = fmaxf(r1[0]*(1.f/127.f), 1e-8f);
  const float inv = 1.f/s_;
  int acc = 0; cnt = 0;
  for (int c = tid; c < 1152; c += 256){
    float q = rintf(vals[cnt++]*inv);
    q = fminf(fmaxf(q, -127.f), 127.f);
    q8[(size_t)row*1152+c] = (int8_t)q;
    acc += (int)q;
  }
  ri[tid]=acc; __syncthreads();
  for (int st=128; st>0; st>>=1){ if (tid<st) ri[tid]+=ri[tid+st]; __syncthreads(); }
  if (tid==0){ s_out[row]=s_; q_out[row]=ri[0]; }
}
// register-cached row quant (C_ <= 4608)
template<int SRC_F32>
__global__ void quant_rows_k(const void* __restrict__ src, int C_,
                             int8_t* __restrict__ q8, float* __restrict__ s_out, int* __restrict__ q_out){
  const int row = blockIdx.x, tid = threadIdx.x;
  __shared__ float red[256];
  __shared__ int redi[256];
  float vals[18];
  float mx = 0.f; int cnt = 0;
  for (int c = tid; c < C_; c += 256){
    float v = SRC_F32 ? ((const float*)src)[(size_t)row*C_+c] : b2f(((const u16*)src)[(size_t)row*C_+c]);
    vals[cnt++] = v;
    mx = fmaxf(mx, fabsf(v));
  }
  red[tid]=mx; __syncthreads();
  for (int st=128; st>0; st>>=1){ if (tid<st) red[tid]=fmaxf(red[tid],red[tid+st]); __syncthreads(); }
  const float s_ = fmaxf(red[0]*(1.f/127.f), 1e-8f);
  const float inv = 1.f/s_;
  int acc = 0; cnt = 0;
  for (int c = tid; c < C_; c += 256){
    float q = rintf(vals[cnt++]*inv);
    q = fminf(fmaxf(q, -127.f), 127.f);
    q8[(size_t)row*C_+c] = (int8_t)q;
    acc += (int)q;
  }
  redi[tid]=acc; __syncthreads();
  for (int st=128; st>0; st>>=1){ if (tid<st) redi[tid]+=redi[tid+st]; __syncthreads(); }
  if (tid==0){ s_out[row]=s_; q_out[row]=redi[0]; }
}

// ------- f16 GEMM: out[M,N] = f16(A)[M,K] @ (Wh+Wl)[N,K]^T + bias -------
template<int MODE>
__global__ __launch_bounds__(256,4) void gemm_f16k(
    const u16* __restrict__ Af, int lda,
    const u16* __restrict__ Wh, const u16* __restrict__ Wl, int ldw,
    const float* __restrict__ bias, float* __restrict__ out, int ldo, int M, int K,
    u16* __restrict__ e1, u16* __restrict__ e2){
  __shared__ u16 sA[128*32];
  __shared__ u16 sWh[128*32];
  __shared__ u16 sWl[128*32];
  const int tid = threadIdx.x, lane = tid & 63;
  const int wv = tid >> 6, wx = wv & 1, wy = wv >> 1;
  const int quad = lane >> 4, l16 = lane & 15;
  const int m0 = blockIdx.y*128, n0 = blockIdx.x*128;
  f32x4 acc[4][4];
  #pragma unroll
  for (int i=0;i<4;i++)
    #pragma unroll
    for (int j=0;j<4;j++) acc[i][j] = (f32x4){0.f,0.f,0.f,0.f};
  for (int k0=0; k0<K; k0+=32){
    #pragma unroll
    for (int r=0;r<2;r++){
      int slotbase = r*256 + wv*64;        // wave-uniform LDS base (slot*16B)
      int slot = slotbase + lane;
      int row = slot >> 2;                 // 4 chunks of 16B per 32-u16 row
      int col8 = ((slot ^ (row>>1)) & 3) * 8;  // phys chunk = logical ^ ((row>>1)&3)
      int gm = m0 + row; if (gm > M-1) gm = M-1;
      size_t aoff = (size_t)gm*lda + k0 + col8;
      size_t woff = (size_t)(n0+row)*ldw + k0 + col8;
      gl2lds16(Af + aoff, &sA[(size_t)slotbase*8]);
      gl2lds16(Wh + woff, &sWh[(size_t)slotbase*8]);
      gl2lds16(Wl + woff, &sWl[(size_t)slotbase*8]);
    }
    __syncthreads();
    const int cs = ((quad ^ ((l16>>1)&3)) * 8);  // recovers logical chunk = quad
    f16v8 a[4], bh[4], bl[4];
    #pragma unroll
    for (int i=0;i<4;i++) a[i] = ldh8(&sA[(wy*64+i*16+l16)*32 + cs]);
    #pragma unroll
    for (int j=0;j<4;j++){
      bh[j] = ldh8(&sWh[(wx*64+j*16+l16)*32 + cs]);
      bl[j] = ldh8(&sWl[(wx*64+j*16+l16)*32 + cs]);
    }
    #pragma unroll
    for (int i=0;i<4;i++)
      #pragma unroll
      for (int j=0;j<4;j++){
        acc[i][j] = MFMA_F16(a[i], bh[j], acc[i][j]);
        acc[i][j] = MFMA_F16(a[i], bl[j], acc[i][j]);
      }
    __syncthreads();
  }
  #pragma unroll
  for (int j=0;j<4;j++){
    int col = n0 + wx*64 + j*16 + l16;
    float bc = bias ? bias[col] : 0.f;
    #pragma unroll
    for (int i=0;i<4;i++)
      #pragma unroll
      for (int r=0;r<4;r++){
        int row = m0 + wy*64 + i*16 + quad*4 + r;
        if (row >= M) continue;
        float v = acc[i][j][r] + bc;
        if (MODE == 0){
          out[(size_t)row*ldo + col] = v;
        } else if (MODE == 1){
          if (col < 2304){
            e1[(size_t)row*2304 + col] = f2h(v);
          } else {
            int vc = col - 2304;
            int hd_ = vc/72, d = vc - hd_*72;
            int z = row >> 8, s2 = row & 255;
            e2[((size_t)(z*16+hd_)*80 + d)*256 + s2] = f2h(v);
          }
        } else { // MODE 2: KV epilogue (448 rows): k f16 plane + V^T [h][80][448] f16
          if (col < 1152){
            e1[(size_t)row*1152 + col] = f2h(v);
          } else {
            int vc = col - 1152;
            int hd_ = vc/72, d = vc - hd_*72;
            e2[((size_t)hd_*80 + d)*448 + row] = f2h(v);
          }
        }
      }
  }
}

// ------- QKV GEMM: 256x256 tile, 4-phase/K-tile pipelined schedule (T3+T4+T5) -------
#define QKV_NT 36
__global__ __launch_bounds__(512,2) void gemm_qkv_8ph(
    const u16* __restrict__ Af,
    const u16* __restrict__ Wh_, const u16* __restrict__ Wl_,
    const float* __restrict__ bias,
    u16* __restrict__ qkf, u16* __restrict__ vtf){
  extern __shared__ u16 sm[];
  char* smb = (char*)sm;
  const int tid = threadIdx.x, lane = tid & 63, wv = tid >> 6;
  const int wr = wv >> 2, wc = wv & 3;            // 2x4 wave grid
  const int quad = lane >> 4, l16 = lane & 15;
  const int c = blockIdx.x & 7, bi = blockIdx.x >> 3;
  const int m0 = (((c>>1)<<2) + (bi&3)) << 8;     // 16 m-tiles
  const int n0 = ((c&1)*7 + (bi>>2)) << 8;        // 14 n-tiles

  const u16* gA[2]; const u16* gH[2]; const u16* gL[2];
  int sbase[2];
  #pragma unroll
  for (int r=0;r<2;r++){
    int slot = r*512 + tid;
    int row = slot >> 2;
    int col8 = ((slot ^ (row>>1)) & 3) * 8;
    sbase[r] = (r*512 + wv*64) * 16;              // wave-uniform byte base
    gA[r] = Af + (size_t)(m0+row)*1152 + col8;
    int gn = n0 + row; if (gn > 3455) gn = 3455;
    gH[r] = Wh_ + (size_t)gn*1152 + col8;
    gL[r] = Wl_ + (size_t)gn*1152 + col8;
  }

  #define STG_A(t2,b) { size_t ko=(size_t)(t2)*32; \
    gl2lds16(gA[0]+ko, smb + (b)*49152 + sbase[0]); \
    gl2lds16(gA[1]+ko, smb + (b)*49152 + sbase[1]); }
  #define STG_H(t2,b) { size_t ko=(size_t)(t2)*32; \
    gl2lds16(gH[0]+ko, smb + (b)*49152 + 16384 + sbase[0]); \
    gl2lds16(gH[1]+ko, smb + (b)*49152 + 16384 + sbase[1]); }
  #define STG_L(t2,b) { size_t ko=(size_t)(t2)*32; \
    gl2lds16(gL[0]+ko, smb + (b)*49152 + 32768 + sbase[0]); \
    gl2lds16(gL[1]+ko, smb + (b)*49152 + 32768 + sbase[1]); }

  STG_A(0,0); STG_H(0,0); STG_L(0,0);
  STG_A(1,1); STG_H(1,1); STG_L(1,1);

  const int cs = (quad ^ ((l16>>1)&3)) * 8;       // read-side swizzle (logical chunk = quad)
  const int arow = wr*128 + l16;                  // + i*16
  const int wrow = wc*64 + l16;                   // + j*16

  f32x4 acc[8][4];
  #pragma unroll
  for (int i=0;i<8;i++)
    #pragma unroll
    for (int j=0;j<4;j++) acc[i][j] = (f32x4){0.f,0.f,0.f,0.f};

  f16v8 bh[4], bl[4];

  #define PHASE(p, STAGE_STMT) { \
    const u16* bA = sm + cur*24576; \
    f16v8 a0 = ldh8(bA + (arow + (2*(p))*16)*32 + cs); \
    f16v8 a1 = ldh8(bA + (arow + (2*(p)+1)*16)*32 + cs); \
    if ((p)==0){ \
      const u16* bH = bA + 8192; \
      const u16* bL = bA + 16384; \
      _Pragma("unroll") \
      for (int j=0;j<4;j++){ \
        bh[j] = ldh8(bH + (wrow + j*16)*32 + cs); \
        bl[j] = ldh8(bL + (wrow + j*16)*32 + cs); \
      } \
    } \
    STAGE_STMT; \
    __builtin_amdgcn_s_barrier(); \
    asm volatile("s_waitcnt lgkmcnt(0)" ::: "memory"); \
    __builtin_amdgcn_sched_barrier(0); \
    __builtin_amdgcn_s_setprio(1); \
    _Pragma("unroll") \
    for (int j=0;j<4;j++){ \
      acc[2*(p)][j]   = MFMA_F16(a0, bh[j], acc[2*(p)][j]); \
      acc[2*(p)][j]   = MFMA_F16(a0, bl[j], acc[2*(p)][j]); \
      acc[2*(p)+1][j] = MFMA_F16(a1, bh[j], acc[2*(p)+1][j]); \
      acc[2*(p)+1][j] = MFMA_F16(a1, bl[j], acc[2*(p)+1][j]); \
    } \
    __builtin_amdgcn_s_setprio(0); \
    __builtin_amdgcn_s_barrier(); \
  }

  int cur = 0;
  for (int t = 0; t < QKV_NT-1; ++t){
    const int nxt = (cur == 0) ? 2 : cur - 1;     // (t+2)%3
    asm volatile("s_waitcnt vmcnt(6)" ::: "memory");
    __builtin_amdgcn_s_barrier();
    __builtin_amdgcn_sched_barrier(0);
    const bool pf = (t < QKV_NT-2);
    PHASE(0, if (pf) STG_A(t+2,nxt));
    PHASE(1, if (pf) STG_H(t+2,nxt));
    PHASE(2, if (pf) STG_L(t+2,nxt));
    PHASE(3, );
    cur = (cur == 2) ? 0 : cur + 1;
  }
  asm volatile("s_waitcnt vmcnt(0)" ::: "memory");
  __builtin_amdgcn_s_barrier();
  __builtin_amdgcn_sched_barrier(0);
  PHASE(0, );
  PHASE(1, );
  PHASE(2, );
  PHASE(3, );

  #pragma unroll
  for (int j=0;j<4;j++){
    const int col = n0 + wc*64 + j*16 + l16;
    if (col < 3456){
      const float bc = bias[col];
      if (col < 2304){
        #pragma unroll
        for (int i=0;i<8;i++){
          const size_t rb = (size_t)(m0 + wr*128 + i*16 + quad*4)*2304 + col;
          #pragma unroll
          for (int r=0;r<4;r++)
            qkf[rb + (size_t)r*2304] = f2h(acc[i][j][r] + bc);
        }
      } else {
        const int vc = col - 2304;
        const int hd_ = vc/72, d = vc - hd_*72;
        #pragma unroll
        for (int i=0;i<8;i++){
          #pragma unroll
          for (int r=0;r<4;r++){
            const int row = m0 + wr*128 + i*16 + quad*4 + r;
            const int z = row >> 8, s2 = row & 255;
            vtf[((size_t)(z*16+hd_)*80 + d)*256 + s2] = f2h(acc[i][j][r] + bc);
          }
        }
      }
    }
  }
  #undef PHASE
  #undef STG_A
  #undef STG_H
  #undef STG_L
}

// ---------------- int8 GEMM, TLP structure (R3-proven), templated on BN ----------------
template<int BN>
__global__ __launch_bounds__(256,4) void gemm_i8(
    const int8_t* __restrict__ A, int lda, const int8_t* __restrict__ W, int ldw,
    const float* __restrict__ rs, const int* __restrict__ rq,
    const float* __restrict__ sw, const int* __restrict__ zw, const float* __restrict__ bias,
    void* __restrict__ out, int ldo, int M, int K, int do_gelu, int out_f32,
    const float* __restrict__ xwf, const float* __restrict__ modf, int do_final){
  constexpr int NJ = BN/64 ? BN/64 : 1;          // j-tiles (32-wide) per wave: 2 (BN=128) / 1 (BN=64)
  __shared__ int8_t As[128*128];
  __shared__ int8_t Bs[BN*128];
  const int tid = threadIdx.x, lane = tid & 63, wv = tid >> 6;
  const int wx = wv & 1, wy = wv >> 1;
  const int l32 = lane & 31, g = lane >> 5;
  // XCD n-major chunked mapping (bijective when nwg%8==0)
  int n_idx = blockIdx.x, m_idx = blockIdx.y;
  {
    int nwg = gridDim.x*gridDim.y;
    if ((nwg & 7) == 0){
      int l = blockIdx.y*gridDim.x + blockIdx.x;
      int qq = nwg >> 3;
      int gidx = (l & 7)*qq + (l >> 3);
      n_idx = gidx / (int)gridDim.y;
      m_idx = gidx - n_idx*(int)gridDim.y;
    }
  }
  const int m0 = m_idx*128, n0 = n_idx*BN;
  const int srow = lane >> 3, schunk = lane & 7;
  const int scol = ((schunk ^ srow) & 7) * 16;   // XOR swizzle fetch column (128B rows)
  i32x16 acc[2][NJ];
  #pragma unroll
  for (int i=0;i<2;i++)
    #pragma unroll
    for (int j=0;j<NJ;j++)
      #pragma unroll
      for (int r=0;r<16;r++) acc[i][j][r] = 0;
  for (int k0 = 0; k0 < K; k0 += 128){
    #pragma unroll
    for (int i=0;i<4;i++){
      int rr = (i*4 + wv)*8;
      int gm = m0 + rr + srow; if (gm > M-1) gm = M-1;
      gl2lds16(A + (size_t)gm*lda + k0 + scol, &As[rr*128]);
    }
    #pragma unroll
    for (int i=0;i<BN/32;i++){
      int rr = (i*4 + wv)*8;
      gl2lds16(W + (size_t)(n0 + rr + srow)*ldw + k0 + scol, &Bs[rr*128]);
    }
    __syncthreads();
    #pragma unroll
    for (int kq=0; kq<4; kq++){
      i32x4 af[2], bw[NJ];
      #pragma unroll
      for (int i=0;i<2;i++){
        int row = wy*64 + i*32 + l32;
        int cs = (((kq*2 + g) ^ (row & 7))) * 16;
        af[i] = *(const i32x4*)&As[row*128 + cs];
      }
      #pragma unroll
      for (int j=0;j<NJ;j++){
        int row = wx*(BN/2) + j*32 + l32;
        int cs = (((kq*2 + g) ^ (row & 7))) * 16;
        bw[j] = *(const i32x4*)&Bs[row*128 + cs];
      }
      #pragma unroll
      for (int i=0;i<2;i++)
        #pragma unroll
        for (int j=0;j<NJ;j++)
          acc[i][j] = MFMA_I8_32(af[i], bw[j], acc[i][j]);
    }
    __syncthreads();
  }
  #pragma unroll
  for (int j=0;j<NJ;j++){
    int col = n0 + wx*(BN/2) + j*32 + l32;
    float swc = sw[col]; float zwc = (float)zw[col]; float bc = bias[col];
    #pragma unroll
    for (int i=0;i<2;i++)
      #pragma unroll
      for (int r=0;r<16;r++){
        int row = m0 + wy*64 + i*32 + (r&3) + 8*(r>>2) + 4*g;
        if (row < M){
          float v = ((float)acc[i][j][r] - (float)rq[row]*zwc) * (rs[row]*swc) + bc;
          if (do_gelu) v = gelu_t(v);
          if (do_final){
            int bb = row >> 11;
            float ov = xwf[(size_t)row*1152 + col] + modf[((size_t)bb*6+5)*1152 + col]*v;
            ((float*)out)[(size_t)row*ldo + col] = ov;
          } else if (out_f32) ((float*)out)[(size_t)row*ldo + col] = v;
          else                ((u16*)out)[(size_t)row*ldo + col] = f2b(v);
        }
      }
  }
}

// ---------------- self-attention (f16 single planes) ----------------
__global__ __launch_bounds__(256) void attn_self_f16(
    const u16* __restrict__ qkf, const u16* __restrict__ vtf,
    u16* __restrict__ of, float scale){
  constexpr int NT = 16, PSTR = 264, VSTR = 256;
  __shared__ u16 P[4*16*PSTR];
  const int tid = threadIdx.x, lane = tid & 63, wv = tid >> 6;
  const int quad = lane >> 4, l16 = lane & 15;
  const int h = blockIdx.y, z = blockIdx.z;
  const int qbase = z*256 + blockIdx.x*64;
  const u16* Vth = vtf + (size_t)(z*16+h)*80*VSTR;
  const f16v8 zf = __builtin_bit_cast(f16v8, (u16v8)0);
  const int mrow = qbase + wv*16 + l16;

  f16v8 qf[3];
  #pragma unroll
  for (int t=0;t<3;t++){
    if (t==2 && quad!=0){ qf[t]=zf; }
    else qf[t] = ldh8(qkf + (size_t)mrow*2304 + h*72 + t*32 + (t==2?0:quad*8));
  }
  f32x4 sc[NT];
  #pragma unroll
  for (int nt=0; nt<NT; nt++){
    f32x4 a = {0.f,0.f,0.f,0.f};
    #pragma unroll
    for (int t=0;t<3;t++){
      f16v8 kf = zf;
      if (!(t==2 && quad!=0))
        kf = ldh8(qkf + (size_t)(z*256 + nt*16 + l16)*2304 + 1152 + h*72 + t*32 + (t==2?0:quad*8));
      a = MFMA_F16(qf[t], kf, a);
    }
    sc[nt] = a;
  }
  float mx[4] = {-1e30f,-1e30f,-1e30f,-1e30f};
  #pragma unroll
  for (int nt=0; nt<NT; nt++)
    #pragma unroll
    for (int r=0;r<4;r++){ float v = sc[nt][r]*scale; sc[nt][r]=v; mx[r]=fmaxf(mx[r],v); }
  #pragma unroll
  for (int r=0;r<4;r++)
    for (int d=1; d<16; d<<=1) mx[r] = fmaxf(mx[r], __shfl_xor(mx[r], d, 64));
  float sm[4] = {0.f,0.f,0.f,0.f};
  #pragma unroll
  for (int nt=0; nt<NT; nt++)
    #pragma unroll
    for (int r=0;r<4;r++){ float p = __expf(sc[nt][r]-mx[r]); sc[nt][r]=p; sm[r]+=p; }
  #pragma unroll
  for (int r=0;r<4;r++){
    for (int d=1; d<16; d<<=1) sm[r] += __shfl_xor(sm[r], d, 64);
    sm[r] = 1.f/sm[r];
  }
  u16* Pw = P + wv*16*PSTR;
  #pragma unroll
  for (int nt=0; nt<NT; nt++)
    #pragma unroll
    for (int r=0;r<4;r++)
      Pw[(quad*4+r)*PSTR + nt*16 + l16] = f2h(sc[nt][r]*sm[r]);
  const u16* Pr = P + wv*16*PSTR + (size_t)l16*PSTR;
  #pragma unroll
  for (int dt=0; dt<5; dt++){
    f32x4 o = {0.f,0.f,0.f,0.f};
    #pragma unroll
    for (int kk=0; kk<8; kk++){
      f16v8 pv = ldh8(Pr + kk*32 + quad*8);
      f16v8 bv = ldh8(Vth + (size_t)(dt*16+l16)*VSTR + kk*32 + quad*8);
      o = MFMA_F16(pv, bv, o);
    }
    int d = dt*16 + l16;
    if (d < 72){
      #pragma unroll
      for (int r=0;r<4;r++){
        int row = qbase + wv*16 + quad*4 + r;
        of[(size_t)row*1152 + h*72 + d] = f2h(o[r]);
      }
    }
  }
}

// ---------------- cross-attention, online-softmax (flash-style, 2 K-halves) ----------------
// R8: halved P LDS (29696 B) kept from R6/R7, but scores computed PER-HALF so only
// sc[14] (56 VGPR) is live at once — R7's failure was sc[28] live across halves
// (VGPR 140 -> 3 waves/SIMD). Online m/l/o rescale between halves (flash-attn);
// final o /= l in epilogue. Target ~110 VGPR -> 4 waves/SIMD, 4 blocks/CU.
// No min-waves launch-bounds clause (R6 lesson: forcing it spills).
__global__ __launch_bounds__(256) void attn_cross_f16(
    const float* __restrict__ Q32,
    const u16* __restrict__ Kf,                  // 448x1152 f16
    const u16* __restrict__ Vt,                  // [h][80][448] f16
    float* __restrict__ O, float scale){
  constexpr int NTH = 14, PSTR = 232, VSTR = 448;
  __shared__ u16 P[4*16*PSTR];                   // 29,696 B
  const int tid = threadIdx.x, lane = tid & 63, wv = tid >> 6;
  const int quad = lane >> 4, l16 = lane & 15;
  const int h = blockIdx.y;
  const int qbase = blockIdx.x*64;
  const u16* Vth = Vt + (size_t)h*80*VSTR;
  const f16v8 zf = __builtin_bit_cast(f16v8, (u16v8)0);

  const int mrow = qbase + wv*16 + l16;
  const float* qp = Q32 + (size_t)mrow*1152 + h*72;
  f16v8 qf[3];
  #pragma unroll
  for (int t=0;t<3;t++){
    if (t==2 && quad!=0){ qf[t]=zf; continue; }
    const float* qpp = qp + t*32 + (t==2?0:quad*8);
    f32x4 q0 = *(const f32x4*)qpp;
    f32x4 q1 = *(const f32x4*)(qpp+4);
    u16v8 hv;
    #pragma unroll
    for (int j=0;j<4;j++){ hv[j] = f2h(q0[j]); hv[4+j] = f2h(q1[j]); }
    qf[t] = __builtin_bit_cast(f16v8, hv);
  }

  float m[4] = {-1e30f,-1e30f,-1e30f,-1e30f};
  float l[4] = {0.f,0.f,0.f,0.f};
  f32x4 o[5];
  #pragma unroll
  for (int dt=0; dt<5; dt++) o[dt] = (f32x4){0.f,0.f,0.f,0.f};
  u16* Pw = P + wv*16*PSTR;
  const u16* Pr = P + wv*16*PSTR + (size_t)l16*PSTR;

  #pragma unroll
  for (int half=0; half<2; half++){
    // QK^T for this half only: sc[14] live (56 VGPR)
    f32x4 sc[NTH];
    #pragma unroll
    for (int nt=0; nt<NTH; nt++){
      f32x4 a = {0.f,0.f,0.f,0.f};
      #pragma unroll
      for (int t=0;t<3;t++){
        f16v8 kf = zf;
        if (!(t==2 && quad!=0))
          kf = ldh8(Kf + (size_t)((half*NTH+nt)*16 + l16)*1152 + h*72 + t*32 + (t==2?0:quad*8));
        a = MFMA_F16(qf[t], kf, a);
      }
      sc[nt] = a;
    }
    // half-local row max
    float hm[4] = {-1e30f,-1e30f,-1e30f,-1e30f};
    #pragma unroll
    for (int nt=0; nt<NTH; nt++)
      #pragma unroll
      for (int r=0;r<4;r++){ float v = sc[nt][r]*scale; sc[nt][r]=v; hm[r]=fmaxf(hm[r],v); }
    #pragma unroll
    for (int r=0;r<4;r++)
      for (int d=1; d<16; d<<=1) hm[r] = fmaxf(hm[r], __shfl_xor(hm[r], d, 64));
    // online rescale
    #pragma unroll
    for (int r=0;r<4;r++){
      float mn = fmaxf(m[r], hm[r]);
      float fac = __expf(m[r]-mn);
      m[r] = mn; l[r] *= fac;
      #pragma unroll
      for (int dt=0; dt<5; dt++) o[dt][r] *= fac;
    }
    // exp + partial-sum + P-write (unnormalized)
    #pragma unroll
    for (int nt=0; nt<NTH; nt++)
      #pragma unroll
      for (int r=0;r<4;r++){
        float p = __expf(sc[nt][r]-m[r]);
        l[r] += p;
        Pw[(quad*4+r)*PSTR + nt*16 + l16] = f2h(p);
      }
    // PV for this half
    #pragma unroll
    for (int dt=0; dt<5; dt++){
      #pragma unroll
      for (int kk=0; kk<7; kk++){
        f16v8 pv = ldh8(Pr + kk*32 + quad*8);
        f16v8 bv = ldh8(Vth + (size_t)(dt*16+l16)*VSTR + half*224 + kk*32 + quad*8);
        o[dt] = MFMA_F16(pv, bv, o[dt]);
      }
    }
  }
  // reduce l across the 16 k-lanes, then normalize
  #pragma unroll
  for (int r=0;r<4;r++){
    for (int d=1; d<16; d<<=1) l[r] += __shfl_xor(l[r], d, 64);
    l[r] = 1.f/l[r];
  }
  #pragma unroll
  for (int dt=0; dt<5; dt++){
    int d = dt*16 + l16;
    if (d < 72){
      #pragma unroll
      for (int r=0;r<4;r++){
        int row = qbase + wv*16 + quad*4 + r;
        O[(size_t)row*1152 + h*72 + d] = o[dt][r]*l[r];
      }
    }
  }
}

// ---------------- launch ----------------
extern "C" void kernel_launch(void* const* d_in, const int* in_sizes, int n_in,
                              void* d_out, int out_size, void* d_ws, size_t ws_size,
                              hipStream_t stream){
  const float* x    = (const float*)d_in[0];
  const float* y    = (const float*)d_in[1];
  const float* t    = (const float*)d_in[2];
  const float* sst  = (const float*)d_in[3];
  const float* Wqkv = (const float*)d_in[4];
  const float* bqkv = (const float*)d_in[5];
  const float* Wo   = (const float*)d_in[6];
  const float* bo   = (const float*)d_in[7];
  const float* Wkv  = (const float*)d_in[8];
  const float* bkv  = (const float*)d_in[9];
  const int*   qw_q  = (const int*)d_in[10];
  const float* sw_q  = (const float*)d_in[11];
  const int*   zw_q  = (const int*)d_in[12];
  const float* b_q   = (const float*)d_in[13];
  const int*   qw_cp = (const int*)d_in[14];
  const float* sw_cp = (const float*)d_in[15];
  const int*   zw_cp = (const int*)d_in[16];
  const float* b_cp  = (const float*)d_in[17];
  const int*   qw_f1 = (const int*)d_in[18];
  const float* sw_f1 = (const float*)d_in[19];
  const int*   zw_f1 = (const int*)d_in[20];
  const float* b_f1  = (const float*)d_in[21];
  const int*   qw_f2 = (const int*)d_in[22];
  const float* sw_f2 = (const float*)d_in[23];
  const int*   zw_f2 = (const int*)d_in[24];
  const float* b_f2  = (const float*)d_in[25];
  (void)in_sizes; (void)n_in; (void)out_size;

  constexpr size_t SZR = (size_t)4096*1152*4;        // 18,874,368
  constexpr size_t R0 = 0;                           // xw f32
  constexpr size_t R1 = R0 + SZR;
  constexpr size_t R2 = R1 + SZR;
  constexpr size_t R3 = R2 + SZR;
  constexpr size_t R4 = R3 + SZR;
  constexpr size_t R5 = R4 + (size_t)9437184;
  constexpr size_t R6 = R5 + (size_t)9437184;
  constexpr size_t RS = R6 + (size_t)10485760;
  constexpr size_t RQ = RS + (size_t)4096*4;
  constexpr size_t RM = RQ + (size_t)4096*4;
  constexpr size_t WS_NEED = RM + (size_t)2*6*1152*4;  // ~100.1 MB (proven ws >= 121.8 MB)
  if (ws_size < WS_NEED) return;

  char* ws = (char*)d_ws;
  float*  xw    = (float*)(ws + R0);
  u16*    wqkvh = (u16*)(ws + R1);
  u16*    wqkvl = (u16*)(ws + R1 + (size_t)3456*1152*2);
  u16*    wkvh  = (u16*)(ws + R1);
  u16*    wkvl  = (u16*)(ws + R1 + (size_t)2304*1152*2);
  u16*    yf    = (u16*)(ws + R1 + (size_t)2*2304*1152*2);
  float*  q32   = (float*)(ws + R1);
  float*  cpout = (float*)(ws + R1);
  int8_t* q8h   = (int8_t*)(ws + R1);
  u16*    qkf   = (u16*)(ws + R2);
  float*  aof   = (float*)(ws + R2);
  u16*    hbuf  = (u16*)(ws + R2);
  u16*    xmf   = (u16*)(ws + R4);
  u16*    of    = (u16*)(ws + R4);
  u16*    kf    = (u16*)(ws + R4 + (size_t)4128768);
  u16*    vtc   = (u16*)(ws + R4 + (size_t)6193152);
  int8_t* w8f2  = (int8_t*)(ws + R4);
  int8_t* w8q   = (int8_t*)(ws + R5);
  int8_t* w8cp  = (int8_t*)(ws + R5 + (size_t)1327104);
  int8_t* w8f1  = (int8_t*)(ws + R5 + (size_t)2654208);
  u16*    vtf   = (u16*)(ws + R6);
  u16*    woh   = (u16*)(ws + R6);
  u16*    wol   = (u16*)(ws + R6 + (size_t)1152*1152*2);
  int8_t* q8x   = (int8_t*)(ws + R6);
  float*  rs    = (float*)(ws + RS);
  int*    rq    = (int*)(ws + RQ);
  float*  mod   = (float*)(ws + RM);

  const float scale = 0.11785113019775793f; // 72^-0.5

  static bool attr_set = false;
  if (!attr_set){
    hipFuncSetAttribute(reinterpret_cast<const void*>(gemm_qkv_8ph),
                        hipFuncAttributeMaxDynamicSharedMemorySize, 3*49152);
    attr_set = true;
  }

  mod_add_k<<<(2*6*1152+255)/256,256,0,stream>>>(sst, t, mod);

  // ---- MSA branch (f16 GEMMs) ----
  ln_mod_f16_k<<<4096,256,0,stream>>>(x, xmf, mod, 0, 1);
  split2h_k<<<(3456*1152+255)/256,256,0,stream>>>(Wqkv, wqkvh, wqkvl, 3456*1152);
  gemm_qkv_8ph<<<dim3(224),dim3(512),3*49152,stream>>>(xmf, wqkvh, wqkvl, bqkv, qkf, vtf);
  attn_self_f16<<<dim3(4,16,16),256,0,stream>>>(qkf, vtf, of, scale);
  split2h_k<<<(1152*1152+255)/256,256,0,stream>>>(Wo, woh, wol, 1152*1152);
  gemm_f16k<0><<<dim3(9,32),256,0,stream>>>(of,1152, woh,wol,1152, bo, aof,1152, 4096,1152, nullptr,nullptr);
  rgq_k<<<4096,256,0,stream>>>(x, aof, mod, 2, xw, q8x, rs, rq);

  // ---- cross-attn branch ----
  cross_prep_k<<<(5824512+255)/256,256,0,stream>>>(qw_q,w8q, qw_cp,w8cp, Wkv,wkvh,wkvl, y,yf);
  gemm_f16k<2><<<dim3(18,4),256,0,stream>>>(yf,1152, wkvh,wkvl,1152, bkv, nullptr,0, 448,1152, kf,vtc);
  gemm_i8<64><<<dim3(18,32),256,0,stream>>>(q8x,1152, w8q,1152, rs,rq, sw_q,zw_q,b_q, q32,1152, 4096,1152, 0, 1, nullptr,nullptr,0);
  attn_cross_f16<<<dim3(64,16),256,0,stream>>>(q32, kf, vtc, aof, scale);
  quant_rows_k<1><<<4096,256,0,stream>>>(aof, 1152, q8x, rs, rq);
  gemm_i8<64><<<dim3(18,32),256,0,stream>>>(q8x,1152, w8cp,1152, rs,rq, sw_cp,zw_cp,b_cp, cpout,1152, 4096,1152, 0, 1, nullptr,nullptr,0);

  // ---- MLP branch ----
  rlq_k<<<4096,256,0,stream>>>(xw, cpout, mod, 3, 4, q8x, rs, rq);
  mlp_prep_k<<<(10616832+255)/256,256,0,stream>>>(qw_f1, w8f1, qw_f2, w8f2);
  gemm_i8<128><<<dim3(36,32),256,0,stream>>>(q8x,1152, w8f1,1152, rs,rq, sw_f1,zw_f1,b_f1, hbuf,4608, 4096,1152, 1, 0, nullptr,nullptr,0);
  quant_rows_k<0><<<4096,256,0,stream>>>(hbuf, 4608, q8h, rs, rq);
  gemm_i8<64><<<dim3(18,32),256,0,stream>>>(q8h,4608, w8f2,4608, rs,rq, sw_f2,zw_f2,b_f2, d_out,1152, 4096,4608, 0, 1, xw,mod,1);
}

// Round 9
// 730.693 us; speedup vs baseline: 1.0478x; 1.0478x over previous
//
#include <hip/hip_runtime.h>
#include <stdint.h>

typedef unsigned short u16;
typedef _Float16 f16;
typedef f16    f16v8  __attribute__((ext_vector_type(8)));
typedef u16    u16v8  __attribute__((ext_vector_type(8)));
typedef float  f32x4  __attribute__((ext_vector_type(4)));
typedef int    i32x4  __attribute__((ext_vector_type(4)));
typedef int    i32x16 __attribute__((ext_vector_type(16)));

#define MFMA_F16(a,b,c)   __builtin_amdgcn_mfma_f32_16x16x32_f16((a),(b),(c),0,0,0)
#define MFMA_I8_32(a,b,c) __builtin_amdgcn_mfma_i32_32x32x32_i8((a),(b),(c),0,0,0)

__device__ __forceinline__ float b2f(u16 u){ union{unsigned u;float f;}v; v.u=((unsigned)u)<<16; return v.f; }
__device__ __forceinline__ u16 f2b(float f){ union{float f;unsigned u;}v; v.f=f;
  return (u16)((v.u + 0x7fffu + ((v.u>>16)&1u))>>16); }
__device__ __forceinline__ u16 f2h(float f){ f16 h = (f16)f; return __builtin_bit_cast(u16, h); }
__device__ __forceinline__ float h2f(u16 u){ return (float)__builtin_bit_cast(f16, u); }
__device__ __forceinline__ f16v8 ldh8(const u16* p){ return __builtin_bit_cast(f16v8, *(const u16v8*)p); }
__device__ __forceinline__ void gl2lds16(const void* g, void* l){
  __builtin_amdgcn_global_load_lds(
    (const __attribute__((address_space(1))) unsigned int*)g,
    (__attribute__((address_space(3))) unsigned int*)l,
    16, 0, 0);
}
// gelu(tanh-approx) via sigmoid identity: 0.5x(1+tanh(u)) = x*sigmoid(2u)
__device__ __forceinline__ float gelu_t(float x){
  float u2 = -1.5957691216057308f*(x + 0.044715f*x*x*x);
  return x * __builtin_amdgcn_rcpf(1.f + __expf(u2));
}

// ---------------- elementwise / prep ----------------
__global__ void mod_add_k(const float* __restrict__ sst, const float* __restrict__ t, float* __restrict__ mod){
  int i = blockIdx.x*256 + threadIdx.x;
  if (i < 2*6*1152) mod[i] = sst[i % 6912] + t[i];
}
// f32 -> f16 hi/lo planes (weights)
__global__ void split2h_k(const float* __restrict__ src, u16* __restrict__ hi, u16* __restrict__ lo, int n){
  int i = blockIdx.x*256 + threadIdx.x;
  if (i >= n) return;
  float v = src[i];
  f16 h = (f16)v;
  hi[i] = __builtin_bit_cast(u16, h);
  lo[i] = f2h(v - (float)h);
}
// fused cross-phase prep: conv qw_q, conv qw_cp, split Wkv (f16 hi/lo), y (f16 single)
__global__ void cross_prep_k(const int* __restrict__ qw_q, int8_t* __restrict__ w8q,
                             const int* __restrict__ qw_cp, int8_t* __restrict__ w8cp,
                             const float* __restrict__ Wkv, u16* __restrict__ wkvh, u16* __restrict__ wkvl,
                             const float* __restrict__ y, u16* __restrict__ yf){
  const int S1 = 1327104, S2 = 2654208, S3 = 5308416, S4 = 5824512;
  int i = blockIdx.x*256 + threadIdx.x;
  if (i < S1){ w8q[i] = (int8_t)qw_q[i]; }
  else if (i < S2){ int j = i - S1; w8cp[j] = (int8_t)qw_cp[j]; }
  else if (i < S3){ int j = i - S2; float v = Wkv[j]; f16 h = (f16)v;
    wkvh[j] = __builtin_bit_cast(u16, h); wkvl[j] = f2h(v - (float)h); }
  else if (i < S4){ int j = i - S3; yf[j] = f2h(y[j]); }
}
// fused MLP-phase prep: conv qw_f1, conv qw_f2
__global__ void mlp_prep_k(const int* __restrict__ qw_f1, int8_t* __restrict__ w8f1,
                           const int* __restrict__ qw_f2, int8_t* __restrict__ w8f2){
  const int S1 = 5308416, S2 = 10616832;
  int i = blockIdx.x*256 + threadIdx.x;
  if (i < S1){ w8f1[i] = (int8_t)qw_f1[i]; }
  else if (i < S2){ int j = i - S1; w8f2[j] = (int8_t)qw_f2[j]; }
}
// LN over C=1152 with modulation -> single f16 plane
__global__ void ln_mod_f16_k(const float* __restrict__ src, u16* __restrict__ xf,
                             const float* __restrict__ mod, int shift_row, int scale_row){
  const int row = blockIdx.x, tid = threadIdx.x;
  const int b = row >> 11;
  const float* ms = mod + ((size_t)b*6 + shift_row)*1152;
  const float* mc = mod + ((size_t)b*6 + scale_row)*1152;
  __shared__ float r1[256], r2[256];
  float s = 0.f, sq = 0.f, vals[5]; int cnt = 0;
  for (int c = tid; c < 1152; c += 256){
    float v = src[(size_t)row*1152+c];
    vals[cnt++] = v; s += v; sq += v*v;
  }
  r1[tid]=s; r2[tid]=sq; __syncthreads();
  for (int st=128; st>0; st>>=1){ if (tid<st){ r1[tid]+=r1[tid+st]; r2[tid]+=r2[tid+st]; } __syncthreads(); }
  float mean = r1[0]*(1.f/1152.f);
  float var  = r2[0]*(1.f/1152.f) - mean*mean;
  float rstd = rsqrtf(var + 1e-6f);
  cnt = 0;
  for (int c = tid; c < 1152; c += 256){
    float v = (vals[cnt++]-mean)*rstd*(1.f+mc[c]) + ms[c];
    xf[(size_t)row*1152+c] = f2h(v);
  }
}
// fused: xw = x + gate*ao, then per-row int8 quant of xw
__global__ void rgq_k(const float* __restrict__ x, const float* __restrict__ ao,
                      const float* __restrict__ mod, int gate_row, float* __restrict__ xw,
                      int8_t* __restrict__ q8, float* __restrict__ s_out, int* __restrict__ q_out){
  const int row = blockIdx.x, tid = threadIdx.x;
  const int b = row >> 11;
  const float* mg = mod + ((size_t)b*6 + gate_row)*1152;
  __shared__ float r1[256];
  __shared__ int ri[256];
  float mx = 0.f, vals[5]; int cnt = 0;
  for (int c = tid; c < 1152; c += 256){
    float v = x[(size_t)row*1152+c] + mg[c]*ao[(size_t)row*1152+c];
    xw[(size_t)row*1152+c] = v;
    vals[cnt++] = v; mx = fmaxf(mx, fabsf(v));
  }
  r1[tid]=mx; __syncthreads();
  for (int st=128; st>0; st>>=1){ if (tid<st) r1[tid]=fmaxf(r1[tid],r1[tid+st]); __syncthreads(); }
  const float s_ = fmaxf(r1[0]*(1.f/127.f), 1e-8f);
  const float inv = 1.f/s_;
  int acc = 0; cnt = 0;
  for (int c = tid; c < 1152; c += 256){
    float q = rintf(vals[cnt++]*inv);
    q = fminf(fmaxf(q, -127.f), 127.f);
    q8[(size_t)row*1152+c] = (int8_t)q;
    acc += (int)q;
  }
  ri[tid]=acc; __syncthreads();
  for (int st=128; st>0; st>>=1){ if (tid<st) ri[tid]+=ri[tid+st]; __syncthreads(); }
  if (tid==0){ s_out[row]=s_; q_out[row]=ri[0]; }
}
// fused: xw += add; LN+mod; per-row int8 quant
__global__ void rlq_k(float* __restrict__ xw, const float* __restrict__ add,
                      const float* __restrict__ mod, int shift_row, int scale_row,
                      int8_t* __restrict__ q8, float* __restrict__ s_out, int* __restrict__ q_out){
  const int row = blockIdx.x, tid = threadIdx.x;
  const int b = row >> 11;
  const float* ms = mod + ((size_t)b*6 + shift_row)*1152;
  const float* mc = mod + ((size_t)b*6 + scale_row)*1152;
  __shared__ float r1[256], r2[256];
  __shared__ int ri[256];
  float s = 0.f, sq = 0.f, vals[5]; int cnt = 0;
  for (int c = tid; c < 1152; c += 256){
    float v = xw[(size_t)row*1152+c] + add[(size_t)row*1152+c];
    xw[(size_t)row*1152+c] = v;
    vals[cnt++] = v; s += v; sq += v*v;
  }
  r1[tid]=s; r2[tid]=sq; __syncthreads();
  for (int st=128; st>0; st>>=1){ if (tid<st){ r1[tid]+=r1[tid+st]; r2[tid]+=r2[tid+st]; } __syncthreads(); }
  float mean = r1[0]*(1.f/1152.f);
  float var  = r2[0]*(1.f/1152.f) - mean*mean;
  float rstd = rsqrtf(var + 1e-6f);
  __syncthreads();
  float mx = 0.f; cnt = 0;
  for (int c = tid; c < 1152; c += 256){
    float v = (vals[cnt]-mean)*rstd*(1.f+mc[c]) + ms[c];
    vals[cnt++] = v; mx = fmaxf(mx, fabsf(v));
  }
  r1[tid]=mx; __syncthreads();
  for (int st=128; st>0; st>>=1){ if (tid<st) r1[tid]=fmaxf(r1[tid],r1[tid+st]); __syncthreads(); }
  const float s_ = fmaxf(r1[0]*(1.f/127.f), 1e-8f);
  const float inv = 1.f/s_;
  int acc = 0; cnt = 0;
  for (int c = tid; c < 1152; c += 256){
    float q = rintf(vals[cnt++]*inv);
    q = fminf(fmaxf(q, -127.f), 127.f);
    q8[(size_t)row*1152+c] = (int8_t)q;
    acc += (int)q;
  }
  ri[tid]=acc; __syncthreads();
  for (int st=128; st>0; st>>=1){ if (tid<st) ri[tid]+=ri[tid+st]; __syncthreads(); }
  if (tid==0){ s_out[row]=s_; q_out[row]=ri[0]; }
}
// register-cached row quant (C_ <= 4608)
template<int SRC_F32>
__global__ void quant_rows_k(const void* __restrict__ src, int C_,
                             int8_t* __restrict__ q8, float* __restrict__ s_out, int* __restrict__ q_out){
  const int row = blockIdx.x, tid = threadIdx.x;
  __shared__ float red[256];
  __shared__ int redi[256];
  float vals[18];
  float mx = 0.f; int cnt = 0;
  for (int c = tid; c < C_; c += 256){
    float v = SRC_F32 ? ((const float*)src)[(size_t)row*C_+c] : b2f(((const u16*)src)[(size_t)row*C_+c]);
    vals[cnt++] = v;
    mx = fmaxf(mx, fabsf(v));
  }
  red[tid]=mx; __syncthreads();
  for (int st=128; st>0; st>>=1){ if (tid<st) red[tid]=fmaxf(red[tid],red[tid+st]); __syncthreads(); }
  const float s_ = fmaxf(red[0]*(1.f/127.f), 1e-8f);
  const float inv = 1.f/s_;
  int acc = 0; cnt = 0;
  for (int c = tid; c < C_; c += 256){
    float q = rintf(vals[cnt++]*inv);
    q = fminf(fmaxf(q, -127.f), 127.f);
    q8[(size_t)row*C_+c] = (int8_t)q;
    acc += (int)q;
  }
  redi[tid]=acc; __syncthreads();
  for (int st=128; st>0; st>>=1){ if (tid<st) redi[tid]+=redi[tid+st]; __syncthreads(); }
  if (tid==0){ s_out[row]=s_; q_out[row]=redi[0]; }
}

// ------- f16 GEMM: out[M,N] = f16(A)[M,K] @ (Wh+Wl)[N,K]^T + bias -------
template<int MODE>
__global__ __launch_bounds__(256,4) void gemm_f16k(
    const u16* __restrict__ Af, int lda,
    const u16* __restrict__ Wh, const u16* __restrict__ Wl, int ldw,
    const float* __restrict__ bias, float* __restrict__ out, int ldo, int M, int K,
    u16* __restrict__ e1, u16* __restrict__ e2){
  __shared__ u16 sA[128*32];
  __shared__ u16 sWh[128*32];
  __shared__ u16 sWl[128*32];
  const int tid = threadIdx.x, lane = tid & 63;
  const int wv = tid >> 6, wx = wv & 1, wy = wv >> 1;
  const int quad = lane >> 4, l16 = lane & 15;
  const int m0 = blockIdx.y*128, n0 = blockIdx.x*128;
  f32x4 acc[4][4];
  #pragma unroll
  for (int i=0;i<4;i++)
    #pragma unroll
    for (int j=0;j<4;j++) acc[i][j] = (f32x4){0.f,0.f,0.f,0.f};
  for (int k0=0; k0<K; k0+=32){
    #pragma unroll
    for (int r=0;r<2;r++){
      int slotbase = r*256 + wv*64;        // wave-uniform LDS base (slot*16B)
      int slot = slotbase + lane;
      int row = slot >> 2;                 // 4 chunks of 16B per 32-u16 row
      int col8 = ((slot ^ (row>>1)) & 3) * 8;  // phys chunk = logical ^ ((row>>1)&3)
      int gm = m0 + row; if (gm > M-1) gm = M-1;
      size_t aoff = (size_t)gm*lda + k0 + col8;
      size_t woff = (size_t)(n0+row)*ldw + k0 + col8;
      gl2lds16(Af + aoff, &sA[(size_t)slotbase*8]);
      gl2lds16(Wh + woff, &sWh[(size_t)slotbase*8]);
      gl2lds16(Wl + woff, &sWl[(size_t)slotbase*8]);
    }
    __syncthreads();
    const int cs = ((quad ^ ((l16>>1)&3)) * 8);  // recovers logical chunk = quad
    f16v8 a[4], bh[4], bl[4];
    #pragma unroll
    for (int i=0;i<4;i++) a[i] = ldh8(&sA[(wy*64+i*16+l16)*32 + cs]);
    #pragma unroll
    for (int j=0;j<4;j++){
      bh[j] = ldh8(&sWh[(wx*64+j*16+l16)*32 + cs]);
      bl[j] = ldh8(&sWl[(wx*64+j*16+l16)*32 + cs]);
    }
    #pragma unroll
    for (int i=0;i<4;i++)
      #pragma unroll
      for (int j=0;j<4;j++){
        acc[i][j] = MFMA_F16(a[i], bh[j], acc[i][j]);
        acc[i][j] = MFMA_F16(a[i], bl[j], acc[i][j]);
      }
    __syncthreads();
  }
  #pragma unroll
  for (int j=0;j<4;j++){
    int col = n0 + wx*64 + j*16 + l16;
    float bc = bias ? bias[col] : 0.f;
    #pragma unroll
    for (int i=0;i<4;i++)
      #pragma unroll
      for (int r=0;r<4;r++){
        int row = m0 + wy*64 + i*16 + quad*4 + r;
        if (row >= M) continue;
        float v = acc[i][j][r] + bc;
        if (MODE == 0){
          out[(size_t)row*ldo + col] = v;
        } else if (MODE == 1){
          if (col < 2304){
            e1[(size_t)row*2304 + col] = f2h(v);
          } else {
            int vc = col - 2304;
            int hd_ = vc/72, d = vc - hd_*72;
            int z = row >> 8, s2 = row & 255;
            e2[((size_t)(z*16+hd_)*80 + d)*256 + s2] = f2h(v);
          }
        } else { // MODE 2: KV epilogue (448 rows): k f16 plane + V^T [h][80][448] f16
          if (col < 1152){
            e1[(size_t)row*1152 + col] = f2h(v);
          } else {
            int vc = col - 1152;
            int hd_ = vc/72, d = vc - hd_*72;
            e2[((size_t)hd_*80 + d)*448 + row] = f2h(v);
          }
        }
      }
  }
}

// ------- QKV GEMM: 256x256 tile, 4-phase/K-tile pipelined schedule (T3+T4+T5) -------
#define QKV_NT 36
__global__ __launch_bounds__(512,2) void gemm_qkv_8ph(
    const u16* __restrict__ Af,
    const u16* __restrict__ Wh_, const u16* __restrict__ Wl_,
    const float* __restrict__ bias,
    u16* __restrict__ qkf, u16* __restrict__ vtf){
  extern __shared__ u16 sm[];
  char* smb = (char*)sm;
  const int tid = threadIdx.x, lane = tid & 63, wv = tid >> 6;
  const int wr = wv >> 2, wc = wv & 3;            // 2x4 wave grid
  const int quad = lane >> 4, l16 = lane & 15;
  const int c = blockIdx.x & 7, bi = blockIdx.x >> 3;
  const int m0 = (((c>>1)<<2) + (bi&3)) << 8;     // 16 m-tiles
  const int n0 = ((c&1)*7 + (bi>>2)) << 8;        // 14 n-tiles

  const u16* gA[2]; const u16* gH[2]; const u16* gL[2];
  int sbase[2];
  #pragma unroll
  for (int r=0;r<2;r++){
    int slot = r*512 + tid;
    int row = slot >> 2;
    int col8 = ((slot ^ (row>>1)) & 3) * 8;
    sbase[r] = (r*512 + wv*64) * 16;              // wave-uniform byte base
    gA[r] = Af + (size_t)(m0+row)*1152 + col8;
    int gn = n0 + row; if (gn > 3455) gn = 3455;
    gH[r] = Wh_ + (size_t)gn*1152 + col8;
    gL[r] = Wl_ + (size_t)gn*1152 + col8;
  }

  #define STG_A(t2,b) { size_t ko=(size_t)(t2)*32; \
    gl2lds16(gA[0]+ko, smb + (b)*49152 + sbase[0]); \
    gl2lds16(gA[1]+ko, smb + (b)*49152 + sbase[1]); }
  #define STG_H(t2,b) { size_t ko=(size_t)(t2)*32; \
    gl2lds16(gH[0]+ko, smb + (b)*49152 + 16384 + sbase[0]); \
    gl2lds16(gH[1]+ko, smb + (b)*49152 + 16384 + sbase[1]); }
  #define STG_L(t2,b) { size_t ko=(size_t)(t2)*32; \
    gl2lds16(gL[0]+ko, smb + (b)*49152 + 32768 + sbase[0]); \
    gl2lds16(gL[1]+ko, smb + (b)*49152 + 32768 + sbase[1]); }

  STG_A(0,0); STG_H(0,0); STG_L(0,0);
  STG_A(1,1); STG_H(1,1); STG_L(1,1);

  const int cs = (quad ^ ((l16>>1)&3)) * 8;       // read-side swizzle (logical chunk = quad)
  const int arow = wr*128 + l16;                  // + i*16
  const int wrow = wc*64 + l16;                   // + j*16

  f32x4 acc[8][4];
  #pragma unroll
  for (int i=0;i<8;i++)
    #pragma unroll
    for (int j=0;j<4;j++) acc[i][j] = (f32x4){0.f,0.f,0.f,0.f};

  f16v8 bh[4], bl[4];

  #define PHASE(p, STAGE_STMT) { \
    const u16* bA = sm + cur*24576; \
    f16v8 a0 = ldh8(bA + (arow + (2*(p))*16)*32 + cs); \
    f16v8 a1 = ldh8(bA + (arow + (2*(p)+1)*16)*32 + cs); \
    if ((p)==0){ \
      const u16* bH = bA + 8192; \
      const u16* bL = bA + 16384; \
      _Pragma("unroll") \
      for (int j=0;j<4;j++){ \
        bh[j] = ldh8(bH + (wrow + j*16)*32 + cs); \
        bl[j] = ldh8(bL + (wrow + j*16)*32 + cs); \
      } \
    } \
    STAGE_STMT; \
    __builtin_amdgcn_s_barrier(); \
    asm volatile("s_waitcnt lgkmcnt(0)" ::: "memory"); \
    __builtin_amdgcn_sched_barrier(0); \
    __builtin_amdgcn_s_setprio(1); \
    _Pragma("unroll") \
    for (int j=0;j<4;j++){ \
      acc[2*(p)][j]   = MFMA_F16(a0, bh[j], acc[2*(p)][j]); \
      acc[2*(p)][j]   = MFMA_F16(a0, bl[j], acc[2*(p)][j]); \
      acc[2*(p)+1][j] = MFMA_F16(a1, bh[j], acc[2*(p)+1][j]); \
      acc[2*(p)+1][j] = MFMA_F16(a1, bl[j], acc[2*(p)+1][j]); \
    } \
    __builtin_amdgcn_s_setprio(0); \
    __builtin_amdgcn_s_barrier(); \
  }

  int cur = 0;
  for (int t = 0; t < QKV_NT-1; ++t){
    const int nxt = (cur == 0) ? 2 : cur - 1;     // (t+2)%3
    asm volatile("s_waitcnt vmcnt(6)" ::: "memory");
    __builtin_amdgcn_s_barrier();
    __builtin_amdgcn_sched_barrier(0);
    const bool pf = (t < QKV_NT-2);
    PHASE(0, if (pf) STG_A(t+2,nxt));
    PHASE(1, if (pf) STG_H(t+2,nxt));
    PHASE(2, if (pf) STG_L(t+2,nxt));
    PHASE(3, );
    cur = (cur == 2) ? 0 : cur + 1;
  }
  asm volatile("s_waitcnt vmcnt(0)" ::: "memory");
  __builtin_amdgcn_s_barrier();
  __builtin_amdgcn_sched_barrier(0);
  PHASE(0, );
  PHASE(1, );
  PHASE(2, );
  PHASE(3, );

  #pragma unroll
  for (int j=0;j<4;j++){
    const int col = n0 + wc*64 + j*16 + l16;
    if (col < 3456){
      const float bc = bias[col];
      if (col < 2304){
        #pragma unroll
        for (int i=0;i<8;i++){
          const size_t rb = (size_t)(m0 + wr*128 + i*16 + quad*4)*2304 + col;
          #pragma unroll
          for (int r=0;r<4;r++)
            qkf[rb + (size_t)r*2304] = f2h(acc[i][j][r] + bc);
        }
      } else {
        const int vc = col - 2304;
        const int hd_ = vc/72, d = vc - hd_*72;
        #pragma unroll
        for (int i=0;i<8;i++){
          #pragma unroll
          for (int r=0;r<4;r++){
            const int row = m0 + wr*128 + i*16 + quad*4 + r;
            const int z = row >> 8, s2 = row & 255;
            vtf[((size_t)(z*16+hd_)*80 + d)*256 + s2] = f2h(acc[i][j][r] + bc);
          }
        }
      }
    }
  }
  #undef PHASE
  #undef STG_A
  #undef STG_H
  #undef STG_L
}

// ---------------- int8 GEMM, TLP structure (R3-proven), templated on BN ----------------
template<int BN>
__global__ __launch_bounds__(256,4) void gemm_i8(
    const int8_t* __restrict__ A, int lda, const int8_t* __restrict__ W, int ldw,
    const float* __restrict__ rs, const int* __restrict__ rq,
    const float* __restrict__ sw, const int* __restrict__ zw, const float* __restrict__ bias,
    void* __restrict__ out, int ldo, int M, int K, int do_gelu, int out_f32,
    const float* __restrict__ xwf, const float* __restrict__ modf, int do_final){
  constexpr int NJ = BN/64 ? BN/64 : 1;          // j-tiles (32-wide) per wave: 2 (BN=128) / 1 (BN=64)
  __shared__ int8_t As[128*128];
  __shared__ int8_t Bs[BN*128];
  const int tid = threadIdx.x, lane = tid & 63, wv = tid >> 6;
  const int wx = wv & 1, wy = wv >> 1;
  const int l32 = lane & 31, g = lane >> 5;
  // XCD n-major chunked mapping (bijective when nwg%8==0)
  int n_idx = blockIdx.x, m_idx = blockIdx.y;
  {
    int nwg = gridDim.x*gridDim.y;
    if ((nwg & 7) == 0){
      int l = blockIdx.y*gridDim.x + blockIdx.x;
      int qq = nwg >> 3;
      int gidx = (l & 7)*qq + (l >> 3);
      n_idx = gidx / (int)gridDim.y;
      m_idx = gidx - n_idx*(int)gridDim.y;
    }
  }
  const int m0 = m_idx*128, n0 = n_idx*BN;
  const int srow = lane >> 3, schunk = lane & 7;
  const int scol = ((schunk ^ srow) & 7) * 16;   // XOR swizzle fetch column (128B rows)
  i32x16 acc[2][NJ];
  #pragma unroll
  for (int i=0;i<2;i++)
    #pragma unroll
    for (int j=0;j<NJ;j++)
      #pragma unroll
      for (int r=0;r<16;r++) acc[i][j][r] = 0;
  for (int k0 = 0; k0 < K; k0 += 128){
    #pragma unroll
    for (int i=0;i<4;i++){
      int rr = (i*4 + wv)*8;
      int gm = m0 + rr + srow; if (gm > M-1) gm = M-1;
      gl2lds16(A + (size_t)gm*lda + k0 + scol, &As[rr*128]);
    }
    #pragma unroll
    for (int i=0;i<BN/32;i++){
      int rr = (i*4 + wv)*8;
      gl2lds16(W + (size_t)(n0 + rr + srow)*ldw + k0 + scol, &Bs[rr*128]);
    }
    __syncthreads();
    #pragma unroll
    for (int kq=0; kq<4; kq++){
      i32x4 af[2], bw[NJ];
      #pragma unroll
      for (int i=0;i<2;i++){
        int row = wy*64 + i*32 + l32;
        int cs = (((kq*2 + g) ^ (row & 7))) * 16;
        af[i] = *(const i32x4*)&As[row*128 + cs];
      }
      #pragma unroll
      for (int j=0;j<NJ;j++){
        int row = wx*(BN/2) + j*32 + l32;
        int cs = (((kq*2 + g) ^ (row & 7))) * 16;
        bw[j] = *(const i32x4*)&Bs[row*128 + cs];
      }
      #pragma unroll
      for (int i=0;i<2;i++)
        #pragma unroll
        for (int j=0;j<NJ;j++)
          acc[i][j] = MFMA_I8_32(af[i], bw[j], acc[i][j]);
    }
    __syncthreads();
  }
  #pragma unroll
  for (int j=0;j<NJ;j++){
    int col = n0 + wx*(BN/2) + j*32 + l32;
    float swc = sw[col]; float zwc = (float)zw[col]; float bc = bias[col];
    #pragma unroll
    for (int i=0;i<2;i++)
      #pragma unroll
      for (int r=0;r<16;r++){
        int row = m0 + wy*64 + i*32 + (r&3) + 8*(r>>2) + 4*g;
        if (row < M){
          float v = ((float)acc[i][j][r] - (float)rq[row]*zwc) * (rs[row]*swc) + bc;
          if (do_gelu) v = gelu_t(v);
          if (do_final){
            int bb = row >> 11;
            float ov = xwf[(size_t)row*1152 + col] + modf[((size_t)bb*6+5)*1152 + col]*v;
            ((float*)out)[(size_t)row*ldo + col] = ov;
          } else if (out_f32) ((float*)out)[(size_t)row*ldo + col] = v;
          else                ((u16*)out)[(size_t)row*ldo + col] = f2b(v);
        }
      }
  }
}

// ---------------- self-attention (f16 single planes) ----------------
__global__ __launch_bounds__(256) void attn_self_f16(
    const u16* __restrict__ qkf, const u16* __restrict__ vtf,
    u16* __restrict__ of, float scale){
  constexpr int NT = 16, PSTR = 264, VSTR = 256;
  __shared__ u16 P[4*16*PSTR];
  const int tid = threadIdx.x, lane = tid & 63, wv = tid >> 6;
  const int quad = lane >> 4, l16 = lane & 15;
  const int h = blockIdx.y, z = blockIdx.z;
  const int qbase = z*256 + blockIdx.x*64;
  const u16* Vth = vtf + (size_t)(z*16+h)*80*VSTR;
  const f16v8 zf = __builtin_bit_cast(f16v8, (u16v8)0);
  const int mrow = qbase + wv*16 + l16;

  f16v8 qf[3];
  #pragma unroll
  for (int t=0;t<3;t++){
    if (t==2 && quad!=0){ qf[t]=zf; }
    else qf[t] = ldh8(qkf + (size_t)mrow*2304 + h*72 + t*32 + (t==2?0:quad*8));
  }
  f32x4 sc[NT];
  #pragma unroll
  for (int nt=0; nt<NT; nt++){
    f32x4 a = {0.f,0.f,0.f,0.f};
    #pragma unroll
    for (int t=0;t<3;t++){
      f16v8 kf = zf;
      if (!(t==2 && quad!=0))
        kf = ldh8(qkf + (size_t)(z*256 + nt*16 + l16)*2304 + 1152 + h*72 + t*32 + (t==2?0:quad*8));
      a = MFMA_F16(qf[t], kf, a);
    }
    sc[nt] = a;
  }
  float mx[4] = {-1e30f,-1e30f,-1e30f,-1e30f};
  #pragma unroll
  for (int nt=0; nt<NT; nt++)
    #pragma unroll
    for (int r=0;r<4;r++){ float v = sc[nt][r]*scale; sc[nt][r]=v; mx[r]=fmaxf(mx[r],v); }
  #pragma unroll
  for (int r=0;r<4;r++)
    for (int d=1; d<16; d<<=1) mx[r] = fmaxf(mx[r], __shfl_xor(mx[r], d, 64));
  float sm[4] = {0.f,0.f,0.f,0.f};
  #pragma unroll
  for (int nt=0; nt<NT; nt++)
    #pragma unroll
    for (int r=0;r<4;r++){ float p = __expf(sc[nt][r]-mx[r]); sc[nt][r]=p; sm[r]+=p; }
  #pragma unroll
  for (int r=0;r<4;r++){
    for (int d=1; d<16; d<<=1) sm[r] += __shfl_xor(sm[r], d, 64);
    sm[r] = 1.f/sm[r];
  }
  u16* Pw = P + wv*16*PSTR;
  #pragma unroll
  for (int nt=0; nt<NT; nt++)
    #pragma unroll
    for (int r=0;r<4;r++)
      Pw[(quad*4+r)*PSTR + nt*16 + l16] = f2h(sc[nt][r]*sm[r]);
  const u16* Pr = P + wv*16*PSTR + (size_t)l16*PSTR;
  #pragma unroll
  for (int dt=0; dt<5; dt++){
    f32x4 o = {0.f,0.f,0.f,0.f};
    #pragma unroll
    for (int kk=0; kk<8; kk++){
      f16v8 pv = ldh8(Pr + kk*32 + quad*8);
      f16v8 bv = ldh8(Vth + (size_t)(dt*16+l16)*VSTR + kk*32 + quad*8);
      o = MFMA_F16(pv, bv, o);
    }
    int d = dt*16 + l16;
    if (d < 72){
      #pragma unroll
      for (int r=0;r<4;r++){
        int row = qbase + wv*16 + quad*4 + r;
        of[(size_t)row*1152 + h*72 + d] = f2h(o[r]);
      }
    }
  }
}

// ---------------- cross-attention (f16 q/k/P/V, f32 scores+softmax) ----------------
// R9: EXACT R5 body (proven 82us, VGPR 120, no spill) with ONE parameter change:
// 2 waves/block (128 thr) instead of 4. P is per-wave, so LDS halves to 29184 B
// -> 5 blocks/CU (was 2 at 58368 B). VGPR 120 allows 4 waves/SIMD, so occupancy
// cap moves 8 -> 10 waves/CU with zero register-structure change (R6-R8 lesson:
// any restructure of the score pipeline lands at 140 VGPR or spills).
__global__ __launch_bounds__(128) void attn_cross_f16(
    const float* __restrict__ Q32,
    const u16* __restrict__ Kf,                  // 448x1152 f16
    const u16* __restrict__ Vt,                  // [h][80][448] f16
    float* __restrict__ O, float scale){
  constexpr int NT = 28, PSTR = 456, VSTR = 448;
  __shared__ u16 P[2*16*PSTR];                   // 29,184 B
  const int tid = threadIdx.x, lane = tid & 63, wv = tid >> 6;
  const int quad = lane >> 4, l16 = lane & 15;
  const int h = blockIdx.y;
  const int qbase = blockIdx.x*32;
  const u16* Vth = Vt + (size_t)h*80*VSTR;
  const f16v8 zf = __builtin_bit_cast(f16v8, (u16v8)0);

  const int mrow = qbase + wv*16 + l16;
  const float* qp = Q32 + (size_t)mrow*1152 + h*72;
  f16v8 qf[3];
  #pragma unroll
  for (int t=0;t<3;t++){
    if (t==2 && quad!=0){ qf[t]=zf; continue; }
    u16v8 hv;
    #pragma unroll
    for (int j=0;j<8;j++) hv[j] = f2h(qp[t*32 + (t==2?0:quad*8) + j]);
    qf[t] = __builtin_bit_cast(f16v8, hv);
  }
  f32x4 sc[NT];
  #pragma unroll
  for (int nt=0; nt<NT; nt++){
    f32x4 a = {0.f,0.f,0.f,0.f};
    #pragma unroll
    for (int t=0;t<3;t++){
      f16v8 kf = zf;
      if (!(t==2 && quad!=0))
        kf = ldh8(Kf + (size_t)(nt*16 + l16)*1152 + h*72 + t*32 + (t==2?0:quad*8));
      a = MFMA_F16(qf[t], kf, a);
    }
    sc[nt] = a;
  }
  float mx[4] = {-1e30f,-1e30f,-1e30f,-1e30f};
  #pragma unroll
  for (int nt=0; nt<NT; nt++)
    #pragma unroll
    for (int r=0;r<4;r++){ float v = sc[nt][r]*scale; sc[nt][r]=v; mx[r]=fmaxf(mx[r],v); }
  #pragma unroll
  for (int r=0;r<4;r++)
    for (int d=1; d<16; d<<=1) mx[r] = fmaxf(mx[r], __shfl_xor(mx[r], d, 64));
  float sm[4] = {0.f,0.f,0.f,0.f};
  #pragma unroll
  for (int nt=0; nt<NT; nt++)
    #pragma unroll
    for (int r=0;r<4;r++){ float p = __expf(sc[nt][r]-mx[r]); sc[nt][r]=p; sm[r]+=p; }
  #pragma unroll
  for (int r=0;r<4;r++){
    for (int d=1; d<16; d<<=1) sm[r] += __shfl_xor(sm[r], d, 64);
    sm[r] = 1.f/sm[r];
  }
  u16* Pw = P + wv*16*PSTR;
  #pragma unroll
  for (int nt=0; nt<NT; nt++)
    #pragma unroll
    for (int r=0;r<4;r++)
      Pw[(quad*4+r)*PSTR + nt*16 + l16] = f2h(sc[nt][r]*sm[r]);
  const u16* Pr = P + wv*16*PSTR + (size_t)l16*PSTR;
  #pragma unroll
  for (int dt=0; dt<5; dt++){
    f32x4 o = {0.f,0.f,0.f,0.f};
    #pragma unroll
    for (int kk=0; kk<14; kk++){
      f16v8 pv = ldh8(Pr + kk*32 + quad*8);
      f16v8 bv = ldh8(Vth + (size_t)(dt*16+l16)*VSTR + kk*32 + quad*8);
      o = MFMA_F16(pv, bv, o);
    }
    int d = dt*16 + l16;
    if (d < 72){
      #pragma unroll
      for (int r=0;r<4;r++){
        int row = qbase + wv*16 + quad*4 + r;
        O[(size_t)row*1152 + h*72 + d] = o[r];
      }
    }
  }
}

// ---------------- launch ----------------
extern "C" void kernel_launch(void* const* d_in, const int* in_sizes, int n_in,
                              void* d_out, int out_size, void* d_ws, size_t ws_size,
                              hipStream_t stream){
  const float* x    = (const float*)d_in[0];
  const float* y    = (const float*)d_in[1];
  const float* t    = (const float*)d_in[2];
  const float* sst  = (const float*)d_in[3];
  const float* Wqkv = (const float*)d_in[4];
  const float* bqkv = (const float*)d_in[5];
  const float* Wo   = (const float*)d_in[6];
  const float* bo   = (const float*)d_in[7];
  const float* Wkv  = (const float*)d_in[8];
  const float* bkv  = (const float*)d_in[9];
  const int*   qw_q  = (const int*)d_in[10];
  const float* sw_q  = (const float*)d_in[11];
  const int*   zw_q  = (const int*)d_in[12];
  const float* b_q   = (const float*)d_in[13];
  const int*   qw_cp = (const int*)d_in[14];
  const float* sw_cp = (const float*)d_in[15];
  const int*   zw_cp = (const int*)d_in[16];
  const float* b_cp  = (const float*)d_in[17];
  const int*   qw_f1 = (const int*)d_in[18];
  const float* sw_f1 = (const float*)d_in[19];
  const int*   zw_f1 = (const int*)d_in[20];
  const float* b_f1  = (const float*)d_in[21];
  const int*   qw_f2 = (const int*)d_in[22];
  const float* sw_f2 = (const float*)d_in[23];
  const int*   zw_f2 = (const int*)d_in[24];
  const float* b_f2  = (const float*)d_in[25];
  (void)in_sizes; (void)n_in; (void)out_size;

  constexpr size_t SZR = (size_t)4096*1152*4;        // 18,874,368
  constexpr size_t R0 = 0;                           // xw f32
  constexpr size_t R1 = R0 + SZR;
  constexpr size_t R2 = R1 + SZR;
  constexpr size_t R3 = R2 + SZR;
  constexpr size_t R4 = R3 + SZR;
  constexpr size_t R5 = R4 + (size_t)9437184;
  constexpr size_t R6 = R5 + (size_t)9437184;
  constexpr size_t RS = R6 + (size_t)10485760;
  constexpr size_t RQ = RS + (size_t)4096*4;
  constexpr size_t RM = RQ + (size_t)4096*4;
  constexpr size_t WS_NEED = RM + (size_t)2*6*1152*4;  // ~100.1 MB (proven ws >= 121.8 MB)
  if (ws_size < WS_NEED) return;

  char* ws = (char*)d_ws;
  float*  xw    = (float*)(ws + R0);
  u16*    wqkvh = (u16*)(ws + R1);
  u16*    wqkvl = (u16*)(ws + R1 + (size_t)3456*1152*2);
  u16*    wkvh  = (u16*)(ws + R1);
  u16*    wkvl  = (u16*)(ws + R1 + (size_t)2304*1152*2);
  u16*    yf    = (u16*)(ws + R1 + (size_t)2*2304*1152*2);
  float*  q32   = (float*)(ws + R1);
  float*  cpout = (float*)(ws + R1);
  int8_t* q8h   = (int8_t*)(ws + R1);
  u16*    qkf   = (u16*)(ws + R2);
  float*  aof   = (float*)(ws + R2);
  u16*    hbuf  = (u16*)(ws + R2);
  u16*    xmf   = (u16*)(ws + R4);
  u16*    of    = (u16*)(ws + R4);
  u16*    kf    = (u16*)(ws + R4 + (size_t)4128768);
  u16*    vtc   = (u16*)(ws + R4 + (size_t)6193152);
  int8_t* w8f2  = (int8_t*)(ws + R4);
  int8_t* w8q   = (int8_t*)(ws + R5);
  int8_t* w8cp  = (int8_t*)(ws + R5 + (size_t)1327104);
  int8_t* w8f1  = (int8_t*)(ws + R5 + (size_t)2654208);
  u16*    vtf   = (u16*)(ws + R6);
  u16*    woh   = (u16*)(ws + R6);
  u16*    wol   = (u16*)(ws + R6 + (size_t)1152*1152*2);
  int8_t* q8x   = (int8_t*)(ws + R6);
  float*  rs    = (float*)(ws + RS);
  int*    rq    = (int*)(ws + RQ);
  float*  mod   = (float*)(ws + RM);

  const float scale = 0.11785113019775793f; // 72^-0.5

  static bool attr_set = false;
  if (!attr_set){
    hipFuncSetAttribute(reinterpret_cast<const void*>(gemm_qkv_8ph),
                        hipFuncAttributeMaxDynamicSharedMemorySize, 3*49152);
    attr_set = true;
  }

  mod_add_k<<<(2*6*1152+255)/256,256,0,stream>>>(sst, t, mod);

  // ---- MSA branch (f16 GEMMs) ----
  ln_mod_f16_k<<<4096,256,0,stream>>>(x, xmf, mod, 0, 1);
  split2h_k<<<(3456*1152+255)/256,256,0,stream>>>(Wqkv, wqkvh, wqkvl, 3456*1152);
  gemm_qkv_8ph<<<dim3(224),dim3(512),3*49152,stream>>>(xmf, wqkvh, wqkvl, bqkv, qkf, vtf);
  attn_self_f16<<<dim3(4,16,16),256,0,stream>>>(qkf, vtf, of, scale);
  split2h_k<<<(1152*1152+255)/256,256,0,stream>>>(Wo, woh, wol, 1152*1152);
  gemm_f16k<0><<<dim3(9,32),256,0,stream>>>(of,1152, woh,wol,1152, bo, aof,1152, 4096,1152, nullptr,nullptr);
  rgq_k<<<4096,256,0,stream>>>(x, aof, mod, 2, xw, q8x, rs, rq);

  // ---- cross-attn branch ----
  cross_prep_k<<<(5824512+255)/256,256,0,stream>>>(qw_q,w8q, qw_cp,w8cp, Wkv,wkvh,wkvl, y,yf);
  gemm_f16k<2><<<dim3(18,4),256,0,stream>>>(yf,1152, wkvh,wkvl,1152, bkv, nullptr,0, 448,1152, kf,vtc);
  gemm_i8<64><<<dim3(18,32),256,0,stream>>>(q8x,1152, w8q,1152, rs,rq, sw_q,zw_q,b_q, q32,1152, 4096,1152, 0, 1, nullptr,nullptr,0);
  attn_cross_f16<<<dim3(128,16),128,0,stream>>>(q32, kf, vtc, aof, scale);
  quant_rows_k<1><<<4096,256,0,stream>>>(aof, 1152, q8x, rs, rq);
  gemm_i8<64><<<dim3(18,32),256,0,stream>>>(q8x,1152, w8cp,1152, rs,rq, sw_cp,zw_cp,b_cp, cpout,1152, 4096,1152, 0, 1, nullptr,nullptr,0);

  // ---- MLP branch ----
  rlq_k<<<4096,256,0,stream>>>(xw, cpout, mod, 3, 4, q8x, rs, rq);
  mlp_prep_k<<<(10616832+255)/256,256,0,stream>>>(qw_f1, w8f1, qw_f2, w8f2);
  gemm_i8<128><<<dim3(36,32),256,0,stream>>>(q8x,1152, w8f1,1152, rs,rq, sw_f1,zw_f1,b_f1, hbuf,4608, 4096,1152, 1, 0, nullptr,nullptr,0);
  quant_rows_k<0><<<4096,256,0,stream>>>(hbuf, 4608, q8h, rs, rq);
  gemm_i8<64><<<dim3(18,32),256,0,stream>>>(q8h,4608, w8f2,4608, rs,rq, sw_f2,zw_f2,b_f2, d_out,1152, 4096,4608, 0, 1, xw,mod,1);
}

// Round 10
// 722.141 us; speedup vs baseline: 1.0602x; 1.0118x over previous
//
#include <hip/hip_runtime.h>
#include <stdint.h>

typedef unsigned short u16;
typedef _Float16 f16;
typedef f16    f16v8  __attribute__((ext_vector_type(8)));
typedef u16    u16v8  __attribute__((ext_vector_type(8)));
typedef float  f32x4  __attribute__((ext_vector_type(4)));
typedef int    i32x4  __attribute__((ext_vector_type(4)));
typedef int    i32x16 __attribute__((ext_vector_type(16)));

#define MFMA_F16(a,b,c)   __builtin_amdgcn_mfma_f32_16x16x32_f16((a),(b),(c),0,0,0)
#define MFMA_I8_32(a,b,c) __builtin_amdgcn_mfma_i32_32x32x32_i8((a),(b),(c),0,0,0)

__device__ __forceinline__ float b2f(u16 u){ union{unsigned u;float f;}v; v.u=((unsigned)u)<<16; return v.f; }
__device__ __forceinline__ u16 f2b(float f){ union{float f;unsigned u;}v; v.f=f;
  return (u16)((v.u + 0x7fffu + ((v.u>>16)&1u))>>16); }
__device__ __forceinline__ u16 f2h(float f){ f16 h = (f16)f; return __builtin_bit_cast(u16, h); }
__device__ __forceinline__ float h2f(u16 u){ return (float)__builtin_bit_cast(f16, u); }
__device__ __forceinline__ f16v8 ldh8(const u16* p){ return __builtin_bit_cast(f16v8, *(const u16v8*)p); }
__device__ __forceinline__ void gl2lds16(const void* g, void* l){
  __builtin_amdgcn_global_load_lds(
    (const __attribute__((address_space(1))) unsigned int*)g,
    (__attribute__((address_space(3))) unsigned int*)l,
    16, 0, 0);
}
// gelu(tanh-approx) via sigmoid identity: 0.5x(1+tanh(u)) = x*sigmoid(2u)
__device__ __forceinline__ float gelu_t(float x){
  float u2 = -1.5957691216057308f*(x + 0.044715f*x*x*x);
  return x * __builtin_amdgcn_rcpf(1.f + __expf(u2));
}

// ---------------- elementwise / prep ----------------
__global__ void mod_add_k(const float* __restrict__ sst, const float* __restrict__ t, float* __restrict__ mod){
  int i = blockIdx.x*256 + threadIdx.x;
  if (i < 2*6*1152) mod[i] = sst[i % 6912] + t[i];
}
// f32 -> f16 hi/lo planes (weights)
__global__ void split2h_k(const float* __restrict__ src, u16* __restrict__ hi, u16* __restrict__ lo, int n){
  int i = blockIdx.x*256 + threadIdx.x;
  if (i >= n) return;
  float v = src[i];
  f16 h = (f16)v;
  hi[i] = __builtin_bit_cast(u16, h);
  lo[i] = f2h(v - (float)h);
}
// fused cross-phase prep: conv qw_q, conv qw_cp, split Wkv (f16 hi/lo), y (f16 single)
__global__ void cross_prep_k(const int* __restrict__ qw_q, int8_t* __restrict__ w8q,
                             const int* __restrict__ qw_cp, int8_t* __restrict__ w8cp,
                             const float* __restrict__ Wkv, u16* __restrict__ wkvh, u16* __restrict__ wkvl,
                             const float* __restrict__ y, u16* __restrict__ yf){
  const int S1 = 1327104, S2 = 2654208, S3 = 5308416, S4 = 5824512;
  int i = blockIdx.x*256 + threadIdx.x;
  if (i < S1){ w8q[i] = (int8_t)qw_q[i]; }
  else if (i < S2){ int j = i - S1; w8cp[j] = (int8_t)qw_cp[j]; }
  else if (i < S3){ int j = i - S2; float v = Wkv[j]; f16 h = (f16)v;
    wkvh[j] = __builtin_bit_cast(u16, h); wkvl[j] = f2h(v - (float)h); }
  else if (i < S4){ int j = i - S3; yf[j] = f2h(y[j]); }
}
// fused MLP-phase prep: conv qw_f1, conv qw_f2
__global__ void mlp_prep_k(const int* __restrict__ qw_f1, int8_t* __restrict__ w8f1,
                           const int* __restrict__ qw_f2, int8_t* __restrict__ w8f2){
  const int S1 = 5308416, S2 = 10616832;
  int i = blockIdx.x*256 + threadIdx.x;
  if (i < S1){ w8f1[i] = (int8_t)qw_f1[i]; }
  else if (i < S2){ int j = i - S1; w8f2[j] = (int8_t)qw_f2[j]; }
}
// LN over C=1152 with modulation -> single f16 plane
__global__ void ln_mod_f16_k(const float* __restrict__ src, u16* __restrict__ xf,
                             const float* __restrict__ mod, int shift_row, int scale_row){
  const int row = blockIdx.x, tid = threadIdx.x;
  const int b = row >> 11;
  const float* ms = mod + ((size_t)b*6 + shift_row)*1152;
  const float* mc = mod + ((size_t)b*6 + scale_row)*1152;
  __shared__ float r1[256], r2[256];
  float s = 0.f, sq = 0.f, vals[5]; int cnt = 0;
  for (int c = tid; c < 1152; c += 256){
    float v = src[(size_t)row*1152+c];
    vals[cnt++] = v; s += v; sq += v*v;
  }
  r1[tid]=s; r2[tid]=sq; __syncthreads();
  for (int st=128; st>0; st>>=1){ if (tid<st){ r1[tid]+=r1[tid+st]; r2[tid]+=r2[tid+st]; } __syncthreads(); }
  float mean = r1[0]*(1.f/1152.f);
  float var  = r2[0]*(1.f/1152.f) - mean*mean;
  float rstd = rsqrtf(var + 1e-6f);
  cnt = 0;
  for (int c = tid; c < 1152; c += 256){
    float v = (vals[cnt++]-mean)*rstd*(1.f+mc[c]) + ms[c];
    xf[(size_t)row*1152+c] = f2h(v);
  }
}
// fused: xw = x + gate*ao, then per-row int8 quant of xw
__global__ void rgq_k(const float* __restrict__ x, const float* __restrict__ ao,
                      const float* __restrict__ mod, int gate_row, float* __restrict__ xw,
                      int8_t* __restrict__ q8, float* __restrict__ s_out, int* __restrict__ q_out){
  const int row = blockIdx.x, tid = threadIdx.x;
  const int b = row >> 11;
  const float* mg = mod + ((size_t)b*6 + gate_row)*1152;
  __shared__ float r1[256];
  __shared__ int ri[256];
  float mx = 0.f, vals[5]; int cnt = 0;
  for (int c = tid; c < 1152; c += 256){
    float v = x[(size_t)row*1152+c] + mg[c]*ao[(size_t)row*1152+c];
    xw[(size_t)row*1152+c] = v;
    vals[cnt++] = v; mx = fmaxf(mx, fabsf(v));
  }
  r1[tid]=mx; __syncthreads();
  for (int st=128; st>0; st>>=1){ if (tid<st) r1[tid]=fmaxf(r1[tid],r1[tid+st]); __syncthreads(); }
  const float s_ = fmaxf(r1[0]*(1.f/127.f), 1e-8f);
  const float inv = 1.f/s_;
  int acc = 0; cnt = 0;
  for (int c = tid; c < 1152; c += 256){
    float q = rintf(vals[cnt++]*inv);
    q = fminf(fmaxf(q, -127.f), 127.f);
    q8[(size_t)row*1152+c] = (int8_t)q;
    acc += (int)q;
  }
  ri[tid]=acc; __syncthreads();
  for (int st=128; st>0; st>>=1){ if (tid<st) ri[tid]+=ri[tid+st]; __syncthreads(); }
  if (tid==0){ s_out[row]=s_; q_out[row]=ri[0]; }
}
// fused: xw += add; LN+mod; per-row int8 quant
__global__ void rlq_k(float* __restrict__ xw, const float* __restrict__ add,
                      const float* __restrict__ mod, int shift_row, int scale_row,
                      int8_t* __restrict__ q8, float* __restrict__ s_out, int* __restrict__ q_out){
  const int row = blockIdx.x, tid = threadIdx.x;
  const int b = row >> 11;
  const float* ms = mod + ((size_t)b*6 + shift_row)*1152;
  const float* mc = mod + ((size_t)b*6 + scale_row)*1152;
  __shared__ float r1[256], r2[256];
  __shared__ int ri[256];
  float s = 0.f, sq = 0.f, vals[5]; int cnt = 0;
  for (int c = tid; c < 1152; c += 256){
    float v = xw[(size_t)row*1152+c] + add[(size_t)row*1152+c];
    xw[(size_t)row*1152+c] = v;
    vals[cnt++] = v; s += v; sq += v*v;
  }
  r1[tid]=s; r2[tid]=sq; __syncthreads();
  for (int st=128; st>0; st>>=1){ if (tid<st){ r1[tid]+=r1[tid+st]; r2[tid]+=r2[tid+st]; } __syncthreads(); }
  float mean = r1[0]*(1.f/1152.f);
  float var  = r2[0]*(1.f/1152.f) - mean*mean;
  float rstd = rsqrtf(var + 1e-6f);
  __syncthreads();
  float mx = 0.f; cnt = 0;
  for (int c = tid; c < 1152; c += 256){
    float v = (vals[cnt]-mean)*rstd*(1.f+mc[c]) + ms[c];
    vals[cnt++] = v; mx = fmaxf(mx, fabsf(v));
  }
  r1[tid]=mx; __syncthreads();
  for (int st=128; st>0; st>>=1){ if (tid<st) r1[tid]=fmaxf(r1[tid],r1[tid+st]); __syncthreads(); }
  const float s_ = fmaxf(r1[0]*(1.f/127.f), 1e-8f);
  const float inv = 1.f/s_;
  int acc = 0; cnt = 0;
  for (int c = tid; c < 1152; c += 256){
    float q = rintf(vals[cnt++]*inv);
    q = fminf(fmaxf(q, -127.f), 127.f);
    q8[(size_t)row*1152+c] = (int8_t)q;
    acc += (int)q;
  }
  ri[tid]=acc; __syncthreads();
  for (int st=128; st>0; st>>=1){ if (tid<st) ri[tid]+=ri[tid+st]; __syncthreads(); }
  if (tid==0){ s_out[row]=s_; q_out[row]=ri[0]; }
}
// register-cached row quant (C_ <= 4608)
template<int SRC_F32>
__global__ void quant_rows_k(const void* __restrict__ src, int C_,
                             int8_t* __restrict__ q8, float* __restrict__ s_out, int* __restrict__ q_out){
  const int row = blockIdx.x, tid = threadIdx.x;
  __shared__ float red[256];
  __shared__ int redi[256];
  float vals[18];
  float mx = 0.f; int cnt = 0;
  for (int c = tid; c < C_; c += 256){
    float v = SRC_F32 ? ((const float*)src)[(size_t)row*C_+c] : b2f(((const u16*)src)[(size_t)row*C_+c]);
    vals[cnt++] = v;
    mx = fmaxf(mx, fabsf(v));
  }
  red[tid]=mx; __syncthreads();
  for (int st=128; st>0; st>>=1){ if (tid<st) red[tid]=fmaxf(red[tid],red[tid+st]); __syncthreads(); }
  const float s_ = fmaxf(red[0]*(1.f/127.f), 1e-8f);
  const float inv = 1.f/s_;
  int acc = 0; cnt = 0;
  for (int c = tid; c < C_; c += 256){
    float q = rintf(vals[cnt++]*inv);
    q = fminf(fmaxf(q, -127.f), 127.f);
    q8[(size_t)row*C_+c] = (int8_t)q;
    acc += (int)q;
  }
  redi[tid]=acc; __syncthreads();
  for (int st=128; st>0; st>>=1){ if (tid<st) redi[tid]+=redi[tid+st]; __syncthreads(); }
  if (tid==0){ s_out[row]=s_; q_out[row]=redi[0]; }
}

// ------- f16 GEMM: out[M,N] = f16(A)[M,K] @ (Wh+Wl)[N,K]^T + bias -------
template<int MODE>
__global__ __launch_bounds__(256,4) void gemm_f16k(
    const u16* __restrict__ Af, int lda,
    const u16* __restrict__ Wh, const u16* __restrict__ Wl, int ldw,
    const float* __restrict__ bias, float* __restrict__ out, int ldo, int M, int K,
    u16* __restrict__ e1, u16* __restrict__ e2){
  __shared__ u16 sA[128*32];
  __shared__ u16 sWh[128*32];
  __shared__ u16 sWl[128*32];
  const int tid = threadIdx.x, lane = tid & 63;
  const int wv = tid >> 6, wx = wv & 1, wy = wv >> 1;
  const int quad = lane >> 4, l16 = lane & 15;
  const int m0 = blockIdx.y*128, n0 = blockIdx.x*128;
  f32x4 acc[4][4];
  #pragma unroll
  for (int i=0;i<4;i++)
    #pragma unroll
    for (int j=0;j<4;j++) acc[i][j] = (f32x4){0.f,0.f,0.f,0.f};
  for (int k0=0; k0<K; k0+=32){
    #pragma unroll
    for (int r=0;r<2;r++){
      int slotbase = r*256 + wv*64;        // wave-uniform LDS base (slot*16B)
      int slot = slotbase + lane;
      int row = slot >> 2;                 // 4 chunks of 16B per 32-u16 row
      int col8 = ((slot ^ (row>>1)) & 3) * 8;  // phys chunk = logical ^ ((row>>1)&3)
      int gm = m0 + row; if (gm > M-1) gm = M-1;
      size_t aoff = (size_t)gm*lda + k0 + col8;
      size_t woff = (size_t)(n0+row)*ldw + k0 + col8;
      gl2lds16(Af + aoff, &sA[(size_t)slotbase*8]);
      gl2lds16(Wh + woff, &sWh[(size_t)slotbase*8]);
      gl2lds16(Wl + woff, &sWl[(size_t)slotbase*8]);
    }
    __syncthreads();
    const int cs = ((quad ^ ((l16>>1)&3)) * 8);  // recovers logical chunk = quad
    f16v8 a[4], bh[4], bl[4];
    #pragma unroll
    for (int i=0;i<4;i++) a[i] = ldh8(&sA[(wy*64+i*16+l16)*32 + cs]);
    #pragma unroll
    for (int j=0;j<4;j++){
      bh[j] = ldh8(&sWh[(wx*64+j*16+l16)*32 + cs]);
      bl[j] = ldh8(&sWl[(wx*64+j*16+l16)*32 + cs]);
    }
    #pragma unroll
    for (int i=0;i<4;i++)
      #pragma unroll
      for (int j=0;j<4;j++){
        acc[i][j] = MFMA_F16(a[i], bh[j], acc[i][j]);
        acc[i][j] = MFMA_F16(a[i], bl[j], acc[i][j]);
      }
    __syncthreads();
  }
  #pragma unroll
  for (int j=0;j<4;j++){
    int col = n0 + wx*64 + j*16 + l16;
    float bc = bias ? bias[col] : 0.f;
    #pragma unroll
    for (int i=0;i<4;i++)
      #pragma unroll
      for (int r=0;r<4;r++){
        int row = m0 + wy*64 + i*16 + quad*4 + r;
        if (row >= M) continue;
        float v = acc[i][j][r] + bc;
        if (MODE == 0){
          out[(size_t)row*ldo + col] = v;
        } else if (MODE == 1){
          if (col < 2304){
            e1[(size_t)row*2304 + col] = f2h(v);
          } else {
            int vc = col - 2304;
            int hd_ = vc/72, d = vc - hd_*72;
            int z = row >> 8, s2 = row & 255;
            e2[((size_t)(z*16+hd_)*80 + d)*256 + s2] = f2h(v);
          }
        } else { // MODE 2: KV epilogue (448 rows): k f16 plane + V^T [h][80][448] f16
          if (col < 1152){
            e1[(size_t)row*1152 + col] = f2h(v);
          } else {
            int vc = col - 1152;
            int hd_ = vc/72, d = vc - hd_*72;
            e2[((size_t)hd_*80 + d)*448 + row] = f2h(v);
          }
        }
      }
  }
}

// ------- QKV GEMM: 256x256 tile, 4-phase/K-tile pipelined schedule (T3+T4+T5) -------
#define QKV_NT 36
__global__ __launch_bounds__(512,2) void gemm_qkv_8ph(
    const u16* __restrict__ Af,
    const u16* __restrict__ Wh_, const u16* __restrict__ Wl_,
    const float* __restrict__ bias,
    u16* __restrict__ qkf, u16* __restrict__ vtf){
  extern __shared__ u16 sm[];
  char* smb = (char*)sm;
  const int tid = threadIdx.x, lane = tid & 63, wv = tid >> 6;
  const int wr = wv >> 2, wc = wv & 3;            // 2x4 wave grid
  const int quad = lane >> 4, l16 = lane & 15;
  const int c = blockIdx.x & 7, bi = blockIdx.x >> 3;
  const int m0 = (((c>>1)<<2) + (bi&3)) << 8;     // 16 m-tiles
  const int n0 = ((c&1)*7 + (bi>>2)) << 8;        // 14 n-tiles

  const u16* gA[2]; const u16* gH[2]; const u16* gL[2];
  int sbase[2];
  #pragma unroll
  for (int r=0;r<2;r++){
    int slot = r*512 + tid;
    int row = slot >> 2;
    int col8 = ((slot ^ (row>>1)) & 3) * 8;
    sbase[r] = (r*512 + wv*64) * 16;              // wave-uniform byte base
    gA[r] = Af + (size_t)(m0+row)*1152 + col8;
    int gn = n0 + row; if (gn > 3455) gn = 3455;
    gH[r] = Wh_ + (size_t)gn*1152 + col8;
    gL[r] = Wl_ + (size_t)gn*1152 + col8;
  }

  #define STG_A(t2,b) { size_t ko=(size_t)(t2)*32; \
    gl2lds16(gA[0]+ko, smb + (b)*49152 + sbase[0]); \
    gl2lds16(gA[1]+ko, smb + (b)*49152 + sbase[1]); }
  #define STG_H(t2,b) { size_t ko=(size_t)(t2)*32; \
    gl2lds16(gH[0]+ko, smb + (b)*49152 + 16384 + sbase[0]); \
    gl2lds16(gH[1]+ko, smb + (b)*49152 + 16384 + sbase[1]); }
  #define STG_L(t2,b) { size_t ko=(size_t)(t2)*32; \
    gl2lds16(gL[0]+ko, smb + (b)*49152 + 32768 + sbase[0]); \
    gl2lds16(gL[1]+ko, smb + (b)*49152 + 32768 + sbase[1]); }

  STG_A(0,0); STG_H(0,0); STG_L(0,0);
  STG_A(1,1); STG_H(1,1); STG_L(1,1);

  const int cs = (quad ^ ((l16>>1)&3)) * 8;       // read-side swizzle (logical chunk = quad)
  const int arow = wr*128 + l16;                  // + i*16
  const int wrow = wc*64 + l16;                   // + j*16

  f32x4 acc[8][4];
  #pragma unroll
  for (int i=0;i<8;i++)
    #pragma unroll
    for (int j=0;j<4;j++) acc[i][j] = (f32x4){0.f,0.f,0.f,0.f};

  f16v8 bh[4], bl[4];

  #define PHASE(p, STAGE_STMT) { \
    const u16* bA = sm + cur*24576; \
    f16v8 a0 = ldh8(bA + (arow + (2*(p))*16)*32 + cs); \
    f16v8 a1 = ldh8(bA + (arow + (2*(p)+1)*16)*32 + cs); \
    if ((p)==0){ \
      const u16* bH = bA + 8192; \
      const u16* bL = bA + 16384; \
      _Pragma("unroll") \
      for (int j=0;j<4;j++){ \
        bh[j] = ldh8(bH + (wrow + j*16)*32 + cs); \
        bl[j] = ldh8(bL + (wrow + j*16)*32 + cs); \
      } \
    } \
    STAGE_STMT; \
    __builtin_amdgcn_s_barrier(); \
    asm volatile("s_waitcnt lgkmcnt(0)" ::: "memory"); \
    __builtin_amdgcn_sched_barrier(0); \
    __builtin_amdgcn_s_setprio(1); \
    _Pragma("unroll") \
    for (int j=0;j<4;j++){ \
      acc[2*(p)][j]   = MFMA_F16(a0, bh[j], acc[2*(p)][j]); \
      acc[2*(p)][j]   = MFMA_F16(a0, bl[j], acc[2*(p)][j]); \
      acc[2*(p)+1][j] = MFMA_F16(a1, bh[j], acc[2*(p)+1][j]); \
      acc[2*(p)+1][j] = MFMA_F16(a1, bl[j], acc[2*(p)+1][j]); \
    } \
    __builtin_amdgcn_s_setprio(0); \
    __builtin_amdgcn_s_barrier(); \
  }

  int cur = 0;
  for (int t = 0; t < QKV_NT-1; ++t){
    const int nxt = (cur == 0) ? 2 : cur - 1;     // (t+2)%3
    asm volatile("s_waitcnt vmcnt(6)" ::: "memory");
    __builtin_amdgcn_s_barrier();
    __builtin_amdgcn_sched_barrier(0);
    const bool pf = (t < QKV_NT-2);
    PHASE(0, if (pf) STG_A(t+2,nxt));
    PHASE(1, if (pf) STG_H(t+2,nxt));
    PHASE(2, if (pf) STG_L(t+2,nxt));
    PHASE(3, );
    cur = (cur == 2) ? 0 : cur + 1;
  }
  asm volatile("s_waitcnt vmcnt(0)" ::: "memory");
  __builtin_amdgcn_s_barrier();
  __builtin_amdgcn_sched_barrier(0);
  PHASE(0, );
  PHASE(1, );
  PHASE(2, );
  PHASE(3, );

  #pragma unroll
  for (int j=0;j<4;j++){
    const int col = n0 + wc*64 + j*16 + l16;
    if (col < 3456){
      const float bc = bias[col];
      if (col < 2304){
        #pragma unroll
        for (int i=0;i<8;i++){
          const size_t rb = (size_t)(m0 + wr*128 + i*16 + quad*4)*2304 + col;
          #pragma unroll
          for (int r=0;r<4;r++)
            qkf[rb + (size_t)r*2304] = f2h(acc[i][j][r] + bc);
        }
      } else {
        const int vc = col - 2304;
        const int hd_ = vc/72, d = vc - hd_*72;
        #pragma unroll
        for (int i=0;i<8;i++){
          #pragma unroll
          for (int r=0;r<4;r++){
            const int row = m0 + wr*128 + i*16 + quad*4 + r;
            const int z = row >> 8, s2 = row & 255;
            vtf[((size_t)(z*16+hd_)*80 + d)*256 + s2] = f2h(acc[i][j][r] + bc);
          }
        }
      }
    }
  }
  #undef PHASE
  #undef STG_A
  #undef STG_H
  #undef STG_L
}

// ---------------- int8 GEMM, TLP structure (R3-proven), templated on BN ----------------
template<int BN>
__global__ __launch_bounds__(256,4) void gemm_i8(
    const int8_t* __restrict__ A, int lda, const int8_t* __restrict__ W, int ldw,
    const float* __restrict__ rs, const int* __restrict__ rq,
    const float* __restrict__ sw, const int* __restrict__ zw, const float* __restrict__ bias,
    void* __restrict__ out, int ldo, int M, int K, int do_gelu, int out_f32,
    const float* __restrict__ xwf, const float* __restrict__ modf, int do_final){
  constexpr int NJ = BN/64 ? BN/64 : 1;          // j-tiles (32-wide) per wave: 2 (BN=128) / 1 (BN=64)
  __shared__ int8_t As[128*128];
  __shared__ int8_t Bs[BN*128];
  const int tid = threadIdx.x, lane = tid & 63, wv = tid >> 6;
  const int wx = wv & 1, wy = wv >> 1;
  const int l32 = lane & 31, g = lane >> 5;
  // XCD n-major chunked mapping (bijective when nwg%8==0)
  int n_idx = blockIdx.x, m_idx = blockIdx.y;
  {
    int nwg = gridDim.x*gridDim.y;
    if ((nwg & 7) == 0){
      int l = blockIdx.y*gridDim.x + blockIdx.x;
      int qq = nwg >> 3;
      int gidx = (l & 7)*qq + (l >> 3);
      n_idx = gidx / (int)gridDim.y;
      m_idx = gidx - n_idx*(int)gridDim.y;
    }
  }
  const int m0 = m_idx*128, n0 = n_idx*BN;
  const int srow = lane >> 3, schunk = lane & 7;
  const int scol = ((schunk ^ srow) & 7) * 16;   // XOR swizzle fetch column (128B rows)
  i32x16 acc[2][NJ];
  #pragma unroll
  for (int i=0;i<2;i++)
    #pragma unroll
    for (int j=0;j<NJ;j++)
      #pragma unroll
      for (int r=0;r<16;r++) acc[i][j][r] = 0;
  for (int k0 = 0; k0 < K; k0 += 128){
    #pragma unroll
    for (int i=0;i<4;i++){
      int rr = (i*4 + wv)*8;
      int gm = m0 + rr + srow; if (gm > M-1) gm = M-1;
      gl2lds16(A + (size_t)gm*lda + k0 + scol, &As[rr*128]);
    }
    #pragma unroll
    for (int i=0;i<BN/32;i++){
      int rr = (i*4 + wv)*8;
      gl2lds16(W + (size_t)(n0 + rr + srow)*ldw + k0 + scol, &Bs[rr*128]);
    }
    __syncthreads();
    #pragma unroll
    for (int kq=0; kq<4; kq++){
      i32x4 af[2], bw[NJ];
      #pragma unroll
      for (int i=0;i<2;i++){
        int row = wy*64 + i*32 + l32;
        int cs = (((kq*2 + g) ^ (row & 7))) * 16;
        af[i] = *(const i32x4*)&As[row*128 + cs];
      }
      #pragma unroll
      for (int j=0;j<NJ;j++){
        int row = wx*(BN/2) + j*32 + l32;
        int cs = (((kq*2 + g) ^ (row & 7))) * 16;
        bw[j] = *(const i32x4*)&Bs[row*128 + cs];
      }
      #pragma unroll
      for (int i=0;i<2;i++)
        #pragma unroll
        for (int j=0;j<NJ;j++)
          acc[i][j] = MFMA_I8_32(af[i], bw[j], acc[i][j]);
    }
    __syncthreads();
  }
  #pragma unroll
  for (int j=0;j<NJ;j++){
    int col = n0 + wx*(BN/2) + j*32 + l32;
    float swc = sw[col]; float zwc = (float)zw[col]; float bc = bias[col];
    #pragma unroll
    for (int i=0;i<2;i++)
      #pragma unroll
      for (int r=0;r<16;r++){
        int row = m0 + wy*64 + i*32 + (r&3) + 8*(r>>2) + 4*g;
        if (row < M){
          float v = ((float)acc[i][j][r] - (float)rq[row]*zwc) * (rs[row]*swc) + bc;
          if (do_gelu) v = gelu_t(v);
          if (do_final){
            int bb = row >> 11;
            float ov = xwf[(size_t)row*1152 + col] + modf[((size_t)bb*6+5)*1152 + col]*v;
            ((float*)out)[(size_t)row*ldo + col] = ov;
          } else if (out_f32) ((float*)out)[(size_t)row*ldo + col] = v;
          else                ((u16*)out)[(size_t)row*ldo + col] = f2b(v);
        }
      }
  }
}

// ---------------- self-attention (f16 single planes) ----------------
__global__ __launch_bounds__(256) void attn_self_f16(
    const u16* __restrict__ qkf, const u16* __restrict__ vtf,
    u16* __restrict__ of, float scale){
  constexpr int NT = 16, PSTR = 264, VSTR = 256;
  __shared__ u16 P[4*16*PSTR];
  const int tid = threadIdx.x, lane = tid & 63, wv = tid >> 6;
  const int quad = lane >> 4, l16 = lane & 15;
  const int h = blockIdx.y, z = blockIdx.z;
  const int qbase = z*256 + blockIdx.x*64;
  const u16* Vth = vtf + (size_t)(z*16+h)*80*VSTR;
  const f16v8 zf = __builtin_bit_cast(f16v8, (u16v8)0);
  const int mrow = qbase + wv*16 + l16;

  f16v8 qf[3];
  #pragma unroll
  for (int t=0;t<3;t++){
    if (t==2 && quad!=0){ qf[t]=zf; }
    else qf[t] = ldh8(qkf + (size_t)mrow*2304 + h*72 + t*32 + (t==2?0:quad*8));
  }
  f32x4 sc[NT];
  #pragma unroll
  for (int nt=0; nt<NT; nt++){
    f32x4 a = {0.f,0.f,0.f,0.f};
    #pragma unroll
    for (int t=0;t<3;t++){
      f16v8 kf = zf;
      if (!(t==2 && quad!=0))
        kf = ldh8(qkf + (size_t)(z*256 + nt*16 + l16)*2304 + 1152 + h*72 + t*32 + (t==2?0:quad*8));
      a = MFMA_F16(qf[t], kf, a);
    }
    sc[nt] = a;
  }
  float mx[4] = {-1e30f,-1e30f,-1e30f,-1e30f};
  #pragma unroll
  for (int nt=0; nt<NT; nt++)
    #pragma unroll
    for (int r=0;r<4;r++){ float v = sc[nt][r]*scale; sc[nt][r]=v; mx[r]=fmaxf(mx[r],v); }
  #pragma unroll
  for (int r=0;r<4;r++)
    for (int d=1; d<16; d<<=1) mx[r] = fmaxf(mx[r], __shfl_xor(mx[r], d, 64));
  float sm[4] = {0.f,0.f,0.f,0.f};
  #pragma unroll
  for (int nt=0; nt<NT; nt++)
    #pragma unroll
    for (int r=0;r<4;r++){ float p = __expf(sc[nt][r]-mx[r]); sc[nt][r]=p; sm[r]+=p; }
  #pragma unroll
  for (int r=0;r<4;r++){
    for (int d=1; d<16; d<<=1) sm[r] += __shfl_xor(sm[r], d, 64);
    sm[r] = 1.f/sm[r];
  }
  u16* Pw = P + wv*16*PSTR;
  #pragma unroll
  for (int nt=0; nt<NT; nt++)
    #pragma unroll
    for (int r=0;r<4;r++)
      Pw[(quad*4+r)*PSTR + nt*16 + l16] = f2h(sc[nt][r]*sm[r]);
  const u16* Pr = P + wv*16*PSTR + (size_t)l16*PSTR;
  #pragma unroll
  for (int dt=0; dt<5; dt++){
    f32x4 o = {0.f,0.f,0.f,0.f};
    #pragma unroll
    for (int kk=0; kk<8; kk++){
      f16v8 pv = ldh8(Pr + kk*32 + quad*8);
      f16v8 bv = ldh8(Vth + (size_t)(dt*16+l16)*VSTR + kk*32 + quad*8);
      o = MFMA_F16(pv, bv, o);
    }
    int d = dt*16 + l16;
    if (d < 72){
      #pragma unroll
      for (int r=0;r<4;r++){
        int row = qbase + wv*16 + quad*4 + r;
        of[(size_t)row*1152 + h*72 + d] = f2h(o[r]);
      }
    }
  }
}

// ---------------- cross-attention (f16 q/k/P/V, f32 scores+softmax) ----------------
// R10: R9 body, but K routed through LDS via global_load_lds (register-free loads).
// Theory: QK^T serializes its 84 K-gathers (~520cyc each) because sc[28] pins 112/120
// VGPRs, leaving no room for loads in flight. gl2lds staging issues all loads of a
// 112-row K-quarter back-to-back (no data VGPRs), pays latency ONCE per stage, then
// QK^T reads KS via ds_read (~12cyc). LDS: P 29184 + KS 17920 = 47104 -> 3 blocks/CU.
// PV keeps global V (sc dead there; registers free to pipeline). sc indices static
// (qt,nt unrolled; rule #20). Numerics bit-identical.
__global__ __launch_bounds__(128) void attn_cross_f16(
    const float* __restrict__ Q32,
    const u16* __restrict__ Kf,                  // 448x1152 f16
    const u16* __restrict__ Vt,                  // [h][80][448] f16
    float* __restrict__ O, float scale){
  constexpr int NT = 28, PSTR = 456, VSTR = 448;
  __shared__ u16 P[2*16*PSTR];                   // 29,184 B
  __shared__ u16 KS[112*80];                     // 17,920 B (K quarter, rows padded to 80 u16)
  const int tid = threadIdx.x, lane = tid & 63, wv = tid >> 6;
  const int quad = lane >> 4, l16 = lane & 15;
  const int h = blockIdx.y;
  const int qbase = blockIdx.x*32;
  const u16* Vth = Vt + (size_t)h*80*VSTR;
  const f16v8 zf = __builtin_bit_cast(f16v8, (u16v8)0);

  const int mrow = qbase + wv*16 + l16;
  const float* qp = Q32 + (size_t)mrow*1152 + h*72;
  f16v8 qf[3];
  #pragma unroll
  for (int t=0;t<3;t++){
    if (t==2 && quad!=0){ qf[t]=zf; continue; }
    u16v8 hv;
    #pragma unroll
    for (int j=0;j<8;j++) hv[j] = f2h(qp[t*32 + (t==2?0:quad*8) + j]);
    qf[t] = __builtin_bit_cast(f16v8, hv);
  }
  f32x4 sc[NT];
  #pragma unroll
  for (int qt=0; qt<4; qt++){
    // stage K rows [qt*112, qt*112+112) cols [h*72, h*72+72) -> KS[112][80]
    // (chunk 9 = cols 72..80 staged-but-unread; last rows' tail lands in ws gap, safe)
    #pragma unroll
    for (int i=0;i<9;i++){
      int slot = i*128 + tid;                    // 0..1151
      if (slot < 1120){
        int row = slot/10, c = slot - row*10;
        gl2lds16(Kf + (size_t)(qt*112+row)*1152 + h*72 + c*8, (char*)KS + (size_t)slot*16);
      }
    }
    asm volatile("s_waitcnt vmcnt(0)" ::: "memory");
    __syncthreads();
    #pragma unroll
    for (int nt=0; nt<7; nt++){
      f32x4 a = {0.f,0.f,0.f,0.f};
      #pragma unroll
      for (int t=0;t<3;t++){
        f16v8 kf = zf;
        if (!(t==2 && quad!=0))
          kf = ldh8(&KS[(nt*16 + l16)*80 + t*32 + (t==2?0:quad*8)]);
        a = MFMA_F16(qf[t], kf, a);
      }
      sc[qt*7+nt] = a;
    }
    __syncthreads();   // all reads of KS done before next quarter overwrites
  }
  float mx[4] = {-1e30f,-1e30f,-1e30f,-1e30f};
  #pragma unroll
  for (int nt=0; nt<NT; nt++)
    #pragma unroll
    for (int r=0;r<4;r++){ float v = sc[nt][r]*scale; sc[nt][r]=v; mx[r]=fmaxf(mx[r],v); }
  #pragma unroll
  for (int r=0;r<4;r++)
    for (int d=1; d<16; d<<=1) mx[r] = fmaxf(mx[r], __shfl_xor(mx[r], d, 64));
  float sm[4] = {0.f,0.f,0.f,0.f};
  #pragma unroll
  for (int nt=0; nt<NT; nt++)
    #pragma unroll
    for (int r=0;r<4;r++){ float p = __expf(sc[nt][r]-mx[r]); sc[nt][r]=p; sm[r]+=p; }
  #pragma unroll
  for (int r=0;r<4;r++){
    for (int d=1; d<16; d<<=1) sm[r] += __shfl_xor(sm[r], d, 64);
    sm[r] = 1.f/sm[r];
  }
  u16* Pw = P + wv*16*PSTR;
  #pragma unroll
  for (int nt=0; nt<NT; nt++)
    #pragma unroll
    for (int r=0;r<4;r++)
      Pw[(quad*4+r)*PSTR + nt*16 + l16] = f2h(sc[nt][r]*sm[r]);
  const u16* Pr = P + wv*16*PSTR + (size_t)l16*PSTR;
  #pragma unroll
  for (int dt=0; dt<5; dt++){
    f32x4 o = {0.f,0.f,0.f,0.f};
    #pragma unroll
    for (int kk=0; kk<14; kk++){
      f16v8 pv = ldh8(Pr + kk*32 + quad*8);
      f16v8 bv = ldh8(Vth + (size_t)(dt*16+l16)*VSTR + kk*32 + quad*8);
      o = MFMA_F16(pv, bv, o);
    }
    int d = dt*16 + l16;
    if (d < 72){
      #pragma unroll
      for (int r=0;r<4;r++){
        int row = qbase + wv*16 + quad*4 + r;
        O[(size_t)row*1152 + h*72 + d] = o[r];
      }
    }
  }
}

// ---------------- launch ----------------
extern "C" void kernel_launch(void* const* d_in, const int* in_sizes, int n_in,
                              void* d_out, int out_size, void* d_ws, size_t ws_size,
                              hipStream_t stream){
  const float* x    = (const float*)d_in[0];
  const float* y    = (const float*)d_in[1];
  const float* t    = (const float*)d_in[2];
  const float* sst  = (const float*)d_in[3];
  const float* Wqkv = (const float*)d_in[4];
  const float* bqkv = (const float*)d_in[5];
  const float* Wo   = (const float*)d_in[6];
  const float* bo   = (const float*)d_in[7];
  const float* Wkv  = (const float*)d_in[8];
  const float* bkv  = (const float*)d_in[9];
  const int*   qw_q  = (const int*)d_in[10];
  const float* sw_q  = (const float*)d_in[11];
  const int*   zw_q  = (const int*)d_in[12];
  const float* b_q   = (const float*)d_in[13];
  const int*   qw_cp = (const int*)d_in[14];
  const float* sw_cp = (const float*)d_in[15];
  const int*   zw_cp = (const int*)d_in[16];
  const float* b_cp  = (const float*)d_in[17];
  const int*   qw_f1 = (const int*)d_in[18];
  const float* sw_f1 = (const float*)d_in[19];
  const int*   zw_f1 = (const int*)d_in[20];
  const float* b_f1  = (const float*)d_in[21];
  const int*   qw_f2 = (const int*)d_in[22];
  const float* sw_f2 = (const float*)d_in[23];
  const int*   zw_f2 = (const int*)d_in[24];
  const float* b_f2  = (const float*)d_in[25];
  (void)in_sizes; (void)n_in; (void)out_size;

  constexpr size_t SZR = (size_t)4096*1152*4;        // 18,874,368
  constexpr size_t R0 = 0;                           // xw f32
  constexpr size_t R1 = R0 + SZR;
  constexpr size_t R2 = R1 + SZR;
  constexpr size_t R3 = R2 + SZR;
  constexpr size_t R4 = R3 + SZR;
  constexpr size_t R5 = R4 + (size_t)9437184;
  constexpr size_t R6 = R5 + (size_t)9437184;
  constexpr size_t RS = R6 + (size_t)10485760;
  constexpr size_t RQ = RS + (size_t)4096*4;
  constexpr size_t RM = RQ + (size_t)4096*4;
  constexpr size_t WS_NEED = RM + (size_t)2*6*1152*4;  // ~100.1 MB (proven ws >= 121.8 MB)
  if (ws_size < WS_NEED) return;

  char* ws = (char*)d_ws;
  float*  xw    = (float*)(ws + R0);
  u16*    wqkvh = (u16*)(ws + R1);
  u16*    wqkvl = (u16*)(ws + R1 + (size_t)3456*1152*2);
  u16*    wkvh  = (u16*)(ws + R1);
  u16*    wkvl  = (u16*)(ws + R1 + (size_t)2304*1152*2);
  u16*    yf    = (u16*)(ws + R1 + (size_t)2*2304*1152*2);
  float*  q32   = (float*)(ws + R1);
  float*  cpout = (float*)(ws + R1);
  int8_t* q8h   = (int8_t*)(ws + R1);
  u16*    qkf   = (u16*)(ws + R2);
  float*  aof   = (float*)(ws + R2);
  u16*    hbuf  = (u16*)(ws + R2);
  u16*    xmf   = (u16*)(ws + R4);
  u16*    of    = (u16*)(ws + R4);
  u16*    kf    = (u16*)(ws + R4 + (size_t)4128768);
  u16*    vtc   = (u16*)(ws + R4 + (size_t)6193152);
  int8_t* w8f2  = (int8_t*)(ws + R4);
  int8_t* w8q   = (int8_t*)(ws + R5);
  int8_t* w8cp  = (int8_t*)(ws + R5 + (size_t)1327104);
  int8_t* w8f1  = (int8_t*)(ws + R5 + (size_t)2654208);
  u16*    vtf   = (u16*)(ws + R6);
  u16*    woh   = (u16*)(ws + R6);
  u16*    wol   = (u16*)(ws + R6 + (size_t)1152*1152*2);
  int8_t* q8x   = (int8_t*)(ws + R6);
  float*  rs    = (float*)(ws + RS);
  int*    rq    = (int*)(ws + RQ);
  float*  mod   = (float*)(ws + RM);

  const float scale = 0.11785113019775793f; // 72^-0.5

  static bool attr_set = false;
  if (!attr_set){
    hipFuncSetAttribute(reinterpret_cast<const void*>(gemm_qkv_8ph),
                        hipFuncAttributeMaxDynamicSharedMemorySize, 3*49152);
    attr_set = true;
  }

  mod_add_k<<<(2*6*1152+255)/256,256,0,stream>>>(sst, t, mod);

  // ---- MSA branch (f16 GEMMs) ----
  ln_mod_f16_k<<<4096,256,0,stream>>>(x, xmf, mod, 0, 1);
  split2h_k<<<(3456*1152+255)/256,256,0,stream>>>(Wqkv, wqkvh, wqkvl, 3456*1152);
  gemm_qkv_8ph<<<dim3(224),dim3(512),3*49152,stream>>>(xmf, wqkvh, wqkvl, bqkv, qkf, vtf);
  attn_self_f16<<<dim3(4,16,16),256,0,stream>>>(qkf, vtf, of, scale);
  split2h_k<<<(1152*1152+255)/256,256,0,stream>>>(Wo, woh, wol, 1152*1152);
  gemm_f16k<0><<<dim3(9,32),256,0,stream>>>(of,1152, woh,wol,1152, bo, aof,1152, 4096,1152, nullptr,nullptr);
  rgq_k<<<4096,256,0,stream>>>(x, aof, mod, 2, xw, q8x, rs, rq);

  // ---- cross-attn branch ----
  cross_prep_k<<<(5824512+255)/256,256,0,stream>>>(qw_q,w8q, qw_cp,w8cp, Wkv,wkvh,wkvl, y,yf);
  gemm_f16k<2><<<dim3(18,4),256,0,stream>>>(yf,1152, wkvh,wkvl,1152, bkv, nullptr,0, 448,1152, kf,vtc);
  gemm_i8<64><<<dim3(18,32),256,0,stream>>>(q8x,1152, w8q,1152, rs,rq, sw_q,zw_q,b_q, q32,1152, 4096,1152, 0, 1, nullptr,nullptr,0);
  attn_cross_f16<<<dim3(128,16),128,0,stream>>>(q32, kf, vtc, aof, scale);
  quant_rows_k<1><<<4096,256,0,stream>>>(aof, 1152, q8x, rs, rq);
  gemm_i8<64><<<dim3(18,32),256,0,stream>>>(q8x,1152, w8cp,1152, rs,rq, sw_cp,zw_cp,b_cp, cpout,1152, 4096,1152, 0, 1, nullptr,nullptr,0);

  // ---- MLP branch ----
  rlq_k<<<4096,256,0,stream>>>(xw, cpout, mod, 3, 4, q8x, rs, rq);
  mlp_prep_k<<<(10616832+255)/256,256,0,stream>>>(qw_f1, w8f1, qw_f2, w8f2);
  gemm_i8<128><<<dim3(36,32),256,0,stream>>>(q8x,1152, w8f1,1152, rs,rq, sw_f1,zw_f1,b_f1, hbuf,4608, 4096,1152, 1, 0, nullptr,nullptr,0);
  quant_rows_k<0><<<4096,256,0,stream>>>(hbuf, 4608, q8h, rs, rq);
  gemm_i8<64><<<dim3(18,32),256,0,stream>>>(q8h,4608, w8f2,4608, rs,rq, sw_f2,zw_f2,b_f2, d_out,1152, 4096,4608, 0, 1, xw,mod,1);
}

// Round 11
// 710.024 us; speedup vs baseline: 1.0783x; 1.0171x over previous
//
#include <hip/hip_runtime.h>
#include <stdint.h>

typedef unsigned short u16;
typedef _Float16 f16;
typedef f16    f16v8  __attribute__((ext_vector_type(8)));
typedef u16    u16v8  __attribute__((ext_vector_type(8)));
typedef float  f32x4  __attribute__((ext_vector_type(4)));
typedef int    i32x4  __attribute__((ext_vector_type(4)));
typedef int    i32x16 __attribute__((ext_vector_type(16)));

#define MFMA_F16(a,b,c)   __builtin_amdgcn_mfma_f32_16x16x32_f16((a),(b),(c),0,0,0)
#define MFMA_I8_32(a,b,c) __builtin_amdgcn_mfma_i32_32x32x32_i8((a),(b),(c),0,0,0)

__device__ __forceinline__ float b2f(u16 u){ union{unsigned u;float f;}v; v.u=((unsigned)u)<<16; return v.f; }
__device__ __forceinline__ u16 f2b(float f){ union{float f;unsigned u;}v; v.f=f;
  return (u16)((v.u + 0x7fffu + ((v.u>>16)&1u))>>16); }
__device__ __forceinline__ u16 f2h(float f){ f16 h = (f16)f; return __builtin_bit_cast(u16, h); }
__device__ __forceinline__ float h2f(u16 u){ return (float)__builtin_bit_cast(f16, u); }
__device__ __forceinline__ f16v8 ldh8(const u16* p){ return __builtin_bit_cast(f16v8, *(const u16v8*)p); }
__device__ __forceinline__ void gl2lds16(const void* g, void* l){
  __builtin_amdgcn_global_load_lds(
    (const __attribute__((address_space(1))) unsigned int*)g,
    (__attribute__((address_space(3))) unsigned int*)l,
    16, 0, 0);
}
// gelu(tanh-approx) via sigmoid identity: 0.5x(1+tanh(u)) = x*sigmoid(2u)
__device__ __forceinline__ float gelu_t(float x){
  float u2 = -1.5957691216057308f*(x + 0.044715f*x*x*x);
  return x * __builtin_amdgcn_rcpf(1.f + __expf(u2));
}

// ---------------- elementwise / prep ----------------
__global__ void mod_add_k(const float* __restrict__ sst, const float* __restrict__ t, float* __restrict__ mod){
  int i = blockIdx.x*256 + threadIdx.x;
  if (i < 2*6*1152) mod[i] = sst[i % 6912] + t[i];
}
// f32 -> f16 hi/lo planes (weights)
__global__ void split2h_k(const float* __restrict__ src, u16* __restrict__ hi, u16* __restrict__ lo, int n){
  int i = blockIdx.x*256 + threadIdx.x;
  if (i >= n) return;
  float v = src[i];
  f16 h = (f16)v;
  hi[i] = __builtin_bit_cast(u16, h);
  lo[i] = f2h(v - (float)h);
}
// fused cross-phase prep: conv qw_q, conv qw_cp, split Wkv (f16 hi/lo), y (f16 single)
__global__ void cross_prep_k(const int* __restrict__ qw_q, int8_t* __restrict__ w8q,
                             const int* __restrict__ qw_cp, int8_t* __restrict__ w8cp,
                             const float* __restrict__ Wkv, u16* __restrict__ wkvh, u16* __restrict__ wkvl,
                             const float* __restrict__ y, u16* __restrict__ yf){
  const int S1 = 1327104, S2 = 2654208, S3 = 5308416, S4 = 5824512;
  int i = blockIdx.x*256 + threadIdx.x;
  if (i < S1){ w8q[i] = (int8_t)qw_q[i]; }
  else if (i < S2){ int j = i - S1; w8cp[j] = (int8_t)qw_cp[j]; }
  else if (i < S3){ int j = i - S2; float v = Wkv[j]; f16 h = (f16)v;
    wkvh[j] = __builtin_bit_cast(u16, h); wkvl[j] = f2h(v - (float)h); }
  else if (i < S4){ int j = i - S3; yf[j] = f2h(y[j]); }
}
// fused MLP-phase prep: conv qw_f1, conv qw_f2
__global__ void mlp_prep_k(const int* __restrict__ qw_f1, int8_t* __restrict__ w8f1,
                           const int* __restrict__ qw_f2, int8_t* __restrict__ w8f2){
  const int S1 = 5308416, S2 = 10616832;
  int i = blockIdx.x*256 + threadIdx.x;
  if (i < S1){ w8f1[i] = (int8_t)qw_f1[i]; }
  else if (i < S2){ int j = i - S1; w8f2[j] = (int8_t)qw_f2[j]; }
}
// LN over C=1152 with modulation -> single f16 plane
__global__ void ln_mod_f16_k(const float* __restrict__ src, u16* __restrict__ xf,
                             const float* __restrict__ mod, int shift_row, int scale_row){
  const int row = blockIdx.x, tid = threadIdx.x;
  const int b = row >> 11;
  const float* ms = mod + ((size_t)b*6 + shift_row)*1152;
  const float* mc = mod + ((size_t)b*6 + scale_row)*1152;
  __shared__ float r1[256], r2[256];
  float s = 0.f, sq = 0.f, vals[5]; int cnt = 0;
  for (int c = tid; c < 1152; c += 256){
    float v = src[(size_t)row*1152+c];
    vals[cnt++] = v; s += v; sq += v*v;
  }
  r1[tid]=s; r2[tid]=sq; __syncthreads();
  for (int st=128; st>0; st>>=1){ if (tid<st){ r1[tid]+=r1[tid+st]; r2[tid]+=r2[tid+st]; } __syncthreads(); }
  float mean = r1[0]*(1.f/1152.f);
  float var  = r2[0]*(1.f/1152.f) - mean*mean;
  float rstd = rsqrtf(var + 1e-6f);
  cnt = 0;
  for (int c = tid; c < 1152; c += 256){
    float v = (vals[cnt++]-mean)*rstd*(1.f+mc[c]) + ms[c];
    xf[(size_t)row*1152+c] = f2h(v);
  }
}
// fused: xw = x + gate*ao, then per-row int8 quant of xw
__global__ void rgq_k(const float* __restrict__ x, const float* __restrict__ ao,
                      const float* __restrict__ mod, int gate_row, float* __restrict__ xw,
                      int8_t* __restrict__ q8, float* __restrict__ s_out, int* __restrict__ q_out){
  const int row = blockIdx.x, tid = threadIdx.x;
  const int b = row >> 11;
  const float* mg = mod + ((size_t)b*6 + gate_row)*1152;
  __shared__ float r1[256];
  __shared__ int ri[256];
  float mx = 0.f, vals[5]; int cnt = 0;
  for (int c = tid; c < 1152; c += 256){
    float v = x[(size_t)row*1152+c] + mg[c]*ao[(size_t)row*1152+c];
    xw[(size_t)row*1152+c] = v;
    vals[cnt++] = v; mx = fmaxf(mx, fabsf(v));
  }
  r1[tid]=mx; __syncthreads();
  for (int st=128; st>0; st>>=1){ if (tid<st) r1[tid]=fmaxf(r1[tid],r1[tid+st]); __syncthreads(); }
  const float s_ = fmaxf(r1[0]*(1.f/127.f), 1e-8f);
  const float inv = 1.f/s_;
  int acc = 0; cnt = 0;
  for (int c = tid; c < 1152; c += 256){
    float q = rintf(vals[cnt++]*inv);
    q = fminf(fmaxf(q, -127.f), 127.f);
    q8[(size_t)row*1152+c] = (int8_t)q;
    acc += (int)q;
  }
  ri[tid]=acc; __syncthreads();
  for (int st=128; st>0; st>>=1){ if (tid<st) ri[tid]+=ri[tid+st]; __syncthreads(); }
  if (tid==0){ s_out[row]=s_; q_out[row]=ri[0]; }
}
// fused: xw += add; LN+mod; per-row int8 quant
__global__ void rlq_k(float* __restrict__ xw, const float* __restrict__ add,
                      const float* __restrict__ mod, int shift_row, int scale_row,
                      int8_t* __restrict__ q8, float* __restrict__ s_out, int* __restrict__ q_out){
  const int row = blockIdx.x, tid = threadIdx.x;
  const int b = row >> 11;
  const float* ms = mod + ((size_t)b*6 + shift_row)*1152;
  const float* mc = mod + ((size_t)b*6 + scale_row)*1152;
  __shared__ float r1[256], r2[256];
  __shared__ int ri[256];
  float s = 0.f, sq = 0.f, vals[5]; int cnt = 0;
  for (int c = tid; c < 1152; c += 256){
    float v = xw[(size_t)row*1152+c] + add[(size_t)row*1152+c];
    xw[(size_t)row*1152+c] = v;
    vals[cnt++] = v; s += v; sq += v*v;
  }
  r1[tid]=s; r2[tid]=sq; __syncthreads();
  for (int st=128; st>0; st>>=1){ if (tid<st){ r1[tid]+=r1[tid+st]; r2[tid]+=r2[tid+st]; } __syncthreads(); }
  float mean = r1[0]*(1.f/1152.f);
  float var  = r2[0]*(1.f/1152.f) - mean*mean;
  float rstd = rsqrtf(var + 1e-6f);
  __syncthreads();
  float mx = 0.f; cnt = 0;
  for (int c = tid; c < 1152; c += 256){
    float v = (vals[cnt]-mean)*rstd*(1.f+mc[c]) + ms[c];
    vals[cnt++] = v; mx = fmaxf(mx, fabsf(v));
  }
  r1[tid]=mx; __syncthreads();
  for (int st=128; st>0; st>>=1){ if (tid<st) r1[tid]=fmaxf(r1[tid],r1[tid+st]); __syncthreads(); }
  const float s_ = fmaxf(r1[0]*(1.f/127.f), 1e-8f);
  const float inv = 1.f/s_;
  int acc = 0; cnt = 0;
  for (int c = tid; c < 1152; c += 256){
    float q = rintf(vals[cnt++]*inv);
    q = fminf(fmaxf(q, -127.f), 127.f);
    q8[(size_t)row*1152+c] = (int8_t)q;
    acc += (int)q;
  }
  ri[tid]=acc; __syncthreads();
  for (int st=128; st>0; st>>=1){ if (tid<st) ri[tid]+=ri[tid+st]; __syncthreads(); }
  if (tid==0){ s_out[row]=s_; q_out[row]=ri[0]; }
}
// register-cached row quant (C_ <= 4608)
template<int SRC_F32>
__global__ void quant_rows_k(const void* __restrict__ src, int C_,
                             int8_t* __restrict__ q8, float* __restrict__ s_out, int* __restrict__ q_out){
  const int row = blockIdx.x, tid = threadIdx.x;
  __shared__ float red[256];
  __shared__ int redi[256];
  float vals[18];
  float mx = 0.f; int cnt = 0;
  for (int c = tid; c < C_; c += 256){
    float v = SRC_F32 ? ((const float*)src)[(size_t)row*C_+c] : b2f(((const u16*)src)[(size_t)row*C_+c]);
    vals[cnt++] = v;
    mx = fmaxf(mx, fabsf(v));
  }
  red[tid]=mx; __syncthreads();
  for (int st=128; st>0; st>>=1){ if (tid<st) red[tid]=fmaxf(red[tid],red[tid+st]); __syncthreads(); }
  const float s_ = fmaxf(red[0]*(1.f/127.f), 1e-8f);
  const float inv = 1.f/s_;
  int acc = 0; cnt = 0;
  for (int c = tid; c < C_; c += 256){
    float q = rintf(vals[cnt++]*inv);
    q = fminf(fmaxf(q, -127.f), 127.f);
    q8[(size_t)row*C_+c] = (int8_t)q;
    acc += (int)q;
  }
  redi[tid]=acc; __syncthreads();
  for (int st=128; st>0; st>>=1){ if (tid<st) redi[tid]+=redi[tid+st]; __syncthreads(); }
  if (tid==0){ s_out[row]=s_; q_out[row]=redi[0]; }
}

// ------- f16 GEMM: out[M,N] = f16(A)[M,K] @ (Wh+Wl)[N,K]^T + bias -------
template<int MODE>
__global__ __launch_bounds__(256,4) void gemm_f16k(
    const u16* __restrict__ Af, int lda,
    const u16* __restrict__ Wh, const u16* __restrict__ Wl, int ldw,
    const float* __restrict__ bias, float* __restrict__ out, int ldo, int M, int K,
    u16* __restrict__ e1, u16* __restrict__ e2){
  __shared__ u16 sA[128*32];
  __shared__ u16 sWh[128*32];
  __shared__ u16 sWl[128*32];
  const int tid = threadIdx.x, lane = tid & 63;
  const int wv = tid >> 6, wx = wv & 1, wy = wv >> 1;
  const int quad = lane >> 4, l16 = lane & 15;
  const int m0 = blockIdx.y*128, n0 = blockIdx.x*128;
  f32x4 acc[4][4];
  #pragma unroll
  for (int i=0;i<4;i++)
    #pragma unroll
    for (int j=0;j<4;j++) acc[i][j] = (f32x4){0.f,0.f,0.f,0.f};
  for (int k0=0; k0<K; k0+=32){
    #pragma unroll
    for (int r=0;r<2;r++){
      int slotbase = r*256 + wv*64;        // wave-uniform LDS base (slot*16B)
      int slot = slotbase + lane;
      int row = slot >> 2;                 // 4 chunks of 16B per 32-u16 row
      int col8 = ((slot ^ (row>>1)) & 3) * 8;  // phys chunk = logical ^ ((row>>1)&3)
      int gm = m0 + row; if (gm > M-1) gm = M-1;
      size_t aoff = (size_t)gm*lda + k0 + col8;
      size_t woff = (size_t)(n0+row)*ldw + k0 + col8;
      gl2lds16(Af + aoff, &sA[(size_t)slotbase*8]);
      gl2lds16(Wh + woff, &sWh[(size_t)slotbase*8]);
      gl2lds16(Wl + woff, &sWl[(size_t)slotbase*8]);
    }
    __syncthreads();
    const int cs = ((quad ^ ((l16>>1)&3)) * 8);  // recovers logical chunk = quad
    f16v8 a[4], bh[4], bl[4];
    #pragma unroll
    for (int i=0;i<4;i++) a[i] = ldh8(&sA[(wy*64+i*16+l16)*32 + cs]);
    #pragma unroll
    for (int j=0;j<4;j++){
      bh[j] = ldh8(&sWh[(wx*64+j*16+l16)*32 + cs]);
      bl[j] = ldh8(&sWl[(wx*64+j*16+l16)*32 + cs]);
    }
    #pragma unroll
    for (int i=0;i<4;i++)
      #pragma unroll
      for (int j=0;j<4;j++){
        acc[i][j] = MFMA_F16(a[i], bh[j], acc[i][j]);
        acc[i][j] = MFMA_F16(a[i], bl[j], acc[i][j]);
      }
    __syncthreads();
  }
  #pragma unroll
  for (int j=0;j<4;j++){
    int col = n0 + wx*64 + j*16 + l16;
    float bc = bias ? bias[col] : 0.f;
    #pragma unroll
    for (int i=0;i<4;i++)
      #pragma unroll
      for (int r=0;r<4;r++){
        int row = m0 + wy*64 + i*16 + quad*4 + r;
        if (row >= M) continue;
        float v = acc[i][j][r] + bc;
        if (MODE == 0){
          out[(size_t)row*ldo + col] = v;
        } else if (MODE == 1){
          if (col < 2304){
            e1[(size_t)row*2304 + col] = f2h(v);
          } else {
            int vc = col - 2304;
            int hd_ = vc/72, d = vc - hd_*72;
            int z = row >> 8, s2 = row & 255;
            e2[((size_t)(z*16+hd_)*80 + d)*256 + s2] = f2h(v);
          }
        } else { // MODE 2: KV epilogue (448 rows): k f16 plane + V^T [h][80][448] f16
          if (col < 1152){
            e1[(size_t)row*1152 + col] = f2h(v);
          } else {
            int vc = col - 1152;
            int hd_ = vc/72, d = vc - hd_*72;
            e2[((size_t)hd_*80 + d)*448 + row] = f2h(v);
          }
        }
      }
  }
}

// ------- QKV GEMM: 256x256 tile, 4-phase/K-tile pipelined schedule (T3+T4+T5) -------
#define QKV_NT 36
__global__ __launch_bounds__(512,2) void gemm_qkv_8ph(
    const u16* __restrict__ Af,
    const u16* __restrict__ Wh_, const u16* __restrict__ Wl_,
    const float* __restrict__ bias,
    u16* __restrict__ qkf, u16* __restrict__ vtf){
  extern __shared__ u16 sm[];
  char* smb = (char*)sm;
  const int tid = threadIdx.x, lane = tid & 63, wv = tid >> 6;
  const int wr = wv >> 2, wc = wv & 3;            // 2x4 wave grid
  const int quad = lane >> 4, l16 = lane & 15;
  const int c = blockIdx.x & 7, bi = blockIdx.x >> 3;
  const int m0 = (((c>>1)<<2) + (bi&3)) << 8;     // 16 m-tiles
  const int n0 = ((c&1)*7 + (bi>>2)) << 8;        // 14 n-tiles

  const u16* gA[2]; const u16* gH[2]; const u16* gL[2];
  int sbase[2];
  #pragma unroll
  for (int r=0;r<2;r++){
    int slot = r*512 + tid;
    int row = slot >> 2;
    int col8 = ((slot ^ (row>>1)) & 3) * 8;
    sbase[r] = (r*512 + wv*64) * 16;              // wave-uniform byte base
    gA[r] = Af + (size_t)(m0+row)*1152 + col8;
    int gn = n0 + row; if (gn > 3455) gn = 3455;
    gH[r] = Wh_ + (size_t)gn*1152 + col8;
    gL[r] = Wl_ + (size_t)gn*1152 + col8;
  }

  #define STG_A(t2,b) { size_t ko=(size_t)(t2)*32; \
    gl2lds16(gA[0]+ko, smb + (b)*49152 + sbase[0]); \
    gl2lds16(gA[1]+ko, smb + (b)*49152 + sbase[1]); }
  #define STG_H(t2,b) { size_t ko=(size_t)(t2)*32; \
    gl2lds16(gH[0]+ko, smb + (b)*49152 + 16384 + sbase[0]); \
    gl2lds16(gH[1]+ko, smb + (b)*49152 + 16384 + sbase[1]); }
  #define STG_L(t2,b) { size_t ko=(size_t)(t2)*32; \
    gl2lds16(gL[0]+ko, smb + (b)*49152 + 32768 + sbase[0]); \
    gl2lds16(gL[1]+ko, smb + (b)*49152 + 32768 + sbase[1]); }

  STG_A(0,0); STG_H(0,0); STG_L(0,0);
  STG_A(1,1); STG_H(1,1); STG_L(1,1);

  const int cs = (quad ^ ((l16>>1)&3)) * 8;       // read-side swizzle (logical chunk = quad)
  const int arow = wr*128 + l16;                  // + i*16
  const int wrow = wc*64 + l16;                   // + j*16

  f32x4 acc[8][4];
  #pragma unroll
  for (int i=0;i<8;i++)
    #pragma unroll
    for (int j=0;j<4;j++) acc[i][j] = (f32x4){0.f,0.f,0.f,0.f};

  f16v8 bh[4], bl[4];

  #define PHASE(p, STAGE_STMT) { \
    const u16* bA = sm + cur*24576; \
    f16v8 a0 = ldh8(bA + (arow + (2*(p))*16)*32 + cs); \
    f16v8 a1 = ldh8(bA + (arow + (2*(p)+1)*16)*32 + cs); \
    if ((p)==0){ \
      const u16* bH = bA + 8192; \
      const u16* bL = bA + 16384; \
      _Pragma("unroll") \
      for (int j=0;j<4;j++){ \
        bh[j] = ldh8(bH + (wrow + j*16)*32 + cs); \
        bl[j] = ldh8(bL + (wrow + j*16)*32 + cs); \
      } \
    } \
    STAGE_STMT; \
    __builtin_amdgcn_s_barrier(); \
    asm volatile("s_waitcnt lgkmcnt(0)" ::: "memory"); \
    __builtin_amdgcn_sched_barrier(0); \
    __builtin_amdgcn_s_setprio(1); \
    _Pragma("unroll") \
    for (int j=0;j<4;j++){ \
      acc[2*(p)][j]   = MFMA_F16(a0, bh[j], acc[2*(p)][j]); \
      acc[2*(p)][j]   = MFMA_F16(a0, bl[j], acc[2*(p)][j]); \
      acc[2*(p)+1][j] = MFMA_F16(a1, bh[j], acc[2*(p)+1][j]); \
      acc[2*(p)+1][j] = MFMA_F16(a1, bl[j], acc[2*(p)+1][j]); \
    } \
    __builtin_amdgcn_s_setprio(0); \
    __builtin_amdgcn_s_barrier(); \
  }

  int cur = 0;
  for (int t = 0; t < QKV_NT-1; ++t){
    const int nxt = (cur == 0) ? 2 : cur - 1;     // (t+2)%3
    asm volatile("s_waitcnt vmcnt(6)" ::: "memory");
    __builtin_amdgcn_s_barrier();
    __builtin_amdgcn_sched_barrier(0);
    const bool pf = (t < QKV_NT-2);
    PHASE(0, if (pf) STG_A(t+2,nxt));
    PHASE(1, if (pf) STG_H(t+2,nxt));
    PHASE(2, if (pf) STG_L(t+2,nxt));
    PHASE(3, );
    cur = (cur == 2) ? 0 : cur + 1;
  }
  asm volatile("s_waitcnt vmcnt(0)" ::: "memory");
  __builtin_amdgcn_s_barrier();
  __builtin_amdgcn_sched_barrier(0);
  PHASE(0, );
  PHASE(1, );
  PHASE(2, );
  PHASE(3, );

  #pragma unroll
  for (int j=0;j<4;j++){
    const int col = n0 + wc*64 + j*16 + l16;
    if (col < 3456){
      const float bc = bias[col];
      if (col < 2304){
        #pragma unroll
        for (int i=0;i<8;i++){
          const size_t rb = (size_t)(m0 + wr*128 + i*16 + quad*4)*2304 + col;
          #pragma unroll
          for (int r=0;r<4;r++)
            qkf[rb + (size_t)r*2304] = f2h(acc[i][j][r] + bc);
        }
      } else {
        const int vc = col - 2304;
        const int hd_ = vc/72, d = vc - hd_*72;
        #pragma unroll
        for (int i=0;i<8;i++){
          #pragma unroll
          for (int r=0;r<4;r++){
            const int row = m0 + wr*128 + i*16 + quad*4 + r;
            const int z = row >> 8, s2 = row & 255;
            vtf[((size_t)(z*16+hd_)*80 + d)*256 + s2] = f2h(acc[i][j][r] + bc);
          }
        }
      }
    }
  }
  #undef PHASE
  #undef STG_A
  #undef STG_H
  #undef STG_L
}

// ---------------- int8 GEMM, TLP structure (R3/R5-proven), BN=64 everywhere ----------------
// R11: f1 switched BN=128 -> BN=64 (grid 36x32 -> 72x32 = 2304 blocks; same proven
// codepath as q/cp/f2) and launch_bounds (256,4) -> (256,6): VGPR=60 and 24KB LDS
// admit 6 blocks/CU = 24 waves/CU. i8 K-steps are latency-bound (128cy compute vs
// ~600cy load); TLP is the proven lever (R5 win, R2/R4 pipelining losses).
template<int BN>
__global__ __launch_bounds__(256,6) void gemm_i8(
    const int8_t* __restrict__ A, int lda, const int8_t* __restrict__ W, int ldw,
    const float* __restrict__ rs, const int* __restrict__ rq,
    const float* __restrict__ sw, const int* __restrict__ zw, const float* __restrict__ bias,
    void* __restrict__ out, int ldo, int M, int K, int do_gelu, int out_f32,
    const float* __restrict__ xwf, const float* __restrict__ modf, int do_final){
  constexpr int NJ = BN/64 ? BN/64 : 1;          // j-tiles (32-wide) per wave
  __shared__ int8_t As[128*128];
  __shared__ int8_t Bs[BN*128];
  const int tid = threadIdx.x, lane = tid & 63, wv = tid >> 6;
  const int wx = wv & 1, wy = wv >> 1;
  const int l32 = lane & 31, g = lane >> 5;
  // XCD n-major chunked mapping (bijective when nwg%8==0)
  int n_idx = blockIdx.x, m_idx = blockIdx.y;
  {
    int nwg = gridDim.x*gridDim.y;
    if ((nwg & 7) == 0){
      int l = blockIdx.y*gridDim.x + blockIdx.x;
      int qq = nwg >> 3;
      int gidx = (l & 7)*qq + (l >> 3);
      n_idx = gidx / (int)gridDim.y;
      m_idx = gidx - n_idx*(int)gridDim.y;
    }
  }
  const int m0 = m_idx*128, n0 = n_idx*BN;
  const int srow = lane >> 3, schunk = lane & 7;
  const int scol = ((schunk ^ srow) & 7) * 16;   // XOR swizzle fetch column (128B rows)
  i32x16 acc[2][NJ];
  #pragma unroll
  for (int i=0;i<2;i++)
    #pragma unroll
    for (int j=0;j<NJ;j++)
      #pragma unroll
      for (int r=0;r<16;r++) acc[i][j][r] = 0;
  for (int k0 = 0; k0 < K; k0 += 128){
    #pragma unroll
    for (int i=0;i<4;i++){
      int rr = (i*4 + wv)*8;
      int gm = m0 + rr + srow; if (gm > M-1) gm = M-1;
      gl2lds16(A + (size_t)gm*lda + k0 + scol, &As[rr*128]);
    }
    #pragma unroll
    for (int i=0;i<BN/32;i++){
      int rr = (i*4 + wv)*8;
      gl2lds16(W + (size_t)(n0 + rr + srow)*ldw + k0 + scol, &Bs[rr*128]);
    }
    __syncthreads();
    #pragma unroll
    for (int kq=0; kq<4; kq++){
      i32x4 af[2], bw[NJ];
      #pragma unroll
      for (int i=0;i<2;i++){
        int row = wy*64 + i*32 + l32;
        int cs = (((kq*2 + g) ^ (row & 7))) * 16;
        af[i] = *(const i32x4*)&As[row*128 + cs];
      }
      #pragma unroll
      for (int j=0;j<NJ;j++){
        int row = wx*(BN/2) + j*32 + l32;
        int cs = (((kq*2 + g) ^ (row & 7))) * 16;
        bw[j] = *(const i32x4*)&Bs[row*128 + cs];
      }
      #pragma unroll
      for (int i=0;i<2;i++)
        #pragma unroll
        for (int j=0;j<NJ;j++)
          acc[i][j] = MFMA_I8_32(af[i], bw[j], acc[i][j]);
    }
    __syncthreads();
  }
  #pragma unroll
  for (int j=0;j<NJ;j++){
    int col = n0 + wx*(BN/2) + j*32 + l32;
    float swc = sw[col]; float zwc = (float)zw[col]; float bc = bias[col];
    #pragma unroll
    for (int i=0;i<2;i++)
      #pragma unroll
      for (int r=0;r<16;r++){
        int row = m0 + wy*64 + i*32 + (r&3) + 8*(r>>2) + 4*g;
        if (row < M){
          float v = ((float)acc[i][j][r] - (float)rq[row]*zwc) * (rs[row]*swc) + bc;
          if (do_gelu) v = gelu_t(v);
          if (do_final){
            int bb = row >> 11;
            float ov = xwf[(size_t)row*1152 + col] + modf[((size_t)bb*6+5)*1152 + col]*v;
            ((float*)out)[(size_t)row*ldo + col] = ov;
          } else if (out_f32) ((float*)out)[(size_t)row*ldo + col] = v;
          else                ((u16*)out)[(size_t)row*ldo + col] = f2b(v);
        }
      }
  }
}

// ---------------- self-attention (f16 single planes) ----------------
__global__ __launch_bounds__(256) void attn_self_f16(
    const u16* __restrict__ qkf, const u16* __restrict__ vtf,
    u16* __restrict__ of, float scale){
  constexpr int NT = 16, PSTR = 264, VSTR = 256;
  __shared__ u16 P[4*16*PSTR];
  const int tid = threadIdx.x, lane = tid & 63, wv = tid >> 6;
  const int quad = lane >> 4, l16 = lane & 15;
  const int h = blockIdx.y, z = blockIdx.z;
  const int qbase = z*256 + blockIdx.x*64;
  const u16* Vth = vtf + (size_t)(z*16+h)*80*VSTR;
  const f16v8 zf = __builtin_bit_cast(f16v8, (u16v8)0);
  const int mrow = qbase + wv*16 + l16;

  f16v8 qf[3];
  #pragma unroll
  for (int t=0;t<3;t++){
    if (t==2 && quad!=0){ qf[t]=zf; }
    else qf[t] = ldh8(qkf + (size_t)mrow*2304 + h*72 + t*32 + (t==2?0:quad*8));
  }
  f32x4 sc[NT];
  #pragma unroll
  for (int nt=0; nt<NT; nt++){
    f32x4 a = {0.f,0.f,0.f,0.f};
    #pragma unroll
    for (int t=0;t<3;t++){
      f16v8 kf = zf;
      if (!(t==2 && quad!=0))
        kf = ldh8(qkf + (size_t)(z*256 + nt*16 + l16)*2304 + 1152 + h*72 + t*32 + (t==2?0:quad*8));
      a = MFMA_F16(qf[t], kf, a);
    }
    sc[nt] = a;
  }
  float mx[4] = {-1e30f,-1e30f,-1e30f,-1e30f};
  #pragma unroll
  for (int nt=0; nt<NT; nt++)
    #pragma unroll
    for (int r=0;r<4;r++){ float v = sc[nt][r]*scale; sc[nt][r]=v; mx[r]=fmaxf(mx[r],v); }
  #pragma unroll
  for (int r=0;r<4;r++)
    for (int d=1; d<16; d<<=1) mx[r] = fmaxf(mx[r], __shfl_xor(mx[r], d, 64));
  float sm[4] = {0.f,0.f,0.f,0.f};
  #pragma unroll
  for (int nt=0; nt<NT; nt++)
    #pragma unroll
    for (int r=0;r<4;r++){ float p = __expf(sc[nt][r]-mx[r]); sc[nt][r]=p; sm[r]+=p; }
  #pragma unroll
  for (int r=0;r<4;r++){
    for (int d=1; d<16; d<<=1) sm[r] += __shfl_xor(sm[r], d, 64);
    sm[r] = 1.f/sm[r];
  }
  u16* Pw = P + wv*16*PSTR;
  #pragma unroll
  for (int nt=0; nt<NT; nt++)
    #pragma unroll
    for (int r=0;r<4;r++)
      Pw[(quad*4+r)*PSTR + nt*16 + l16] = f2h(sc[nt][r]*sm[r]);
  const u16* Pr = P + wv*16*PSTR + (size_t)l16*PSTR;
  #pragma unroll
  for (int dt=0; dt<5; dt++){
    f32x4 o = {0.f,0.f,0.f,0.f};
    #pragma unroll
    for (int kk=0; kk<8; kk++){
      f16v8 pv = ldh8(Pr + kk*32 + quad*8);
      f16v8 bv = ldh8(Vth + (size_t)(dt*16+l16)*VSTR + kk*32 + quad*8);
      o = MFMA_F16(pv, bv, o);
    }
    int d = dt*16 + l16;
    if (d < 72){
      #pragma unroll
      for (int r=0;r<4;r++){
        int row = qbase + wv*16 + quad*4 + r;
        of[(size_t)row*1152 + h*72 + d] = f2h(o[r]);
      }
    }
  }
}

// ---------------- cross-attention (f16 q/k/P/V, f32 scores+softmax) ----------------
// R10-proven: K staged through LDS via global_load_lds (register-free loads); QK^T
// reads KS via ds_read. 2 waves/block; LDS P 29184 + KS 17920 = 47104 B.
__global__ __launch_bounds__(128) void attn_cross_f16(
    const float* __restrict__ Q32,
    const u16* __restrict__ Kf,                  // 448x1152 f16
    const u16* __restrict__ Vt,                  // [h][80][448] f16
    float* __restrict__ O, float scale){
  constexpr int NT = 28, PSTR = 456, VSTR = 448;
  __shared__ u16 P[2*16*PSTR];                   // 29,184 B
  __shared__ u16 KS[112*80];                     // 17,920 B (K quarter, rows padded to 80 u16)
  const int tid = threadIdx.x, lane = tid & 63, wv = tid >> 6;
  const int quad = lane >> 4, l16 = lane & 15;
  const int h = blockIdx.y;
  const int qbase = blockIdx.x*32;
  const u16* Vth = Vt + (size_t)h*80*VSTR;
  const f16v8 zf = __builtin_bit_cast(f16v8, (u16v8)0);

  const int mrow = qbase + wv*16 + l16;
  const float* qp = Q32 + (size_t)mrow*1152 + h*72;
  f16v8 qf[3];
  #pragma unroll
  for (int t=0;t<3;t++){
    if (t==2 && quad!=0){ qf[t]=zf; continue; }
    u16v8 hv;
    #pragma unroll
    for (int j=0;j<8;j++) hv[j] = f2h(qp[t*32 + (t==2?0:quad*8) + j]);
    qf[t] = __builtin_bit_cast(f16v8, hv);
  }
  f32x4 sc[NT];
  #pragma unroll
  for (int qt=0; qt<4; qt++){
    #pragma unroll
    for (int i=0;i<9;i++){
      int slot = i*128 + tid;                    // 0..1151
      if (slot < 1120){
        int row = slot/10, c = slot - row*10;
        gl2lds16(Kf + (size_t)(qt*112+row)*1152 + h*72 + c*8, (char*)KS + (size_t)slot*16);
      }
    }
    asm volatile("s_waitcnt vmcnt(0)" ::: "memory");
    __syncthreads();
    #pragma unroll
    for (int nt=0; nt<7; nt++){
      f32x4 a = {0.f,0.f,0.f,0.f};
      #pragma unroll
      for (int t=0;t<3;t++){
        f16v8 kf = zf;
        if (!(t==2 && quad!=0))
          kf = ldh8(&KS[(nt*16 + l16)*80 + t*32 + (t==2?0:quad*8)]);
        a = MFMA_F16(qf[t], kf, a);
      }
      sc[qt*7+nt] = a;
    }
    __syncthreads();   // all reads of KS done before next quarter overwrites
  }
  float mx[4] = {-1e30f,-1e30f,-1e30f,-1e30f};
  #pragma unroll
  for (int nt=0; nt<NT; nt++)
    #pragma unroll
    for (int r=0;r<4;r++){ float v = sc[nt][r]*scale; sc[nt][r]=v; mx[r]=fmaxf(mx[r],v); }
  #pragma unroll
  for (int r=0;r<4;r++)
    for (int d=1; d<16; d<<=1) mx[r] = fmaxf(mx[r], __shfl_xor(mx[r], d, 64));
  float sm[4] = {0.f,0.f,0.f,0.f};
  #pragma unroll
  for (int nt=0; nt<NT; nt++)
    #pragma unroll
    for (int r=0;r<4;r++){ float p = __expf(sc[nt][r]-mx[r]); sc[nt][r]=p; sm[r]+=p; }
  #pragma unroll
  for (int r=0;r<4;r++){
    for (int d=1; d<16; d<<=1) sm[r] += __shfl_xor(sm[r], d, 64);
    sm[r] = 1.f/sm[r];
  }
  u16* Pw = P + wv*16*PSTR;
  #pragma unroll
  for (int nt=0; nt<NT; nt++)
    #pragma unroll
    for (int r=0;r<4;r++)
      Pw[(quad*4+r)*PSTR + nt*16 + l16] = f2h(sc[nt][r]*sm[r]);
  const u16* Pr = P + wv*16*PSTR + (size_t)l16*PSTR;
  #pragma unroll
  for (int dt=0; dt<5; dt++){
    f32x4 o = {0.f,0.f,0.f,0.f};
    #pragma unroll
    for (int kk=0; kk<14; kk++){
      f16v8 pv = ldh8(Pr + kk*32 + quad*8);
      f16v8 bv = ldh8(Vth + (size_t)(dt*16+l16)*VSTR + kk*32 + quad*8);
      o = MFMA_F16(pv, bv, o);
    }
    int d = dt*16 + l16;
    if (d < 72){
      #pragma unroll
      for (int r=0;r<4;r++){
        int row = qbase + wv*16 + quad*4 + r;
        O[(size_t)row*1152 + h*72 + d] = o[r];
      }
    }
  }
}

// ---------------- launch ----------------
extern "C" void kernel_launch(void* const* d_in, const int* in_sizes, int n_in,
                              void* d_out, int out_size, void* d_ws, size_t ws_size,
                              hipStream_t stream){
  const float* x    = (const float*)d_in[0];
  const float* y    = (const float*)d_in[1];
  const float* t    = (const float*)d_in[2];
  const float* sst  = (const float*)d_in[3];
  const float* Wqkv = (const float*)d_in[4];
  const float* bqkv = (const float*)d_in[5];
  const float* Wo   = (const float*)d_in[6];
  const float* bo   = (const float*)d_in[7];
  const float* Wkv  = (const float*)d_in[8];
  const float* bkv  = (const float*)d_in[9];
  const int*   qw_q  = (const int*)d_in[10];
  const float* sw_q  = (const float*)d_in[11];
  const int*   zw_q  = (const int*)d_in[12];
  const float* b_q   = (const float*)d_in[13];
  const int*   qw_cp = (const int*)d_in[14];
  const float* sw_cp = (const float*)d_in[15];
  const int*   zw_cp = (const int*)d_in[16];
  const float* b_cp  = (const float*)d_in[17];
  const int*   qw_f1 = (const int*)d_in[18];
  const float* sw_f1 = (const float*)d_in[19];
  const int*   zw_f1 = (const int*)d_in[20];
  const float* b_f1  = (const float*)d_in[21];
  const int*   qw_f2 = (const int*)d_in[22];
  const float* sw_f2 = (const float*)d_in[23];
  const int*   zw_f2 = (const int*)d_in[24];
  const float* b_f2  = (const float*)d_in[25];
  (void)in_sizes; (void)n_in; (void)out_size;

  constexpr size_t SZR = (size_t)4096*1152*4;        // 18,874,368
  constexpr size_t R0 = 0;                           // xw f32
  constexpr size_t R1 = R0 + SZR;
  constexpr size_t R2 = R1 + SZR;
  constexpr size_t R3 = R2 + SZR;
  constexpr size_t R4 = R3 + SZR;
  constexpr size_t R5 = R4 + (size_t)9437184;
  constexpr size_t R6 = R5 + (size_t)9437184;
  constexpr size_t RS = R6 + (size_t)10485760;
  constexpr size_t RQ = RS + (size_t)4096*4;
  constexpr size_t RM = RQ + (size_t)4096*4;
  constexpr size_t WS_NEED = RM + (size_t)2*6*1152*4;  // ~100.1 MB (proven ws >= 121.8 MB)
  if (ws_size < WS_NEED) return;

  char* ws = (char*)d_ws;
  float*  xw    = (float*)(ws + R0);
  u16*    wqkvh = (u16*)(ws + R1);
  u16*    wqkvl = (u16*)(ws + R1 + (size_t)3456*1152*2);
  u16*    wkvh  = (u16*)(ws + R1);
  u16*    wkvl  = (u16*)(ws + R1 + (size_t)2304*1152*2);
  u16*    yf    = (u16*)(ws + R1 + (size_t)2*2304*1152*2);
  float*  q32   = (float*)(ws + R1);
  float*  cpout = (float*)(ws + R1);
  int8_t* q8h   = (int8_t*)(ws + R1);
  u16*    qkf   = (u16*)(ws + R2);
  float*  aof   = (float*)(ws + R2);
  u16*    hbuf  = (u16*)(ws + R2);
  u16*    xmf   = (u16*)(ws + R4);
  u16*    of    = (u16*)(ws + R4);
  u16*    kf    = (u16*)(ws + R4 + (size_t)4128768);
  u16*    vtc   = (u16*)(ws + R4 + (size_t)6193152);
  int8_t* w8f2  = (int8_t*)(ws + R4);
  int8_t* w8q   = (int8_t*)(ws + R5);
  int8_t* w8cp  = (int8_t*)(ws + R5 + (size_t)1327104);
  int8_t* w8f1  = (int8_t*)(ws + R5 + (size_t)2654208);
  u16*    vtf   = (u16*)(ws + R6);
  u16*    woh   = (u16*)(ws + R6);
  u16*    wol   = (u16*)(ws + R6 + (size_t)1152*1152*2);
  int8_t* q8x   = (int8_t*)(ws + R6);
  float*  rs    = (float*)(ws + RS);
  int*    rq    = (int*)(ws + RQ);
  float*  mod   = (float*)(ws + RM);

  const float scale = 0.11785113019775793f; // 72^-0.5

  static bool attr_set = false;
  if (!attr_set){
    hipFuncSetAttribute(reinterpret_cast<const void*>(gemm_qkv_8ph),
                        hipFuncAttributeMaxDynamicSharedMemorySize, 3*49152);
    attr_set = true;
  }

  mod_add_k<<<(2*6*1152+255)/256,256,0,stream>>>(sst, t, mod);

  // ---- MSA branch (f16 GEMMs) ----
  ln_mod_f16_k<<<4096,256,0,stream>>>(x, xmf, mod, 0, 1);
  split2h_k<<<(3456*1152+255)/256,256,0,stream>>>(Wqkv, wqkvh, wqkvl, 3456*1152);
  gemm_qkv_8ph<<<dim3(224),dim3(512),3*49152,stream>>>(xmf, wqkvh, wqkvl, bqkv, qkf, vtf);
  attn_self_f16<<<dim3(4,16,16),256,0,stream>>>(qkf, vtf, of, scale);
  split2h_k<<<(1152*1152+255)/256,256,0,stream>>>(Wo, woh, wol, 1152*1152);
  gemm_f16k<0><<<dim3(9,32),256,0,stream>>>(of,1152, woh,wol,1152, bo, aof,1152, 4096,1152, nullptr,nullptr);
  rgq_k<<<4096,256,0,stream>>>(x, aof, mod, 2, xw, q8x, rs, rq);

  // ---- cross-attn branch ----
  cross_prep_k<<<(5824512+255)/256,256,0,stream>>>(qw_q,w8q, qw_cp,w8cp, Wkv,wkvh,wkvl, y,yf);
  gemm_f16k<2><<<dim3(18,4),256,0,stream>>>(yf,1152, wkvh,wkvl,1152, bkv, nullptr,0, 448,1152, kf,vtc);
  gemm_i8<64><<<dim3(18,32),256,0,stream>>>(q8x,1152, w8q,1152, rs,rq, sw_q,zw_q,b_q, q32,1152, 4096,1152, 0, 1, nullptr,nullptr,0);
  attn_cross_f16<<<dim3(128,16),128,0,stream>>>(q32, kf, vtc, aof, scale);
  quant_rows_k<1><<<4096,256,0,stream>>>(aof, 1152, q8x, rs, rq);
  gemm_i8<64><<<dim3(18,32),256,0,stream>>>(q8x,1152, w8cp,1152, rs,rq, sw_cp,zw_cp,b_cp, cpout,1152, 4096,1152, 0, 1, nullptr,nullptr,0);

  // ---- MLP branch ----
  rlq_k<<<4096,256,0,stream>>>(xw, cpout, mod, 3, 4, q8x, rs, rq);
  mlp_prep_k<<<(10616832+255)/256,256,0,stream>>>(qw_f1, w8f1, qw_f2, w8f2);
  gemm_i8<64><<<dim3(72,32),256,0,stream>>>(q8x,1152, w8f1,1152, rs,rq, sw_f1,zw_f1,b_f1, hbuf,4608, 4096,1152, 1, 0, nullptr,nullptr,0);
  quant_rows_k<0><<<4096,256,0,stream>>>(hbuf, 4608, q8h, rs, rq);
  gemm_i8<64><<<dim3(18,32),256,0,stream>>>(q8h,4608, w8f2,4608, rs,rq, sw_f2,zw_f2,b_f2, d_out,1152, 4096,4608, 0, 1, xw,mod,1);
}

// Round 12
// 690.782 us; speedup vs baseline: 1.1084x; 1.0279x over previous
//
#include <hip/hip_runtime.h>
#include <stdint.h>

typedef unsigned short u16;
typedef _Float16 f16;
typedef f16    f16v8  __attribute__((ext_vector_type(8)));
typedef u16    u16v8  __attribute__((ext_vector_type(8)));
typedef u16    u16v4  __attribute__((ext_vector_type(4)));
typedef float  f32x4  __attribute__((ext_vector_type(4)));
typedef int    i32x4  __attribute__((ext_vector_type(4)));
typedef int    i32x16 __attribute__((ext_vector_type(16)));

#define MFMA_F16(a,b,c)   __builtin_amdgcn_mfma_f32_16x16x32_f16((a),(b),(c),0,0,0)
#define MFMA_I8_32(a,b,c) __builtin_amdgcn_mfma_i32_32x32x32_i8((a),(b),(c),0,0,0)

__device__ __forceinline__ float b2f(u16 u){ union{unsigned u;float f;}v; v.u=((unsigned)u)<<16; return v.f; }
__device__ __forceinline__ u16 f2b(float f){ union{float f;unsigned u;}v; v.f=f;
  return (u16)((v.u + 0x7fffu + ((v.u>>16)&1u))>>16); }
__device__ __forceinline__ u16 f2h(float f){ f16 h = (f16)f; return __builtin_bit_cast(u16, h); }
__device__ __forceinline__ float h2f(u16 u){ return (float)__builtin_bit_cast(f16, u); }
__device__ __forceinline__ f16v8 ldh8(const u16* p){ return __builtin_bit_cast(f16v8, *(const u16v8*)p); }
__device__ __forceinline__ void gl2lds16(const void* g, void* l){
  __builtin_amdgcn_global_load_lds(
    (const __attribute__((address_space(1))) unsigned int*)g,
    (__attribute__((address_space(3))) unsigned int*)l,
    16, 0, 0);
}
// gelu(tanh-approx) via sigmoid identity: 0.5x(1+tanh(u)) = x*sigmoid(2u)
__device__ __forceinline__ float gelu_t(float x){
  float u2 = -1.5957691216057308f*(x + 0.044715f*x*x*x);
  return x * __builtin_amdgcn_rcpf(1.f + __expf(u2));
}

// ---------------- elementwise / prep ----------------
__global__ void mod_add_k(const float* __restrict__ sst, const float* __restrict__ t, float* __restrict__ mod){
  int i = blockIdx.x*256 + threadIdx.x;
  if (i < 2*6*1152) mod[i] = sst[i % 6912] + t[i];
}
// f32 -> f16 hi/lo planes (weights)
__global__ void split2h_k(const float* __restrict__ src, u16* __restrict__ hi, u16* __restrict__ lo, int n){
  int i = blockIdx.x*256 + threadIdx.x;
  if (i >= n) return;
  float v = src[i];
  f16 h = (f16)v;
  hi[i] = __builtin_bit_cast(u16, h);
  lo[i] = f2h(v - (float)h);
}
// fused cross-phase prep: conv qw_q, conv qw_cp, split Wkv (f16 hi/lo), y (f16 single)
__global__ void cross_prep_k(const int* __restrict__ qw_q, int8_t* __restrict__ w8q,
                             const int* __restrict__ qw_cp, int8_t* __restrict__ w8cp,
                             const float* __restrict__ Wkv, u16* __restrict__ wkvh, u16* __restrict__ wkvl,
                             const float* __restrict__ y, u16* __restrict__ yf){
  const int S1 = 1327104, S2 = 2654208, S3 = 5308416, S4 = 5824512;
  int i = blockIdx.x*256 + threadIdx.x;
  if (i < S1){ w8q[i] = (int8_t)qw_q[i]; }
  else if (i < S2){ int j = i - S1; w8cp[j] = (int8_t)qw_cp[j]; }
  else if (i < S3){ int j = i - S2; float v = Wkv[j]; f16 h = (f16)v;
    wkvh[j] = __builtin_bit_cast(u16, h); wkvl[j] = f2h(v - (float)h); }
  else if (i < S4){ int j = i - S3; yf[j] = f2h(y[j]); }
}
// fused MLP-phase prep: conv qw_f1, conv qw_f2
__global__ void mlp_prep_k(const int* __restrict__ qw_f1, int8_t* __restrict__ w8f1,
                           const int* __restrict__ qw_f2, int8_t* __restrict__ w8f2){
  const int S1 = 5308416, S2 = 10616832;
  int i = blockIdx.x*256 + threadIdx.x;
  if (i < S1){ w8f1[i] = (int8_t)qw_f1[i]; }
  else if (i < S2){ int j = i - S1; w8f2[j] = (int8_t)qw_f2[j]; }
}
// LN over C=1152 with modulation -> single f16 plane
__global__ void ln_mod_f16_k(const float* __restrict__ src, u16* __restrict__ xf,
                             const float* __restrict__ mod, int shift_row, int scale_row){
  const int row = blockIdx.x, tid = threadIdx.x;
  const int b = row >> 11;
  const float* ms = mod + ((size_t)b*6 + shift_row)*1152;
  const float* mc = mod + ((size_t)b*6 + scale_row)*1152;
  __shared__ float r1[256], r2[256];
  float s = 0.f, sq = 0.f, vals[5]; int cnt = 0;
  for (int c = tid; c < 1152; c += 256){
    float v = src[(size_t)row*1152+c];
    vals[cnt++] = v; s += v; sq += v*v;
  }
  r1[tid]=s; r2[tid]=sq; __syncthreads();
  for (int st=128; st>0; st>>=1){ if (tid<st){ r1[tid]+=r1[tid+st]; r2[tid]+=r2[tid+st]; } __syncthreads(); }
  float mean = r1[0]*(1.f/1152.f);
  float var  = r2[0]*(1.f/1152.f) - mean*mean;
  float rstd = rsqrtf(var + 1e-6f);
  cnt = 0;
  for (int c = tid; c < 1152; c += 256){
    float v = (vals[cnt++]-mean)*rstd*(1.f+mc[c]) + ms[c];
    xf[(size_t)row*1152+c] = f2h(v);
  }
}
// fused: xw = x + gate*ao, then per-row int8 quant of xw
__global__ void rgq_k(const float* __restrict__ x, const float* __restrict__ ao,
                      const float* __restrict__ mod, int gate_row, float* __restrict__ xw,
                      int8_t* __restrict__ q8, float* __restrict__ s_out, int* __restrict__ q_out){
  const int row = blockIdx.x, tid = threadIdx.x;
  const int b = row >> 11;
  const float* mg = mod + ((size_t)b*6 + gate_row)*1152;
  __shared__ float r1[256];
  __shared__ int ri[256];
  float mx = 0.f, vals[5]; int cnt = 0;
  for (int c = tid; c < 1152; c += 256){
    float v = x[(size_t)row*1152+c] + mg[c]*ao[(size_t)row*1152+c];
    xw[(size_t)row*1152+c] = v;
    vals[cnt++] = v; mx = fmaxf(mx, fabsf(v));
  }
  r1[tid]=mx; __syncthreads();
  for (int st=128; st>0; st>>=1){ if (tid<st) r1[tid]=fmaxf(r1[tid],r1[tid+st]); __syncthreads(); }
  const float s_ = fmaxf(r1[0]*(1.f/127.f), 1e-8f);
  const float inv = 1.f/s_;
  int acc = 0; cnt = 0;
  for (int c = tid; c < 1152; c += 256){
    float q = rintf(vals[cnt++]*inv);
    q = fminf(fmaxf(q, -127.f), 127.f);
    q8[(size_t)row*1152+c] = (int8_t)q;
    acc += (int)q;
  }
  ri[tid]=acc; __syncthreads();
  for (int st=128; st>0; st>>=1){ if (tid<st) ri[tid]+=ri[tid+st]; __syncthreads(); }
  if (tid==0){ s_out[row]=s_; q_out[row]=ri[0]; }
}
// fused: xw += add; LN+mod; per-row int8 quant
__global__ void rlq_k(float* __restrict__ xw, const float* __restrict__ add,
                      const float* __restrict__ mod, int shift_row, int scale_row,
                      int8_t* __restrict__ q8, float* __restrict__ s_out, int* __restrict__ q_out){
  const int row = blockIdx.x, tid = threadIdx.x;
  const int b = row >> 11;
  const float* ms = mod + ((size_t)b*6 + shift_row)*1152;
  const float* mc = mod + ((size_t)b*6 + scale_row)*1152;
  __shared__ float r1[256], r2[256];
  __shared__ int ri[256];
  float s = 0.f, sq = 0.f, vals[5]; int cnt = 0;
  for (int c = tid; c < 1152; c += 256){
    float v = xw[(size_t)row*1152+c] + add[(size_t)row*1152+c];
    xw[(size_t)row*1152+c] = v;
    vals[cnt++] = v; s += v; sq += v*v;
  }
  r1[tid]=s; r2[tid]=sq; __syncthreads();
  for (int st=128; st>0; st>>=1){ if (tid<st){ r1[tid]+=r1[tid+st]; r2[tid]+=r2[tid+st]; } __syncthreads(); }
  float mean = r1[0]*(1.f/1152.f);
  float var  = r2[0]*(1.f/1152.f) - mean*mean;
  float rstd = rsqrtf(var + 1e-6f);
  __syncthreads();
  float mx = 0.f; cnt = 0;
  for (int c = tid; c < 1152; c += 256){
    float v = (vals[cnt]-mean)*rstd*(1.f+mc[c]) + ms[c];
    vals[cnt++] = v; mx = fmaxf(mx, fabsf(v));
  }
  r1[tid]=mx; __syncthreads();
  for (int st=128; st>0; st>>=1){ if (tid<st) r1[tid]=fmaxf(r1[tid],r1[tid+st]); __syncthreads(); }
  const float s_ = fmaxf(r1[0]*(1.f/127.f), 1e-8f);
  const float inv = 1.f/s_;
  int acc = 0; cnt = 0;
  for (int c = tid; c < 1152; c += 256){
    float q = rintf(vals[cnt++]*inv);
    q = fminf(fmaxf(q, -127.f), 127.f);
    q8[(size_t)row*1152+c] = (int8_t)q;
    acc += (int)q;
  }
  ri[tid]=acc; __syncthreads();
  for (int st=128; st>0; st>>=1){ if (tid<st) ri[tid]+=ri[tid+st]; __syncthreads(); }
  if (tid==0){ s_out[row]=s_; q_out[row]=ri[0]; }
}
// register-cached row quant (C_ <= 4608)
template<int SRC_F32>
__global__ void quant_rows_k(const void* __restrict__ src, int C_,
                             int8_t* __restrict__ q8, float* __restrict__ s_out, int* __restrict__ q_out){
  const int row = blockIdx.x, tid = threadIdx.x;
  __shared__ float red[256];
  __shared__ int redi[256];
  float vals[18];
  float mx = 0.f; int cnt = 0;
  for (int c = tid; c < C_; c += 256){
    float v = SRC_F32 ? ((const float*)src)[(size_t)row*C_+c] : b2f(((const u16*)src)[(size_t)row*C_+c]);
    vals[cnt++] = v;
    mx = fmaxf(mx, fabsf(v));
  }
  red[tid]=mx; __syncthreads();
  for (int st=128; st>0; st>>=1){ if (tid<st) red[tid]=fmaxf(red[tid],red[tid+st]); __syncthreads(); }
  const float s_ = fmaxf(red[0]*(1.f/127.f), 1e-8f);
  const float inv = 1.f/s_;
  int acc = 0; cnt = 0;
  for (int c = tid; c < C_; c += 256){
    float q = rintf(vals[cnt++]*inv);
    q = fminf(fmaxf(q, -127.f), 127.f);
    q8[(size_t)row*C_+c] = (int8_t)q;
    acc += (int)q;
  }
  redi[tid]=acc; __syncthreads();
  for (int st=128; st>0; st>>=1){ if (tid<st) redi[tid]+=redi[tid+st]; __syncthreads(); }
  if (tid==0){ s_out[row]=s_; q_out[row]=redi[0]; }
}

// ------- f16 GEMM: out[M,N] = f16(A)[M,K] @ (Wh+Wl)[N,K]^T + bias -------
template<int MODE>
__global__ __launch_bounds__(256,4) void gemm_f16k(
    const u16* __restrict__ Af, int lda,
    const u16* __restrict__ Wh, const u16* __restrict__ Wl, int ldw,
    const float* __restrict__ bias, float* __restrict__ out, int ldo, int M, int K,
    u16* __restrict__ e1, u16* __restrict__ e2){
  __shared__ u16 sA[128*32];
  __shared__ u16 sWh[128*32];
  __shared__ u16 sWl[128*32];
  const int tid = threadIdx.x, lane = tid & 63;
  const int wv = tid >> 6, wx = wv & 1, wy = wv >> 1;
  const int quad = lane >> 4, l16 = lane & 15;
  const int m0 = blockIdx.y*128, n0 = blockIdx.x*128;
  f32x4 acc[4][4];
  #pragma unroll
  for (int i=0;i<4;i++)
    #pragma unroll
    for (int j=0;j<4;j++) acc[i][j] = (f32x4){0.f,0.f,0.f,0.f};
  for (int k0=0; k0<K; k0+=32){
    #pragma unroll
    for (int r=0;r<2;r++){
      int slotbase = r*256 + wv*64;        // wave-uniform LDS base (slot*16B)
      int slot = slotbase + lane;
      int row = slot >> 2;                 // 4 chunks of 16B per 32-u16 row
      int col8 = ((slot ^ (row>>1)) & 3) * 8;  // phys chunk = logical ^ ((row>>1)&3)
      int gm = m0 + row; if (gm > M-1) gm = M-1;
      size_t aoff = (size_t)gm*lda + k0 + col8;
      size_t woff = (size_t)(n0+row)*ldw + k0 + col8;
      gl2lds16(Af + aoff, &sA[(size_t)slotbase*8]);
      gl2lds16(Wh + woff, &sWh[(size_t)slotbase*8]);
      gl2lds16(Wl + woff, &sWl[(size_t)slotbase*8]);
    }
    __syncthreads();
    const int cs = ((quad ^ ((l16>>1)&3)) * 8);  // recovers logical chunk = quad
    f16v8 a[4], bh[4], bl[4];
    #pragma unroll
    for (int i=0;i<4;i++) a[i] = ldh8(&sA[(wy*64+i*16+l16)*32 + cs]);
    #pragma unroll
    for (int j=0;j<4;j++){
      bh[j] = ldh8(&sWh[(wx*64+j*16+l16)*32 + cs]);
      bl[j] = ldh8(&sWl[(wx*64+j*16+l16)*32 + cs]);
    }
    #pragma unroll
    for (int i=0;i<4;i++)
      #pragma unroll
      for (int j=0;j<4;j++){
        acc[i][j] = MFMA_F16(a[i], bh[j], acc[i][j]);
        acc[i][j] = MFMA_F16(a[i], bl[j], acc[i][j]);
      }
    __syncthreads();
  }
  #pragma unroll
  for (int j=0;j<4;j++){
    int col = n0 + wx*64 + j*16 + l16;
    float bc = bias ? bias[col] : 0.f;
    #pragma unroll
    for (int i=0;i<4;i++)
      #pragma unroll
      for (int r=0;r<4;r++){
        int row = m0 + wy*64 + i*16 + quad*4 + r;
        if (row >= M) continue;
        float v = acc[i][j][r] + bc;
        if (MODE == 0){
          out[(size_t)row*ldo + col] = v;
        } else if (MODE == 1){
          if (col < 2304){
            e1[(size_t)row*2304 + col] = f2h(v);
          } else {
            int vc = col - 2304;
            int hd_ = vc/72, d = vc - hd_*72;
            int z = row >> 8, s2 = row & 255;
            e2[((size_t)(z*16+hd_)*80 + d)*256 + s2] = f2h(v);
          }
        } else { // MODE 2: KV epilogue (448 rows): k f16 plane + V^T [h][80][448] f16
          if (col < 1152){
            e1[(size_t)row*1152 + col] = f2h(v);
          } else {
            int vc = col - 1152;
            int hd_ = vc/72, d = vc - hd_*72;
            e2[((size_t)hd_*80 + d)*448 + row] = f2h(v);
          }
        }
      }
  }
}

// ------- QKV GEMM: 256x256 tile, 4-phase/K-tile pipelined schedule (T3+T4+T5) -------
// R12: LDS-staged coalesced epilogue. WRITE_SIZE showed 41-49MB vs 29.4MB ideal (scalar
// u16 stores, 2B-granular vtf scatter). qkf/vtf split is tile-aligned (2304 = 9*256) so
// each block is pure-qkf or pure-vtf; after the final barrier all 144KB LDS is dead ->
// stage the 256x256 f16 tile (row-major for qkf; transposed for vtf since vtf is
// contiguous in s2=row) and write 16B dwordx4 runs. Main-loop schedule untouched.
#define QKV_NT 36
__global__ __launch_bounds__(512,2) void gemm_qkv_8ph(
    const u16* __restrict__ Af,
    const u16* __restrict__ Wh_, const u16* __restrict__ Wl_,
    const float* __restrict__ bias,
    u16* __restrict__ qkf, u16* __restrict__ vtf){
  extern __shared__ u16 sm[];
  char* smb = (char*)sm;
  const int tid = threadIdx.x, lane = tid & 63, wv = tid >> 6;
  const int wr = wv >> 2, wc = wv & 3;            // 2x4 wave grid
  const int quad = lane >> 4, l16 = lane & 15;
  const int c = blockIdx.x & 7, bi = blockIdx.x >> 3;
  const int m0 = (((c>>1)<<2) + (bi&3)) << 8;     // 16 m-tiles
  const int n0 = ((c&1)*7 + (bi>>2)) << 8;        // 14 n-tiles

  const u16* gA[2]; const u16* gH[2]; const u16* gL[2];
  int sbase[2];
  #pragma unroll
  for (int r=0;r<2;r++){
    int slot = r*512 + tid;
    int row = slot >> 2;
    int col8 = ((slot ^ (row>>1)) & 3) * 8;
    sbase[r] = (r*512 + wv*64) * 16;              // wave-uniform byte base
    gA[r] = Af + (size_t)(m0+row)*1152 + col8;
    int gn = n0 + row; if (gn > 3455) gn = 3455;
    gH[r] = Wh_ + (size_t)gn*1152 + col8;
    gL[r] = Wl_ + (size_t)gn*1152 + col8;
  }

  #define STG_A(t2,b) { size_t ko=(size_t)(t2)*32; \
    gl2lds16(gA[0]+ko, smb + (b)*49152 + sbase[0]); \
    gl2lds16(gA[1]+ko, smb + (b)*49152 + sbase[1]); }
  #define STG_H(t2,b) { size_t ko=(size_t)(t2)*32; \
    gl2lds16(gH[0]+ko, smb + (b)*49152 + 16384 + sbase[0]); \
    gl2lds16(gH[1]+ko, smb + (b)*49152 + 16384 + sbase[1]); }
  #define STG_L(t2,b) { size_t ko=(size_t)(t2)*32; \
    gl2lds16(gL[0]+ko, smb + (b)*49152 + 32768 + sbase[0]); \
    gl2lds16(gL[1]+ko, smb + (b)*49152 + 32768 + sbase[1]); }

  STG_A(0,0); STG_H(0,0); STG_L(0,0);
  STG_A(1,1); STG_H(1,1); STG_L(1,1);

  const int cs = (quad ^ ((l16>>1)&3)) * 8;       // read-side swizzle (logical chunk = quad)
  const int arow = wr*128 + l16;                  // + i*16
  const int wrow = wc*64 + l16;                   // + j*16

  f32x4 acc[8][4];
  #pragma unroll
  for (int i=0;i<8;i++)
    #pragma unroll
    for (int j=0;j<4;j++) acc[i][j] = (f32x4){0.f,0.f,0.f,0.f};

  f16v8 bh[4], bl[4];

  #define PHASE(p, STAGE_STMT) { \
    const u16* bA = sm + cur*24576; \
    f16v8 a0 = ldh8(bA + (arow + (2*(p))*16)*32 + cs); \
    f16v8 a1 = ldh8(bA + (arow + (2*(p)+1)*16)*32 + cs); \
    if ((p)==0){ \
      const u16* bH = bA + 8192; \
      const u16* bL = bA + 16384; \
      _Pragma("unroll") \
      for (int j=0;j<4;j++){ \
        bh[j] = ldh8(bH + (wrow + j*16)*32 + cs); \
        bl[j] = ldh8(bL + (wrow + j*16)*32 + cs); \
      } \
    } \
    STAGE_STMT; \
    __builtin_amdgcn_s_barrier(); \
    asm volatile("s_waitcnt lgkmcnt(0)" ::: "memory"); \
    __builtin_amdgcn_sched_barrier(0); \
    __builtin_amdgcn_s_setprio(1); \
    _Pragma("unroll") \
    for (int j=0;j<4;j++){ \
      acc[2*(p)][j]   = MFMA_F16(a0, bh[j], acc[2*(p)][j]); \
      acc[2*(p)][j]   = MFMA_F16(a0, bl[j], acc[2*(p)][j]); \
      acc[2*(p)+1][j] = MFMA_F16(a1, bh[j], acc[2*(p)+1][j]); \
      acc[2*(p)+1][j] = MFMA_F16(a1, bl[j], acc[2*(p)+1][j]); \
    } \
    __builtin_amdgcn_s_setprio(0); \
    __builtin_amdgcn_s_barrier(); \
  }

  int cur = 0;
  for (int t = 0; t < QKV_NT-1; ++t){
    const int nxt = (cur == 0) ? 2 : cur - 1;     // (t+2)%3
    asm volatile("s_waitcnt vmcnt(6)" ::: "memory");
    __builtin_amdgcn_s_barrier();
    __builtin_amdgcn_sched_barrier(0);
    const bool pf = (t < QKV_NT-2);
    PHASE(0, if (pf) STG_A(t+2,nxt));
    PHASE(1, if (pf) STG_H(t+2,nxt));
    PHASE(2, if (pf) STG_L(t+2,nxt));
    PHASE(3, );
    cur = (cur == 2) ? 0 : cur + 1;
  }
  asm volatile("s_waitcnt vmcnt(0)" ::: "memory");
  __builtin_amdgcn_s_barrier();
  __builtin_amdgcn_sched_barrier(0);
  PHASE(0, );
  PHASE(1, );
  PHASE(2, );
  PHASE(3, );

  // ---- R12 epilogue: LDS-staged coalesced stores ----
  {
    u16* T = sm;                      // staging tile, 256 x TS u16 (135,168 B <= 147,456)
    constexpr int TS = 264;           // +8 u16 pad (bank spread)
    const bool isv = (n0 >= 2304);
    if (!isv){
      // qkf block: stage row-major, copy 512B row-runs
      #pragma unroll
      for (int j=0;j<4;j++){
        const int col = wc*64 + j*16 + l16;
        const float bc = bias[n0 + col];
        #pragma unroll
        for (int i=0;i<8;i++){
          const int rowb = wr*128 + i*16 + quad*4;
          #pragma unroll
          for (int r=0;r<4;r++)
            T[(rowb+r)*TS + col] = f2h(acc[i][j][r] + bc);
        }
      }
      __syncthreads();
      for (int c2 = tid; c2 < 8192; c2 += 512){
        int row = c2 >> 5, ck = c2 & 31;
        u16v8 v = *(const u16v8*)&T[row*TS + ck*8];
        *(u16v8*)&qkf[(size_t)(m0+row)*2304 + n0 + ck*8] = v;
      }
    } else {
      // vtf block: stage TRANSPOSED (T[col][row]; vtf contiguous in s2=row)
      #pragma unroll
      for (int j=0;j<4;j++){
        const int col = wc*64 + j*16 + l16;
        const float bc = (n0 + col < 3456) ? bias[n0 + col] : 0.f;
        #pragma unroll
        for (int i=0;i<8;i++){
          const int rowb = wr*128 + i*16 + quad*4;
          u16v4 pk;
          #pragma unroll
          for (int r=0;r<4;r++) pk[r] = f2h(acc[i][j][r] + bc);
          *(u16v4*)&T[col*TS + rowb] = pk;     // 8B-aligned (rowb%4==0, TS*2%8==0)
        }
      }
      __syncthreads();
      const int vbase = n0 - 2304, z = m0 >> 8;
      for (int c2 = tid; c2 < 8192; c2 += 512){
        int col = c2 >> 5, ck = c2 & 31;
        if (n0 + col < 3456){
          int vc = vbase + col;
          int hd_ = vc/72, d = vc - hd_*72;
          u16v8 v = *(const u16v8*)&T[col*TS + ck*8];
          *(u16v8*)&vtf[((size_t)(z*16+hd_)*80 + d)*256 + ck*8] = v;
        }
      }
    }
  }
  #undef PHASE
  #undef STG_A
  #undef STG_H
  #undef STG_L
}

// ---------------- int8 GEMM, TLP structure (R3/R5-proven), BN=64 everywhere ----------------
template<int BN>
__global__ __launch_bounds__(256,6) void gemm_i8(
    const int8_t* __restrict__ A, int lda, const int8_t* __restrict__ W, int ldw,
    const float* __restrict__ rs, const int* __restrict__ rq,
    const float* __restrict__ sw, const int* __restrict__ zw, const float* __restrict__ bias,
    void* __restrict__ out, int ldo, int M, int K, int do_gelu, int out_f32,
    const float* __restrict__ xwf, const float* __restrict__ modf, int do_final){
  constexpr int NJ = BN/64 ? BN/64 : 1;          // j-tiles (32-wide) per wave
  __shared__ int8_t As[128*128];
  __shared__ int8_t Bs[BN*128];
  const int tid = threadIdx.x, lane = tid & 63, wv = tid >> 6;
  const int wx = wv & 1, wy = wv >> 1;
  const int l32 = lane & 31, g = lane >> 5;
  // XCD n-major chunked mapping (bijective when nwg%8==0)
  int n_idx = blockIdx.x, m_idx = blockIdx.y;
  {
    int nwg = gridDim.x*gridDim.y;
    if ((nwg & 7) == 0){
      int l = blockIdx.y*gridDim.x + blockIdx.x;
      int qq = nwg >> 3;
      int gidx = (l & 7)*qq + (l >> 3);
      n_idx = gidx / (int)gridDim.y;
      m_idx = gidx - n_idx*(int)gridDim.y;
    }
  }
  const int m0 = m_idx*128, n0 = n_idx*BN;
  const int srow = lane >> 3, schunk = lane & 7;
  const int scol = ((schunk ^ srow) & 7) * 16;   // XOR swizzle fetch column (128B rows)
  i32x16 acc[2][NJ];
  #pragma unroll
  for (int i=0;i<2;i++)
    #pragma unroll
    for (int j=0;j<NJ;j++)
      #pragma unroll
      for (int r=0;r<16;r++) acc[i][j][r] = 0;
  for (int k0 = 0; k0 < K; k0 += 128){
    #pragma unroll
    for (int i=0;i<4;i++){
      int rr = (i*4 + wv)*8;
      int gm = m0 + rr + srow; if (gm > M-1) gm = M-1;
      gl2lds16(A + (size_t)gm*lda + k0 + scol, &As[rr*128]);
    }
    #pragma unroll
    for (int i=0;i<BN/32;i++){
      int rr = (i*4 + wv)*8;
      gl2lds16(W + (size_t)(n0 + rr + srow)*ldw + k0 + scol, &Bs[rr*128]);
    }
    __syncthreads();
    #pragma unroll
    for (int kq=0; kq<4; kq++){
      i32x4 af[2], bw[NJ];
      #pragma unroll
      for (int i=0;i<2;i++){
        int row = wy*64 + i*32 + l32;
        int cs = (((kq*2 + g) ^ (row & 7))) * 16;
        af[i] = *(const i32x4*)&As[row*128 + cs];
      }
      #pragma unroll
      for (int j=0;j<NJ;j++){
        int row = wx*(BN/2) + j*32 + l32;
        int cs = (((kq*2 + g) ^ (row & 7))) * 16;
        bw[j] = *(const i32x4*)&Bs[row*128 + cs];
      }
      #pragma unroll
      for (int i=0;i<2;i++)
        #pragma unroll
        for (int j=0;j<NJ;j++)
          acc[i][j] = MFMA_I8_32(af[i], bw[j], acc[i][j]);
    }
    __syncthreads();
  }
  #pragma unroll
  for (int j=0;j<NJ;j++){
    int col = n0 + wx*(BN/2) + j*32 + l32;
    float swc = sw[col]; float zwc = (float)zw[col]; float bc = bias[col];
    #pragma unroll
    for (int i=0;i<2;i++)
      #pragma unroll
      for (int r=0;r<16;r++){
        int row = m0 + wy*64 + i*32 + (r&3) + 8*(r>>2) + 4*g;
        if (row < M){
          float v = ((float)acc[i][j][r] - (float)rq[row]*zwc) * (rs[row]*swc) + bc;
          if (do_gelu) v = gelu_t(v);
          if (do_final){
            int bb = row >> 11;
            float ov = xwf[(size_t)row*1152 + col] + modf[((size_t)bb*6+5)*1152 + col]*v;
            ((float*)out)[(size_t)row*ldo + col] = ov;
          } else if (out_f32) ((float*)out)[(size_t)row*ldo + col] = v;
          else                ((u16*)out)[(size_t)row*ldo + col] = f2b(v);
        }
      }
  }
}

// ---------------- self-attention (f16 single planes) ----------------
__global__ __launch_bounds__(256) void attn_self_f16(
    const u16* __restrict__ qkf, const u16* __restrict__ vtf,
    u16* __restrict__ of, float scale){
  constexpr int NT = 16, PSTR = 264, VSTR = 256;
  __shared__ u16 P[4*16*PSTR];
  const int tid = threadIdx.x, lane = tid & 63, wv = tid >> 6;
  const int quad = lane >> 4, l16 = lane & 15;
  const int h = blockIdx.y, z = blockIdx.z;
  const int qbase = z*256 + blockIdx.x*64;
  const u16* Vth = vtf + (size_t)(z*16+h)*80*VSTR;
  const f16v8 zf = __builtin_bit_cast(f16v8, (u16v8)0);
  const int mrow = qbase + wv*16 + l16;

  f16v8 qf[3];
  #pragma unroll
  for (int t=0;t<3;t++){
    if (t==2 && quad!=0){ qf[t]=zf; }
    else qf[t] = ldh8(qkf + (size_t)mrow*2304 + h*72 + t*32 + (t==2?0:quad*8));
  }
  f32x4 sc[NT];
  #pragma unroll
  for (int nt=0; nt<NT; nt++){
    f32x4 a = {0.f,0.f,0.f,0.f};
    #pragma unroll
    for (int t=0;t<3;t++){
      f16v8 kf = zf;
      if (!(t==2 && quad!=0))
        kf = ldh8(qkf + (size_t)(z*256 + nt*16 + l16)*2304 + 1152 + h*72 + t*32 + (t==2?0:quad*8));
      a = MFMA_F16(qf[t], kf, a);
    }
    sc[nt] = a;
  }
  float mx[4] = {-1e30f,-1e30f,-1e30f,-1e30f};
  #pragma unroll
  for (int nt=0; nt<NT; nt++)
    #pragma unroll
    for (int r=0;r<4;r++){ float v = sc[nt][r]*scale; sc[nt][r]=v; mx[r]=fmaxf(mx[r],v); }
  #pragma unroll
  for (int r=0;r<4;r++)
    for (int d=1; d<16; d<<=1) mx[r] = fmaxf(mx[r], __shfl_xor(mx[r], d, 64));
  float sm_[4] = {0.f,0.f,0.f,0.f};
  #pragma unroll
  for (int nt=0; nt<NT; nt++)
    #pragma unroll
    for (int r=0;r<4;r++){ float p = __expf(sc[nt][r]-mx[r]); sc[nt][r]=p; sm_[r]+=p; }
  #pragma unroll
  for (int r=0;r<4;r++){
    for (int d=1; d<16; d<<=1) sm_[r] += __shfl_xor(sm_[r], d, 64);
    sm_[r] = 1.f/sm_[r];
  }
  u16* Pw = P + wv*16*PSTR;
  #pragma unroll
  for (int nt=0; nt<NT; nt++)
    #pragma unroll
    for (int r=0;r<4;r++)
      Pw[(quad*4+r)*PSTR + nt*16 + l16] = f2h(sc[nt][r]*sm_[r]);
  const u16* Pr = P + wv*16*PSTR + (size_t)l16*PSTR;
  #pragma unroll
  for (int dt=0; dt<5; dt++){
    f32x4 o = {0.f,0.f,0.f,0.f};
    #pragma unroll
    for (int kk=0; kk<8; kk++){
      f16v8 pv = ldh8(Pr + kk*32 + quad*8);
      f16v8 bv = ldh8(Vth + (size_t)(dt*16+l16)*VSTR + kk*32 + quad*8);
      o = MFMA_F16(pv, bv, o);
    }
    int d = dt*16 + l16;
    if (d < 72){
      #pragma unroll
      for (int r=0;r<4;r++){
        int row = qbase + wv*16 + quad*4 + r;
        of[(size_t)row*1152 + h*72 + d] = f2h(o[r]);
      }
    }
  }
}

// ---------------- cross-attention (f16 q/k/P/V, f32 scores+softmax) ----------------
// R10-proven: K staged through LDS via global_load_lds (register-free loads); QK^T
// reads KS via ds_read. 2 waves/block; LDS P 29184 + KS 17920 = 47104 B.
__global__ __launch_bounds__(128) void attn_cross_f16(
    const float* __restrict__ Q32,
    const u16* __restrict__ Kf,                  // 448x1152 f16
    const u16* __restrict__ Vt,                  // [h][80][448] f16
    float* __restrict__ O, float scale){
  constexpr int NT = 28, PSTR = 456, VSTR = 448;
  __shared__ u16 P[2*16*PSTR];                   // 29,184 B
  __shared__ u16 KS[112*80];                     // 17,920 B (K quarter, rows padded to 80 u16)
  const int tid = threadIdx.x, lane = tid & 63, wv = tid >> 6;
  const int quad = lane >> 4, l16 = lane & 15;
  const int h = blockIdx.y;
  const int qbase = blockIdx.x*32;
  const u16* Vth = Vt + (size_t)h*80*VSTR;
  const f16v8 zf = __builtin_bit_cast(f16v8, (u16v8)0);

  const int mrow = qbase + wv*16 + l16;
  const float* qp = Q32 + (size_t)mrow*1152 + h*72;
  f16v8 qf[3];
  #pragma unroll
  for (int t=0;t<3;t++){
    if (t==2 && quad!=0){ qf[t]=zf; continue; }
    u16v8 hv;
    #pragma unroll
    for (int j=0;j<8;j++) hv[j] = f2h(qp[t*32 + (t==2?0:quad*8) + j]);
    qf[t] = __builtin_bit_cast(f16v8, hv);
  }
  f32x4 sc[NT];
  #pragma unroll
  for (int qt=0; qt<4; qt++){
    #pragma unroll
    for (int i=0;i<9;i++){
      int slot = i*128 + tid;                    // 0..1151
      if (slot < 1120){
        int row = slot/10, c = slot - row*10;
        gl2lds16(Kf + (size_t)(qt*112+row)*1152 + h*72 + c*8, (char*)KS + (size_t)slot*16);
      }
    }
    asm volatile("s_waitcnt vmcnt(0)" ::: "memory");
    __syncthreads();
    #pragma unroll
    for (int nt=0; nt<7; nt++){
      f32x4 a = {0.f,0.f,0.f,0.f};
      #pragma unroll
      for (int t=0;t<3;t++){
        f16v8 kf = zf;
        if (!(t==2 && quad!=0))
          kf = ldh8(&KS[(nt*16 + l16)*80 + t*32 + (t==2?0:quad*8)]);
        a = MFMA_F16(qf[t], kf, a);
      }
      sc[qt*7+nt] = a;
    }
    __syncthreads();   // all reads of KS done before next quarter overwrites
  }
  float mx[4] = {-1e30f,-1e30f,-1e30f,-1e30f};
  #pragma unroll
  for (int nt=0; nt<NT; nt++)
    #pragma unroll
    for (int r=0;r<4;r++){ float v = sc[nt][r]*scale; sc[nt][r]=v; mx[r]=fmaxf(mx[r],v); }
  #pragma unroll
  for (int r=0;r<4;r++)
    for (int d=1; d<16; d<<=1) mx[r] = fmaxf(mx[r], __shfl_xor(mx[r], d, 64));
  float sm_[4] = {0.f,0.f,0.f,0.f};
  #pragma unroll
  for (int nt=0; nt<NT; nt++)
    #pragma unroll
    for (int r=0;r<4;r++){ float p = __expf(sc[nt][r]-mx[r]); sc[nt][r]=p; sm_[r]+=p; }
  #pragma unroll
  for (int r=0;r<4;r++){
    for (int d=1; d<16; d<<=1) sm_[r] += __shfl_xor(sm_[r], d, 64);
    sm_[r] = 1.f/sm_[r];
  }
  u16* Pw = P + wv*16*PSTR;
  #pragma unroll
  for (int nt=0; nt<NT; nt++)
    #pragma unroll
    for (int r=0;r<4;r++)
      Pw[(quad*4+r)*PSTR + nt*16 + l16] = f2h(sc[nt][r]*sm_[r]);
  const u16* Pr = P + wv*16*PSTR + (size_t)l16*PSTR;
  #pragma unroll
  for (int dt=0; dt<5; dt++){
    f32x4 o = {0.f,0.f,0.f,0.f};
    #pragma unroll
    for (int kk=0; kk<14; kk++){
      f16v8 pv = ldh8(Pr + kk*32 + quad*8);
      f16v8 bv = ldh8(Vth + (size_t)(dt*16+l16)*VSTR + kk*32 + quad*8);
      o = MFMA_F16(pv, bv, o);
    }
    int d = dt*16 + l16;
    if (d < 72){
      #pragma unroll
      for (int r=0;r<4;r++){
        int row = qbase + wv*16 + quad*4 + r;
        O[(size_t)row*1152 + h*72 + d] = o[r];
      }
    }
  }
}

// ---------------- launch ----------------
extern "C" void kernel_launch(void* const* d_in, const int* in_sizes, int n_in,
                              void* d_out, int out_size, void* d_ws, size_t ws_size,
                              hipStream_t stream){
  const float* x    = (const float*)d_in[0];
  const float* y    = (const float*)d_in[1];
  const float* t    = (const float*)d_in[2];
  const float* sst  = (const float*)d_in[3];
  const float* Wqkv = (const float*)d_in[4];
  const float* bqkv = (const float*)d_in[5];
  const float* Wo   = (const float*)d_in[6];
  const float* bo   = (const float*)d_in[7];
  const float* Wkv  = (const float*)d_in[8];
  const float* bkv  = (const float*)d_in[9];
  const int*   qw_q  = (const int*)d_in[10];
  const float* sw_q  = (const float*)d_in[11];
  const int*   zw_q  = (const int*)d_in[12];
  const float* b_q   = (const float*)d_in[13];
  const int*   qw_cp = (const int*)d_in[14];
  const float* sw_cp = (const float*)d_in[15];
  const int*   zw_cp = (const int*)d_in[16];
  const float* b_cp  = (const float*)d_in[17];
  const int*   qw_f1 = (const int*)d_in[18];
  const float* sw_f1 = (const float*)d_in[19];
  const int*   zw_f1 = (const int*)d_in[20];
  const float* b_f1  = (const float*)d_in[21];
  const int*   qw_f2 = (const int*)d_in[22];
  const float* sw_f2 = (const float*)d_in[23];
  const int*   zw_f2 = (const int*)d_in[24];
  const float* b_f2  = (const float*)d_in[25];
  (void)in_sizes; (void)n_in; (void)out_size;

  constexpr size_t SZR = (size_t)4096*1152*4;        // 18,874,368
  constexpr size_t R0 = 0;                           // xw f32
  constexpr size_t R1 = R0 + SZR;
  constexpr size_t R2 = R1 + SZR;
  constexpr size_t R3 = R2 + SZR;
  constexpr size_t R4 = R3 + SZR;
  constexpr size_t R5 = R4 + (size_t)9437184;
  constexpr size_t R6 = R5 + (size_t)9437184;
  constexpr size_t RS = R6 + (size_t)10485760;
  constexpr size_t RQ = RS + (size_t)4096*4;
  constexpr size_t RM = RQ + (size_t)4096*4;
  constexpr size_t WS_NEED = RM + (size_t)2*6*1152*4;  // ~100.1 MB (proven ws >= 121.8 MB)
  if (ws_size < WS_NEED) return;

  char* ws = (char*)d_ws;
  float*  xw    = (float*)(ws + R0);
  u16*    wqkvh = (u16*)(ws + R1);
  u16*    wqkvl = (u16*)(ws + R1 + (size_t)3456*1152*2);
  u16*    wkvh  = (u16*)(ws + R1);
  u16*    wkvl  = (u16*)(ws + R1 + (size_t)2304*1152*2);
  u16*    yf    = (u16*)(ws + R1 + (size_t)2*2304*1152*2);
  float*  q32   = (float*)(ws + R1);
  float*  cpout = (float*)(ws + R1);
  int8_t* q8h   = (int8_t*)(ws + R1);
  u16*    qkf   = (u16*)(ws + R2);
  float*  aof   = (float*)(ws + R2);
  u16*    hbuf  = (u16*)(ws + R2);
  u16*    xmf   = (u16*)(ws + R4);
  u16*    of    = (u16*)(ws + R4);
  u16*    kf    = (u16*)(ws + R4 + (size_t)4128768);
  u16*    vtc   = (u16*)(ws + R4 + (size_t)6193152);
  int8_t* w8f2  = (int8_t*)(ws + R4);
  int8_t* w8q   = (int8_t*)(ws + R5);
  int8_t* w8cp  = (int8_t*)(ws + R5 + (size_t)1327104);
  int8_t* w8f1  = (int8_t*)(ws + R5 + (size_t)2654208);
  u16*    vtf   = (u16*)(ws + R6);
  u16*    woh   = (u16*)(ws + R6);
  u16*    wol   = (u16*)(ws + R6 + (size_t)1152*1152*2);
  int8_t* q8x   = (int8_t*)(ws + R6);
  float*  rs    = (float*)(ws + RS);
  int*    rq    = (int*)(ws + RQ);
  float*  mod   = (float*)(ws + RM);

  const float scale = 0.11785113019775793f; // 72^-0.5

  static bool attr_set = false;
  if (!attr_set){
    hipFuncSetAttribute(reinterpret_cast<const void*>(gemm_qkv_8ph),
                        hipFuncAttributeMaxDynamicSharedMemorySize, 3*49152);
    attr_set = true;
  }

  mod_add_k<<<(2*6*1152+255)/256,256,0,stream>>>(sst, t, mod);

  // ---- MSA branch (f16 GEMMs) ----
  ln_mod_f16_k<<<4096,256,0,stream>>>(x, xmf, mod, 0, 1);
  split2h_k<<<(3456*1152+255)/256,256,0,stream>>>(Wqkv, wqkvh, wqkvl, 3456*1152);
  gemm_qkv_8ph<<<dim3(224),dim3(512),3*49152,stream>>>(xmf, wqkvh, wqkvl, bqkv, qkf, vtf);
  attn_self_f16<<<dim3(4,16,16),256,0,stream>>>(qkf, vtf, of, scale);
  split2h_k<<<(1152*1152+255)/256,256,0,stream>>>(Wo, woh, wol, 1152*1152);
  gemm_f16k<0><<<dim3(9,32),256,0,stream>>>(of,1152, woh,wol,1152, bo, aof,1152, 4096,1152, nullptr,nullptr);
  rgq_k<<<4096,256,0,stream>>>(x, aof, mod, 2, xw, q8x, rs, rq);

  // ---- cross-attn branch ----
  cross_prep_k<<<(5824512+255)/256,256,0,stream>>>(qw_q,w8q, qw_cp,w8cp, Wkv,wkvh,wkvl, y,yf);
  gemm_f16k<2><<<dim3(18,4),256,0,stream>>>(yf,1152, wkvh,wkvl,1152, bkv, nullptr,0, 448,1152, kf,vtc);
  gemm_i8<64><<<dim3(18,32),256,0,stream>>>(q8x,1152, w8q,1152, rs,rq, sw_q,zw_q,b_q, q32,1152, 4096,1152, 0, 1, nullptr,nullptr,0);
  attn_cross_f16<<<dim3(128,16),128,0,stream>>>(q32, kf, vtc, aof, scale);
  quant_rows_k<1><<<4096,256,0,stream>>>(aof, 1152, q8x, rs, rq);
  gemm_i8<64><<<dim3(18,32),256,0,stream>>>(q8x,1152, w8cp,1152, rs,rq, sw_cp,zw_cp,b_cp, cpout,1152, 4096,1152, 0, 1, nullptr,nullptr,0);

  // ---- MLP branch ----
  rlq_k<<<4096,256,0,stream>>>(xw, cpout, mod, 3, 4, q8x, rs, rq);
  mlp_prep_k<<<(10616832+255)/256,256,0,stream>>>(qw_f1, w8f1, qw_f2, w8f2);
  gemm_i8<64><<<dim3(72,32),256,0,stream>>>(q8x,1152, w8f1,1152, rs,rq, sw_f1,zw_f1,b_f1, hbuf,4608, 4096,1152, 1, 0, nullptr,nullptr,0);
  quant_rows_k<0><<<4096,256,0,stream>>>(hbuf, 4608, q8h, rs, rq);
  gemm_i8<64><<<dim3(18,32),256,0,stream>>>(q8h,4608, w8f2,4608, rs,rq, sw_f2,zw_f2,b_f2, d_out,1152, 4096,4608, 0, 1, xw,mod,1);
}